// Round 3
// baseline (40829.913 us; speedup 1.0000x reference)
//
#include <hip/hip_runtime.h>
#include <stdint.h>

#define DEV __device__ __forceinline__

// ---------- double block reduce (256 threads), result on thread 0 ----------
DEV double dbl_block_reduce(double v, double* lds) {
#pragma unroll
  for (int off = 32; off > 0; off >>= 1) v += __shfl_down(v, off);
  int lane = threadIdx.x & 63, w = threadIdx.x >> 6;
  if (lane == 0) lds[w] = v;
  __syncthreads();
  double r = 0.0;
  if (threadIdx.x == 0) r = lds[0] + lds[1] + lds[2] + lds[3];
  __syncthreads();
  return r;
}

// ---------------- ternarize: fp64 stats ----------------
// per-tensor slot (4 doubles): [0]=sum|w|, [1]=masked sum|w|, [2]=count
__global__ __launch_bounds__(256) void tern_abs_sum(const float* __restrict__ w, int n,
                                                    double* __restrict__ st) {
  __shared__ double lds[4];
  double s = 0.0;
  for (int i = blockIdx.x * 256 + threadIdx.x; i < n; i += gridDim.x * 256)
    s += fabs((double)w[i]);
  s = dbl_block_reduce(s, lds);
  if (threadIdx.x == 0) atomicAdd(st, s);
}

__global__ __launch_bounds__(256) void tern_masked(const float* __restrict__ w, int n,
                                                   double* __restrict__ st) {
  __shared__ double lds[4];
  const double delta = 0.7 * st[0] / (double)n;
  double ms = 0.0, cnt = 0.0;
  for (int i = blockIdx.x * 256 + threadIdx.x; i < n; i += gridDim.x * 256) {
    double a = fabs((double)w[i]);
    if (a > delta) { ms += a; cnt += 1.0; }
  }
  ms = dbl_block_reduce(ms, lds);
  cnt = dbl_block_reduce(cnt, lds);
  if (threadIdx.x == 0) { atomicAdd(st + 1, ms); atomicAdd(st + 2, cnt); }
}

DEV float tern_alpha_d(const double* st, double n) {
  double cnt = st[2];
  return (float)(cnt > 0.0 ? st[1] / fmax(cnt, 1.0) : st[0] / n);
}

// conv weights -> ternarized floats, transposed to [cin*9][cout]
__global__ __launch_bounds__(256) void tern_write_conv(const float* __restrict__ w,
                                                       const double* __restrict__ st, int total,
                                                       int cin9, int COUT,
                                                       float* __restrict__ out) {
  int i = blockIdx.x * 256 + threadIdx.x;
  if (i >= total) return;
  double delta = 0.7 * st[0] / (double)total;
  float alpha = tern_alpha_d(st, (double)total);
  double v = (double)w[i];
  float r = v > delta ? alpha : (v < -delta ? -alpha : 0.f);
  int o = i / cin9;
  int rr = i - o * cin9;
  out[(size_t)rr * COUT + o] = r;
}

// fc weights -> int8 codes {-1,0,1}; alpha applied per-element in FC kernels
__global__ __launch_bounds__(256) void tern_write_code(const float* __restrict__ w,
                                                       const double* __restrict__ st, int total,
                                                       int8_t* __restrict__ out) {
  int i = blockIdx.x * 256 + threadIdx.x;
  if (i >= total) return;
  double delta = 0.7 * st[0] / (double)total;
  double v = (double)w[i];
  out[i] = (int8_t)((v > delta) ? 1 : ((v < -delta) ? -1 : 0));
}

// ---------------- dumb direct conv (recompute; no stored y) ----------------
// weights layout [cin*9][cout]; square images HW x HW; zero pad 1; stride 1.
template <int CIN>
DEV float conv_at(const float* __restrict__ in, const float* __restrict__ tw, int n, int co,
                  int y, int x, int HW, int COUT) {
  float acc = 0.f;
  const float* ib = in + (size_t)n * CIN * HW * HW;
#pragma unroll 1
  for (int ci = 0; ci < CIN; ++ci) {
    const float* ic = ib + (size_t)ci * HW * HW;
    const float* wr = tw + (size_t)(ci * 9) * COUT + co;
#pragma unroll
    for (int dy = 0; dy < 3; ++dy) {
      int gy = y + dy - 1;
      if ((unsigned)gy >= (unsigned)HW) continue;
#pragma unroll
      for (int dx = 0; dx < 3; ++dx) {
        int gx = x + dx - 1;
        if ((unsigned)gx >= (unsigned)HW) continue;
        acc = fmaf(ic[gy * HW + gx], wr[(dy * 3 + dx) * COUT], acc);
      }
    }
  }
  return acc;
}

// BN batch stats: blockIdx.y = channel, blockIdx.x covers N*H*W (exact multiple of 256).
// y = conv + bias, accumulated in fp64.
template <int CIN>
__global__ __launch_bounds__(256) void dconv_stats(const float* __restrict__ in,
                                                   const float* __restrict__ tw,
                                                   const float* __restrict__ b, int lhw,
                                                   int COUT, double* __restrict__ S,
                                                   double* __restrict__ Q) {
  __shared__ double lds[4];
  const int co = blockIdx.y;
  const int HW = 1 << lhw;
  int i = blockIdx.x * 256 + threadIdx.x;  // over N*HW*HW
  int x = i & (HW - 1);
  int y = (i >> lhw) & (HW - 1);
  int n = i >> (2 * lhw);
  float v = conv_at<CIN>(in, tw, n, co, y, x, HW, COUT) + b[co];
  double s = dbl_block_reduce((double)v, lds);
  double q = dbl_block_reduce((double)v * (double)v, lds);
  if (threadIdx.x == 0) {
    atomicAdd(&S[co], s);
    atomicAdd(&Q[co], q);
  }
}

__global__ void dfin(const double* __restrict__ S, const double* __restrict__ Q,
                     const float* __restrict__ g, const float* __restrict__ be, double M, int C,
                     float* __restrict__ scsh) {
  int c = blockIdx.x * blockDim.x + threadIdx.x;
  if (c >= C) return;
  double mean = S[c] / M;
  double var = Q[c] / M - mean * mean;
  double sc = (double)g[c] / sqrt(var + 1e-5);
  scsh[c] = (float)sc;
  scsh[C + c] = (float)((double)be[c] - mean * sc);
}

// Apply pass: one thread per pooled output (NCHW); recomputes the 4 conv values.
template <int CIN>
__global__ __launch_bounds__(256) void dconv_pool(const float* __restrict__ in,
                                                  const float* __restrict__ tw,
                                                  const float* __restrict__ b,
                                                  const float* __restrict__ scsh, int lhw,
                                                  int COUT, int lc, float* __restrict__ out) {
  const int HW = 1 << lhw, lho = lhw - 1, Ho = 1 << lho;
  int i = blockIdx.x * 256 + threadIdx.x;  // over N*COUT*Ho*Wo
  int qx = i & (Ho - 1);
  int qy = (i >> lho) & (Ho - 1);
  int co = (i >> (2 * lho)) & ((1 << lc) - 1);
  int n = i >> (2 * lho + lc);
  float sc = scsh[co], sh = scsh[(1 << lc) + co], bb = b[co];
  float m = 0.f;  // post-relu values are >= 0
#pragma unroll
  for (int d = 0; d < 4; ++d) {
    int y = 2 * qy + (d >> 1), x = 2 * qx + (d & 1);
    float v = conv_at<CIN>(in, tw, n, co, y, x, HW, COUT) + bb;
    m = fmaxf(m, fmaxf(fmaf(v, sc, sh), 0.f));
  }
  out[i] = m;
}

// ---------------- dumb FC: one thread per output element ----------------
__global__ __launch_bounds__(256) void dfc(const float* __restrict__ xin,
                                           const int8_t* __restrict__ codes,
                                           const double* __restrict__ st, double nels,
                                           const float* __restrict__ fb, int K, int OUT,
                                           int relu, float* __restrict__ out) {
  int i = blockIdx.x * 256 + threadIdx.x;  // over 32*OUT
  if (i >= 32 * OUT) return;
  int o = i % OUT, n = i / OUT;
  float alpha = tern_alpha_d(st, nels);
  const int8_t* cr = codes + (size_t)o * K;
  const float* xr = xin + (size_t)n * K;
  float acc = 0.f;
  for (int k = 0; k < K; ++k) {
    int c = cr[k];
    if (c) acc = fmaf(alpha * (float)c, xr[k], acc);
  }
  acc += fb[o];
  if (relu) acc = fmaxf(acc, 0.f);
  out[(size_t)n * OUT + o] = acc;
}

// ---------------- host ----------------
extern "C" void kernel_launch(void* const* d_in, const int* in_sizes, int n_in, void* d_out,
                              int out_size, void* d_ws, size_t ws_size, hipStream_t stream) {
  const float* x = (const float*)d_in[0];
  const float* w1 = (const float*)d_in[1];
  const float* b1 = (const float*)d_in[2];
  const float* g1 = (const float*)d_in[3];
  const float* be1 = (const float*)d_in[4];
  const float* w2 = (const float*)d_in[5];
  const float* b2 = (const float*)d_in[6];
  const float* g2 = (const float*)d_in[7];
  const float* be2 = (const float*)d_in[8];
  const float* w3 = (const float*)d_in[9];
  const float* b3 = (const float*)d_in[10];
  const float* g3 = (const float*)d_in[11];
  const float* be3 = (const float*)d_in[12];
  const float* w4 = (const float*)d_in[13];
  const float* b4 = (const float*)d_in[14];
  const float* g4 = (const float*)d_in[15];
  const float* be4 = (const float*)d_in[16];
  const float* fw1 = (const float*)d_in[17];
  const float* fb1 = (const float*)d_in[18];
  const float* fw2 = (const float*)d_in[19];
  const float* fb2 = (const float*)d_in[20];
  (void)in_sizes; (void)n_in; (void)out_size; (void)ws_size;

  char* ws = (char*)d_ws;
  size_t off = 0;
  auto alloc = [&](size_t bytes) {
    size_t o = off;
    off += (bytes + 255) & ~(size_t)255;
    return o;
  };
  float* tw1t = (float*)(ws + alloc((size_t)1728 * 4));      // [27][64]
  float* tw2t = (float*)(ws + alloc((size_t)73728 * 4));     // [576][128]
  float* tw3t = (float*)(ws + alloc((size_t)294912 * 4));    // [1152][256]
  float* tw4t = (float*)(ws + alloc((size_t)1179648 * 4));   // [2304][512]
  int8_t* c1 = (int8_t*)(ws + alloc((size_t)33554432));      // [1024][32768]
  int8_t* c2 = (int8_t*)(ws + alloc((size_t)1024000));       // [1000][1024]
  double* dst = (double*)(ws + alloc((size_t)2048 * 8));     // tern(6x4) + BN S/Q
  float* scsh = (float*)(ws + alloc((size_t)4096 * 4));      // per-layer [sc|sh]
  float* pool1 = (float*)(ws + alloc((size_t)8388608 * 4));  // [32][64][64][64]
  float* pool2 = (float*)(ws + alloc((size_t)4194304 * 4));  // [32][128][32][32]
  float* pool3 = (float*)(ws + alloc((size_t)2097152 * 4));  // [32][256][16][16]
  float* pool4 = (float*)(ws + alloc((size_t)1048576 * 4));  // [32][512][8][8] == [32][32768]
  float* fc1b = (float*)(ws + alloc((size_t)32768 * 4));     // [32][1024]
  // total ~104 MB

  // zero all fp64 stats accumulators (tern + BN sums)
  hipMemsetAsync(dst, 0, 2048 * 8, stream);

  struct TT { const float* w; int n; };
  TT ts[6] = {{w1, 1728},    {w2, 73728},     {w3, 294912},
              {w4, 1179648}, {fw1, 33554432}, {fw2, 1024000}};
  for (int t = 0; t < 6; ++t) {
    int blocks = (ts[t].n + 2047) / 2048;
    if (blocks > 4096) blocks = 4096;
    tern_abs_sum<<<blocks, 256, 0, stream>>>(ts[t].w, ts[t].n, dst + t * 4);
  }
  for (int t = 0; t < 6; ++t) {
    int blocks = (ts[t].n + 2047) / 2048;
    if (blocks > 4096) blocks = 4096;
    tern_masked<<<blocks, 256, 0, stream>>>(ts[t].w, ts[t].n, dst + t * 4);
  }
  tern_write_conv<<<7, 256, 0, stream>>>(w1, dst + 0, 1728, 27, 64, tw1t);
  tern_write_conv<<<288, 256, 0, stream>>>(w2, dst + 4, 73728, 576, 128, tw2t);
  tern_write_conv<<<1152, 256, 0, stream>>>(w3, dst + 8, 294912, 1152, 256, tw3t);
  tern_write_conv<<<4608, 256, 0, stream>>>(w4, dst + 12, 1179648, 2304, 512, tw4t);
  tern_write_code<<<131072, 256, 0, stream>>>(fw1, dst + 16, 33554432, c1);
  tern_write_code<<<4000, 256, 0, stream>>>(fw2, dst + 20, 1024000, c2);

  // fp64 BN sum slots
  double* S1 = dst + 48;   double* Q1 = S1 + 64;
  double* S2 = dst + 176;  double* Q2 = S2 + 128;
  double* S3 = dst + 432;  double* Q3 = S3 + 256;
  double* S4 = dst + 944;  double* Q4 = S4 + 512;
  float* ss1 = scsh;        // 128 floats
  float* ss2 = scsh + 128;  // 256
  float* ss3 = scsh + 512;  // 512
  float* ss4 = scsh + 1024; // 1024

  // Layer 1: 3->64 @128x128  (stats pass + fused apply/pool pass; y never stored)
  dconv_stats<3><<<dim3(2048, 64), 256, 0, stream>>>(x, tw1t, b1, 7, 64, S1, Q1);
  dfin<<<1, 64, 0, stream>>>(S1, Q1, g1, be1, 524288.0, 64, ss1);
  dconv_pool<3><<<32768, 256, 0, stream>>>(x, tw1t, b1, ss1, 7, 64, 6, pool1);

  // Layer 2: 64->128 @64x64
  dconv_stats<64><<<dim3(512, 128), 256, 0, stream>>>(pool1, tw2t, b2, 6, 128, S2, Q2);
  dfin<<<2, 64, 0, stream>>>(S2, Q2, g2, be2, 131072.0, 128, ss2);
  dconv_pool<64><<<16384, 256, 0, stream>>>(pool1, tw2t, b2, ss2, 6, 128, 7, pool2);

  // Layer 3: 128->256 @32x32
  dconv_stats<128><<<dim3(128, 256), 256, 0, stream>>>(pool2, tw3t, b3, 5, 256, S3, Q3);
  dfin<<<4, 64, 0, stream>>>(S3, Q3, g3, be3, 32768.0, 256, ss3);
  dconv_pool<128><<<8192, 256, 0, stream>>>(pool2, tw3t, b3, ss3, 5, 256, 8, pool3);

  // Layer 4: 256->512 @16x16
  dconv_stats<256><<<dim3(32, 512), 256, 0, stream>>>(pool3, tw4t, b4, 4, 512, S4, Q4);
  dfin<<<8, 64, 0, stream>>>(S4, Q4, g4, be4, 8192.0, 512, ss4);
  dconv_pool<256><<<4096, 256, 0, stream>>>(pool3, tw4t, b4, ss4, 4, 512, 9, pool4);

  // FC1: [32,32768] x [1024,32768]^T, relu
  dfc<<<128, 256, 0, stream>>>(pool4, c1, dst + 16, 33554432.0, fb1, 32768, 1024, 1, fc1b);
  // FC2: [32,1024] x [1000,1024]^T
  dfc<<<125, 256, 0, stream>>>(fc1b, c2, dst + 20, 1024000.0, fb2, 1024, 1000, 0,
                               (float*)d_out);
}

// Round 4
// 2432.538 us; speedup vs baseline: 16.7849x; 16.7849x over previous
//
#include <hip/hip_runtime.h>
#include <stdint.h>

#define DEV __device__ __forceinline__

DEV float wave_reduce_f(float v) {
#pragma unroll
  for (int off = 32; off > 0; off >>= 1) v += __shfl_down(v, off);
  return v;
}

DEV double wave_reduce_d(double v) {
#pragma unroll
  for (int off = 32; off > 0; off >>= 1) v += __shfl_down(v, off);
  return v;
}

// 256-thread block reduce (double); result valid on thread 0 only.
DEV double dbl_block_reduce(double v, double* lds) {
  v = wave_reduce_d(v);
  int lane = threadIdx.x & 63, w = threadIdx.x >> 6;
  if (lane == 0) lds[w] = v;
  __syncthreads();
  double r = 0.0;
  if (threadIdx.x == 0) r = lds[0] + lds[1] + lds[2] + lds[3];
  __syncthreads();
  return r;
}

// ---------------- ternarize: fp64 stats (matches fp64 numpy ref decisions) ----------------
// per-tensor slot (4 doubles): [0]=sum|w|, [1]=masked sum|w|, [2]=count
__global__ __launch_bounds__(256) void tern_abs_sum(const float* __restrict__ w, int n,
                                                    double* __restrict__ st) {
  __shared__ double lds[4];
  double s = 0.0;
  for (int i = blockIdx.x * 256 + threadIdx.x; i < n; i += gridDim.x * 256)
    s += fabs((double)w[i]);
  s = dbl_block_reduce(s, lds);
  if (threadIdx.x == 0) atomicAdd(st, s);
}

__global__ __launch_bounds__(256) void tern_masked(const float* __restrict__ w, int n,
                                                   double* __restrict__ st) {
  __shared__ double lds[4];
  const double delta = 0.7 * st[0] / (double)n;
  double ms = 0.0, cnt = 0.0;
  for (int i = blockIdx.x * 256 + threadIdx.x; i < n; i += gridDim.x * 256) {
    double a = fabs((double)w[i]);
    if (a > delta) { ms += a; cnt += 1.0; }
  }
  ms = dbl_block_reduce(ms, lds);
  cnt = dbl_block_reduce(cnt, lds);
  if (threadIdx.x == 0) { atomicAdd(st + 1, ms); atomicAdd(st + 2, cnt); }
}

DEV float tern_alpha_d(const double* st, double n) {
  double cnt = st[2];
  return (float)(cnt > 0.0 ? st[1] / fmax(cnt, 1.0) : st[0] / n);
}

// conv weights -> ternarized floats, transposed to [cin*9][cout]
__global__ __launch_bounds__(256) void tern_write_conv(const float* __restrict__ w,
                                                       const double* __restrict__ st, int total,
                                                       int cin9, int COUT,
                                                       float* __restrict__ out) {
  int i = blockIdx.x * 256 + threadIdx.x;
  if (i >= total) return;
  double delta = 0.7 * st[0] / (double)total;
  float alpha = tern_alpha_d(st, (double)total);
  double v = (double)w[i];
  float r = v > delta ? alpha : (v < -delta ? -alpha : 0.f);
  int o = i / cin9;
  int rr = i - o * cin9;
  out[(size_t)rr * COUT + o] = r;
}

// fc weights -> int8 codes {-1,0,1}; alpha applied in FC epilogue
__global__ __launch_bounds__(256) void tern_write_code(const float* __restrict__ w,
                                                       const double* __restrict__ st, int total,
                                                       int8_t* __restrict__ out) {
  int i = blockIdx.x * 256 + threadIdx.x;
  if (i >= total) return;
  double delta = 0.7 * st[0] / (double)total;
  double v = (double)w[i];
  out[i] = (int8_t)((v > delta) ? 1 : ((v < -delta) ? -1 : 0));
}

// ---------------- BN reduce + finalize (fp64 partials -> fp32 sc/sh) ----------------
__global__ __launch_bounds__(256) void bn_reduce_fin(const double* __restrict__ pS,
                                                     const double* __restrict__ pQ, int P,
                                                     const float* __restrict__ g,
                                                     const float* __restrict__ be, double M,
                                                     float* __restrict__ scsh, int C) {
  __shared__ double lds[4];
  const int c = blockIdx.x;
  double s = 0.0, q = 0.0;
  for (int p = threadIdx.x; p < P; p += 256) {
    s += pS[(size_t)c * P + p];
    q += pQ[(size_t)c * P + p];
  }
  s = dbl_block_reduce(s, lds);
  q = dbl_block_reduce(q, lds);
  if (threadIdx.x == 0) {
    double mean = s / M;
    double var = q / M - mean * mean;
    double sc = (double)g[c] / sqrt(var + 1e-5);
    scsh[c] = (float)sc;
    scsh[C + c] = (float)((double)be[c] - mean * sc);
  }
}

// ---------------- layer 1 (3->64, 128x128): recomputed, y never materialized -------------
DEV void conv1_acc_body(const float* __restrict__ in, const float* __restrict__ wt,
                        const float* __restrict__ b, int tX, int tY, int g0, int n,
                        float (&smem)[3][18][18], float (&acc)[16]) {
  const int px = threadIdx.x & 15, py = threadIdx.x >> 4;
  const int tx0 = tX * 16 - 1, ty0 = tY * 16 - 1;
  for (int idx = threadIdx.x; idx < 3 * 324; idx += 256) {
    int ck = idx / 324, rem = idx - ck * 324;
    int yy = rem / 18, xx = rem - yy * 18;
    int gy = ty0 + yy, gx = tx0 + xx;
    float v = 0.f;
    if ((unsigned)gy < 128u && (unsigned)gx < 128u)
      v = in[(((size_t)n * 3 + ck) * 128 + gy) * 128 + gx];
    smem[ck][yy][xx] = v;
  }
  __syncthreads();
#pragma unroll
  for (int g = 0; g < 16; ++g) acc[g] = b[g0 + g];
#pragma unroll
  for (int ck = 0; ck < 3; ++ck) {
    const float* wrow = wt + (size_t)(ck * 9) * 64 + g0;
#pragma unroll
    for (int dy = 0; dy < 3; ++dy) {
#pragma unroll
      for (int dx = 0; dx < 3; ++dx) {
        float xv = smem[ck][py + dy][px + dx];
        const float* wp = wrow + (dy * 3 + dx) * 64;  // block-uniform -> scalar loads
#pragma unroll
        for (int g = 0; g < 16; ++g) acc[g] = fmaf(xv, wp[g], acc[g]);
      }
    }
  }
}

__global__ __launch_bounds__(256) void conv1_stats(const float* __restrict__ in,
                                                   const float* __restrict__ wt,
                                                   const float* __restrict__ b,
                                                   double* __restrict__ pS,
                                                   double* __restrict__ pQ) {
  __shared__ float smem[3][18][18];
  __shared__ double ldsS[4][16], ldsQ[4][16];
  const int tX = blockIdx.x & 7, tY = blockIdx.x >> 3;
  const int g0 = blockIdx.y * 16, n = blockIdx.z;
  float acc[16];
  conv1_acc_body(in, wt, b, tX, tY, g0, n, smem, acc);
  const int lane = threadIdx.x & 63, w = threadIdx.x >> 6;
#pragma unroll
  for (int g = 0; g < 16; ++g) {
    double s = wave_reduce_d((double)acc[g]);
    double q = wave_reduce_d((double)acc[g] * (double)acc[g]);
    if (lane == 0) { ldsS[w][g] = s; ldsQ[w][g] = q; }
  }
  __syncthreads();
  const int p = n * 64 + blockIdx.x;  // P = 2048
  if (threadIdx.x < 16) {
    int g = threadIdx.x;
    pS[(size_t)(g0 + g) * 2048 + p] = ldsS[0][g] + ldsS[1][g] + ldsS[2][g] + ldsS[3][g];
  } else if (threadIdx.x < 32) {
    int g = threadIdx.x - 16;
    pQ[(size_t)(g0 + g) * 2048 + p] = ldsQ[0][g] + ldsQ[1][g] + ldsQ[2][g] + ldsQ[3][g];
  }
}

__global__ __launch_bounds__(256) void conv1_pool(const float* __restrict__ in,
                                                  const float* __restrict__ wt,
                                                  const float* __restrict__ b,
                                                  const float* __restrict__ scsh,
                                                  float* __restrict__ out) {
  __shared__ float smem[3][18][18];
  __shared__ float pool[4][16][16];
  const int tX = blockIdx.x & 7, tY = blockIdx.x >> 3;
  const int g0 = blockIdx.y * 16, n = blockIdx.z;
  float acc[16];
  conv1_acc_body(in, wt, b, tX, tY, g0, n, smem, acc);
  const int px = threadIdx.x & 15, py = threadIdx.x >> 4;
  for (int chunk = 0; chunk < 4; ++chunk) {
    __syncthreads();
#pragma unroll
    for (int gl = 0; gl < 4; ++gl) {
      int g = chunk * 4 + gl, c = g0 + g;
      pool[gl][py][px] = fmaxf(fmaf(acc[g], scsh[c], scsh[64 + c]), 0.f);
    }
    __syncthreads();
    int gl = threadIdx.x >> 6, r = threadIdx.x & 63, qy = r >> 3, qx = r & 7;
    float m = fmaxf(fmaxf(pool[gl][2 * qy][2 * qx], pool[gl][2 * qy][2 * qx + 1]),
                    fmaxf(pool[gl][2 * qy + 1][2 * qx], pool[gl][2 * qy + 1][2 * qx + 1]));
    int c = g0 + chunk * 4 + gl;
    out[(((size_t)n * 64 + c) * 64 + tY * 8 + qy) * 64 + tX * 8 + qx] = m;
  }
}

// ---------------- conv 3x3, pad 1, fp32, bias included, fused fp64 BN partials -----------
// block: 16x16 pixel tile, 16 couts/block, LDS-staged input w/ halo, weights [cin*9][cout]
template <int CIN, int CK>
__global__ __launch_bounds__(256) void conv3x3f(const float* __restrict__ in,
                                                const float* __restrict__ wt,
                                                const float* __restrict__ b,
                                                float* __restrict__ out, int H, int W, int COUT,
                                                int tilesX, double* __restrict__ pS,
                                                double* __restrict__ pQ, int P) {
  __shared__ float smem[CK][18][18];
  __shared__ double ldsS[4][16], ldsQ[4][16];
  const int tX = blockIdx.x % tilesX, tY = blockIdx.x / tilesX;
  const int g0 = blockIdx.y * 16;
  const int n = blockIdx.z;
  const int px = threadIdx.x & 15, py = threadIdx.x >> 4;
  const int tx0 = tX * 16 - 1, ty0 = tY * 16 - 1;
  float acc[16];
#pragma unroll
  for (int g = 0; g < 16; ++g) acc[g] = b[g0 + g];

  for (int c0 = 0; c0 < CIN; c0 += CK) {
    __syncthreads();
    for (int idx = threadIdx.x; idx < CK * 324; idx += 256) {
      int ck = idx / 324, rem = idx - ck * 324;
      int yy = rem / 18, xx = rem - yy * 18;
      int gy = ty0 + yy, gx = tx0 + xx;
      float v = 0.f;
      if ((unsigned)gy < (unsigned)H && (unsigned)gx < (unsigned)W)
        v = in[(((size_t)n * CIN + (c0 + ck)) * H + gy) * W + gx];
      smem[ck][yy][xx] = v;
    }
    __syncthreads();
#pragma unroll
    for (int ck = 0; ck < CK; ++ck) {
      const float* wrow = wt + (size_t)((c0 + ck) * 9) * COUT + g0;
#pragma unroll
      for (int dy = 0; dy < 3; ++dy) {
#pragma unroll
        for (int dx = 0; dx < 3; ++dx) {
          float xv = smem[ck][py + dy][px + dx];
          const float* wp = wrow + (dy * 3 + dx) * COUT;  // block-uniform -> scalar loads
#pragma unroll
          for (int g = 0; g < 16; ++g) acc[g] = fmaf(xv, wp[g], acc[g]);
        }
      }
    }
  }
  const int oy = tY * 16 + py, ox = tX * 16 + px;
#pragma unroll
  for (int g = 0; g < 16; ++g)
    out[(((size_t)n * COUT + g0 + g) * H + oy) * W + ox] = acc[g];

  // fused fp64 BN partial sums (one partial per block per cout)
  const int lane = threadIdx.x & 63, w = threadIdx.x >> 6;
#pragma unroll
  for (int g = 0; g < 16; ++g) {
    double s = wave_reduce_d((double)acc[g]);
    double q = wave_reduce_d((double)acc[g] * (double)acc[g]);
    if (lane == 0) { ldsS[w][g] = s; ldsQ[w][g] = q; }
  }
  __syncthreads();
  const int p = blockIdx.z * gridDim.x + blockIdx.x;
  if (threadIdx.x < 16) {
    int g = threadIdx.x;
    pS[(size_t)(g0 + g) * P + p] = ldsS[0][g] + ldsS[1][g] + ldsS[2][g] + ldsS[3][g];
  } else if (threadIdx.x < 32) {
    int g = threadIdx.x - 16;
    pQ[(size_t)(g0 + g) * P + p] = ldsQ[0][g] + ldsQ[1][g] + ldsQ[2][g] + ldsQ[3][g];
  }
}

// ---------------- fused norm+relu+pool (fp32 y in) ----------------
// out normal NCHW, or (TRANS) [k=c*Ho*Wo+ho*Wo+wo][n=32] for the FC1 GEMM
template <bool TRANS>
__global__ __launch_bounds__(256) void bn_pool(const float* __restrict__ y,
                                               const float* __restrict__ scsh, int C, int lw,
                                               int lh, int lc, int N, float* __restrict__ out) {
  const int Wo = 1 << lw, Ho = 1 << lh;
  const int total = (N << lc) << (lw + lh);
  const int Wrow = 1 << (lw + 1);
  for (int i = blockIdx.x * 256 + threadIdx.x; i < total; i += gridDim.x * 256) {
    int wo = i & (Wo - 1);
    int ho = (i >> lw) & (Ho - 1);
    int c = (i >> (lw + lh)) & (C - 1);
    int n = i >> (lw + lh + lc);
    float sc = scsh[c], sh = scsh[C + c];
    size_t idx = (((((size_t)n * C + c) << (lh + 1)) + (ho << 1)) << (lw + 1)) + (wo << 1);
    float z00 = fmaxf(fmaf(y[idx], sc, sh), 0.f);
    float z01 = fmaxf(fmaf(y[idx + 1], sc, sh), 0.f);
    float z10 = fmaxf(fmaf(y[idx + Wrow], sc, sh), 0.f);
    float z11 = fmaxf(fmaf(y[idx + Wrow + 1], sc, sh), 0.f);
    float m = fmaxf(fmaxf(z00, z01), fmaxf(z10, z11));
    if (TRANS) {
      int k = (((c << lh) + ho) << lw) + wo;
      out[(size_t)k * 32 + n] = m;
    } else {
      out[i] = m;
    }
  }
}

// ---------------- FC layers (ternary codes, alpha in epilogue) ----------------
// pT: [K][32], codes: [OUT][K]; one block per output o
template <int K>
__global__ __launch_bounds__(256) void fc_kernel(const float* __restrict__ pT,
                                                 const int8_t* __restrict__ codes,
                                                 const double* __restrict__ st, double nels,
                                                 const float* __restrict__ fb, int relu,
                                                 float* __restrict__ outT,
                                                 float* __restrict__ outN, int OUT) {
  const int o = blockIdx.x;
  float acc[32];
#pragma unroll
  for (int j = 0; j < 32; ++j) acc[j] = 0.f;
  const int8_t* crow = codes + (size_t)o * K;
  for (int k = threadIdx.x; k < K; k += 256) {
    int cv = crow[k];
    if (cv != 0) {
      float c = (float)cv;
      const float4* pv = (const float4*)(pT + ((size_t)k << 5));
#pragma unroll
      for (int j = 0; j < 8; ++j) {
        float4 v = pv[j];
        acc[4 * j + 0] = fmaf(c, v.x, acc[4 * j + 0]);
        acc[4 * j + 1] = fmaf(c, v.y, acc[4 * j + 1]);
        acc[4 * j + 2] = fmaf(c, v.z, acc[4 * j + 2]);
        acc[4 * j + 3] = fmaf(c, v.w, acc[4 * j + 3]);
      }
    }
  }
#pragma unroll
  for (int j = 0; j < 32; ++j) {
#pragma unroll
    for (int off = 32; off > 0; off >>= 1) acc[j] += __shfl_down(acc[j], off);
  }
  __shared__ float red[4][32];
  int lane = threadIdx.x & 63, wv = threadIdx.x >> 6;
  if (lane == 0) {
#pragma unroll
    for (int j = 0; j < 32; ++j) red[wv][j] = acc[j];
  }
  __syncthreads();
  if (threadIdx.x < 32) {
    int n = threadIdx.x;
    float alpha = tern_alpha_d(st, nels);
    float t = (red[0][n] + red[1][n] + red[2][n] + red[3][n]) * alpha + fb[o];
    if (relu) t = fmaxf(t, 0.f);
    if (outT) outT[(size_t)o * 32 + n] = t;
    if (outN) outN[(size_t)n * OUT + o] = t;
  }
}

// ---------------- host ----------------
extern "C" void kernel_launch(void* const* d_in, const int* in_sizes, int n_in, void* d_out,
                              int out_size, void* d_ws, size_t ws_size, hipStream_t stream) {
  const float* x = (const float*)d_in[0];
  const float* w1 = (const float*)d_in[1];
  const float* b1 = (const float*)d_in[2];
  const float* g1 = (const float*)d_in[3];
  const float* be1 = (const float*)d_in[4];
  const float* w2 = (const float*)d_in[5];
  const float* b2 = (const float*)d_in[6];
  const float* g2 = (const float*)d_in[7];
  const float* be2 = (const float*)d_in[8];
  const float* w3 = (const float*)d_in[9];
  const float* b3 = (const float*)d_in[10];
  const float* g3 = (const float*)d_in[11];
  const float* be3 = (const float*)d_in[12];
  const float* w4 = (const float*)d_in[13];
  const float* b4 = (const float*)d_in[14];
  const float* g4 = (const float*)d_in[15];
  const float* be4 = (const float*)d_in[16];
  const float* fw1 = (const float*)d_in[17];
  const float* fb1 = (const float*)d_in[18];
  const float* fw2 = (const float*)d_in[19];
  const float* fb2 = (const float*)d_in[20];
  (void)in_sizes; (void)n_in; (void)out_size; (void)ws_size;

  char* ws = (char*)d_ws;
  size_t off = 0;
  auto alloc = [&](size_t bytes) {
    size_t o = off;
    off += (bytes + 255) & ~(size_t)255;
    return o;
  };
  float* tw1t = (float*)(ws + alloc((size_t)1728 * 4));       // [27][64]
  float* tw2t = (float*)(ws + alloc((size_t)73728 * 4));      // [576][128]
  float* tw3t = (float*)(ws + alloc((size_t)294912 * 4));     // [1152][256]
  float* tw4t = (float*)(ws + alloc((size_t)1179648 * 4));    // [2304][512]
  int8_t* c1 = (int8_t*)(ws + alloc((size_t)33554432));       // [1024][32768]
  int8_t* c2 = (int8_t*)(ws + alloc((size_t)1024000));        // [1000][1024]
  double* dst = (double*)(ws + alloc((size_t)32 * 8));        // tern stats 6x4 doubles
  float* scsh = (float*)(ws + alloc((size_t)4096 * 4));       // per-layer [sc|sh]
  double* pS = (double*)(ws + alloc((size_t)131072 * 8));     // fp64 BN partials
  double* pQ = (double*)(ws + alloc((size_t)131072 * 8));
  float* bufY = (float*)(ws + alloc((size_t)16777216 * 4));   // 67MB: pre-BN y (layers 2-4)
  float* bufA = (float*)(ws + alloc((size_t)8388608 * 4));    // 33.5MB: pooled acts (reused)
  float* fc1T = (float*)(ws + alloc((size_t)32768 * 4));      // [1024][32]
  float* p4T = bufA + 4194304;  // pooled4 [32768][32]; disjoint from pooled3 (first 2.1M floats)
  // total ~143 MB (R1 ran 163 MB without fault -> ws_size >= 163 MB)

  hipMemsetAsync(dst, 0, 32 * 8, stream);

  struct TT { const float* w; int n; };
  TT ts[6] = {{w1, 1728},    {w2, 73728},     {w3, 294912},
              {w4, 1179648}, {fw1, 33554432}, {fw2, 1024000}};
  for (int t = 0; t < 6; ++t) {
    int blocks = (ts[t].n + 2047) / 2048;
    if (blocks > 4096) blocks = 4096;
    tern_abs_sum<<<blocks, 256, 0, stream>>>(ts[t].w, ts[t].n, dst + t * 4);
  }
  for (int t = 0; t < 6; ++t) {
    int blocks = (ts[t].n + 2047) / 2048;
    if (blocks > 4096) blocks = 4096;
    tern_masked<<<blocks, 256, 0, stream>>>(ts[t].w, ts[t].n, dst + t * 4);
  }
  tern_write_conv<<<7, 256, 0, stream>>>(w1, dst + 0, 1728, 27, 64, tw1t);
  tern_write_conv<<<288, 256, 0, stream>>>(w2, dst + 4, 73728, 576, 128, tw2t);
  tern_write_conv<<<1152, 256, 0, stream>>>(w3, dst + 8, 294912, 1152, 256, tw3t);
  tern_write_conv<<<4608, 256, 0, stream>>>(w4, dst + 12, 1179648, 2304, 512, tw4t);
  tern_write_code<<<131072, 256, 0, stream>>>(fw1, dst + 16, 33554432, c1);
  tern_write_code<<<4000, 256, 0, stream>>>(fw2, dst + 20, 1024000, c2);

  float* ss1 = scsh;         // 128 floats
  float* ss2 = scsh + 128;   // 256
  float* ss3 = scsh + 512;   // 512
  float* ss4 = scsh + 1024;  // 1024

  // Layer 1: 3->64 @128x128. Recompute trick: stats pass (no y store), then fused
  // conv+BN+relu+pool pass writing pooled fp32 directly; y (134MB) never materialized.
  conv1_stats<<<dim3(64, 4, 32), 256, 0, stream>>>(x, tw1t, b1, pS, pQ);
  bn_reduce_fin<<<64, 256, 0, stream>>>(pS, pQ, 2048, g1, be1, 524288.0, ss1, 64);
  conv1_pool<<<dim3(64, 4, 32), 256, 0, stream>>>(x, tw1t, b1, ss1, bufA);

  // Layer 2: 64->128 @64x64 (conv writes fp32 y + fused fp64 BN partials)
  conv3x3f<64, 8><<<dim3(16, 8, 32), 256, 0, stream>>>(bufA, tw2t, b2, bufY, 64, 64, 128, 4, pS,
                                                       pQ, 512);
  bn_reduce_fin<<<128, 256, 0, stream>>>(pS, pQ, 512, g2, be2, 131072.0, ss2, 128);
  bn_pool<false><<<16384, 256, 0, stream>>>(bufY, ss2, 128, 5, 5, 7, 32, bufA);

  // Layer 3: 128->256 @32x32
  conv3x3f<128, 8><<<dim3(4, 16, 32), 256, 0, stream>>>(bufA, tw3t, b3, bufY, 32, 32, 256, 2, pS,
                                                        pQ, 128);
  bn_reduce_fin<<<256, 256, 0, stream>>>(pS, pQ, 128, g3, be3, 32768.0, ss3, 256);
  bn_pool<false><<<8192, 256, 0, stream>>>(bufY, ss3, 256, 4, 4, 8, 32, bufA);

  // Layer 4: 256->512 @16x16; pooled output written transposed [k][n] for FC1
  conv3x3f<256, 8><<<dim3(1, 32, 32), 256, 0, stream>>>(bufA, tw4t, b4, bufY, 16, 16, 512, 1, pS,
                                                        pQ, 32);
  bn_reduce_fin<<<512, 256, 0, stream>>>(pS, pQ, 32, g4, be4, 8192.0, ss4, 512);
  bn_pool<true><<<4096, 256, 0, stream>>>(bufY, ss4, 512, 3, 3, 9, 32, p4T);

  // FC1 (relu, outputs [o][n] for FC2), FC2 (writes d_out [n][1000])
  fc_kernel<32768><<<1024, 256, 0, stream>>>(p4T, c1, dst + 16, 33554432.0, fb1, 1, fc1T,
                                             nullptr, 1024);
  fc_kernel<1024><<<1000, 256, 0, stream>>>(fc1T, c2, dst + 20, 1024000.0, fb2, 0, nullptr,
                                            (float*)d_out, 1000);
}

// Round 5
// 1494.173 us; speedup vs baseline: 27.3261x; 1.6280x over previous
//
#include <hip/hip_runtime.h>
#include <hip/hip_bf16.h>
#include <stdint.h>

#define DEV __device__ __forceinline__

typedef __bf16 bf16x8 __attribute__((ext_vector_type(8)));
typedef float f32x4 __attribute__((ext_vector_type(4)));
typedef unsigned short us8 __attribute__((ext_vector_type(8)));

DEV unsigned short f2us(float f) {
  __hip_bfloat16 h = __float2bfloat16(f);
  unsigned short u;
  __builtin_memcpy(&u, &h, 2);
  return u;
}

DEV double wave_reduce_d(double v) {
#pragma unroll
  for (int off = 32; off > 0; off >>= 1) v += __shfl_down(v, off);
  return v;
}

// 256-thread block reduce (double); result valid on thread 0 only.
DEV double dbl_block_reduce(double v, double* lds) {
  v = wave_reduce_d(v);
  int lane = threadIdx.x & 63, w = threadIdx.x >> 6;
  if (lane == 0) lds[w] = v;
  __syncthreads();
  double r = 0.0;
  if (threadIdx.x == 0) r = lds[0] + lds[1] + lds[2] + lds[3];
  __syncthreads();
  return r;
}

// ---------------- ternarize: fp64 stats ----------------
__global__ __launch_bounds__(256) void tern_abs_sum(const float* __restrict__ w, int n,
                                                    double* __restrict__ st) {
  __shared__ double lds[4];
  double s = 0.0;
  for (int i = blockIdx.x * 256 + threadIdx.x; i < n; i += gridDim.x * 256)
    s += fabs((double)w[i]);
  s = dbl_block_reduce(s, lds);
  if (threadIdx.x == 0) atomicAdd(st, s);
}

__global__ __launch_bounds__(256) void tern_masked(const float* __restrict__ w, int n,
                                                   double* __restrict__ st) {
  __shared__ double lds[4];
  const double delta = 0.7 * st[0] / (double)n;
  double ms = 0.0, cnt = 0.0;
  for (int i = blockIdx.x * 256 + threadIdx.x; i < n; i += gridDim.x * 256) {
    double a = fabs((double)w[i]);
    if (a > delta) { ms += a; cnt += 1.0; }
  }
  ms = dbl_block_reduce(ms, lds);
  cnt = dbl_block_reduce(cnt, lds);
  if (threadIdx.x == 0) { atomicAdd(st + 1, ms); atomicAdd(st + 2, cnt); }
}

DEV float tern_alpha_d(const double* st, double n) {
  double cnt = st[2];
  return (float)(cnt > 0.0 ? st[1] / fmax(cnt, 1.0) : st[0] / n);
}
DEV double tern_alpha_dd(const double* st, double n) {
  double cnt = st[2];
  return cnt > 0.0 ? st[1] / fmax(cnt, 1.0) : st[0] / n;
}

// conv1 weights -> ternarized fp32 [ci*9+tap][cout] (alpha baked in)
__global__ __launch_bounds__(256) void tern_write_conv(const float* __restrict__ w,
                                                       const double* __restrict__ st, int total,
                                                       int cin9, int COUT,
                                                       float* __restrict__ out) {
  int i = blockIdx.x * 256 + threadIdx.x;
  if (i >= total) return;
  double delta = 0.7 * st[0] / (double)total;
  float alpha = tern_alpha_d(st, (double)total);
  double v = (double)w[i];
  float r = v > delta ? alpha : (v < -delta ? -alpha : 0.f);
  int o = i / cin9;
  int rr = i - o * cin9;
  out[(size_t)rr * COUT + o] = r;
}

// conv2-4 weights -> bf16 codes {-1,0,+1} (exact), layout [cout][k= tap*CIN+ci] (tap-major K)
__global__ __launch_bounds__(256) void tern_write_convb(const float* __restrict__ w,
                                                        const double* __restrict__ st, int total,
                                                        int CIN, unsigned short* __restrict__ out) {
  int i = blockIdx.x * 256 + threadIdx.x;
  if (i >= total) return;
  double delta = 0.7 * st[0] / (double)total;
  double v = (double)w[i];
  float code = v > delta ? 1.f : (v < -delta ? -1.f : 0.f);
  int cin9 = CIN * 9;
  int o = i / cin9, rem = i - o * cin9;
  int ci = rem / 9, tap = rem - ci * 9;
  out[(size_t)o * cin9 + tap * CIN + ci] = f2us(code);
}

// fc weights -> int8 codes
__global__ __launch_bounds__(256) void tern_write_code(const float* __restrict__ w,
                                                       const double* __restrict__ st, int total,
                                                       int8_t* __restrict__ out) {
  int i = blockIdx.x * 256 + threadIdx.x;
  if (i >= total) return;
  double delta = 0.7 * st[0] / (double)total;
  double v = (double)w[i];
  out[i] = (int8_t)((v > delta) ? 1 : ((v < -delta) ? -1 : 0));
}

// ---------------- BN reduce+finalize ----------------
// plain (layer 1: stats are of y = conv+bias directly)
__global__ __launch_bounds__(256) void bn_reduce_fin(const double* __restrict__ pS,
                                                     const double* __restrict__ pQ, int P,
                                                     const float* __restrict__ g,
                                                     const float* __restrict__ be, double M,
                                                     float* __restrict__ scsh, int C) {
  __shared__ double lds[4];
  const int c = blockIdx.x;
  double s = 0.0, q = 0.0;
  for (int p = threadIdx.x; p < P; p += 256) {
    s += pS[(size_t)c * P + p];
    q += pQ[(size_t)c * P + p];
  }
  s = dbl_block_reduce(s, lds);
  q = dbl_block_reduce(q, lds);
  if (threadIdx.x == 0) {
    double mean = s / M;
    double var = q / M - mean * mean;
    double sc = (double)g[c] / sqrt(var + 1e-5);
    scsh[c] = (float)sc;
    scsh[C + c] = (float)((double)be[c] - mean * sc);
  }
}

// alpha-folded (layers 2-4): stats are of z (code-conv); y = alpha*z + b per channel.
// mean_y = alpha*mz + b, var_y = alpha^2*vz  =>  sc_z = g*alpha/sqrt(alpha^2*vz+eps),
// sh_z = be - mz*sc_z. Bias b cancels exactly.
__global__ __launch_bounds__(256) void bn_fin_alpha(const double* __restrict__ pS,
                                                    const double* __restrict__ pQ, int P,
                                                    const float* __restrict__ g,
                                                    const float* __restrict__ be, double M,
                                                    const double* __restrict__ st, double nels,
                                                    float* __restrict__ scsh, int C) {
  __shared__ double lds[4];
  const int c = blockIdx.x;
  double s = 0.0, q = 0.0;
  for (int p = threadIdx.x; p < P; p += 256) {
    s += pS[(size_t)c * P + p];
    q += pQ[(size_t)c * P + p];
  }
  s = dbl_block_reduce(s, lds);
  q = dbl_block_reduce(q, lds);
  if (threadIdx.x == 0) {
    double al = tern_alpha_dd(st, nels);
    double mean = s / M;
    double var = q / M - mean * mean;
    double sc = (double)g[c] * al / sqrt(al * al * var + 1e-5);
    scsh[c] = (float)sc;
    scsh[C + c] = (float)((double)be[c] - mean * sc);
  }
}

// ---------------- layer 1 (3->64, 128x128): fp32, recomputed ----------------
DEV void conv1_acc_body(const float* __restrict__ in, const float* __restrict__ wt,
                        const float* __restrict__ b, int tX, int tY, int g0, int n,
                        float (&smem)[3][18][18], float (&acc)[16]) {
  const int px = threadIdx.x & 15, py = threadIdx.x >> 4;
  const int tx0 = tX * 16 - 1, ty0 = tY * 16 - 1;
  for (int idx = threadIdx.x; idx < 3 * 324; idx += 256) {
    int ck = idx / 324, rem = idx - ck * 324;
    int yy = rem / 18, xx = rem - yy * 18;
    int gy = ty0 + yy, gx = tx0 + xx;
    float v = 0.f;
    if ((unsigned)gy < 128u && (unsigned)gx < 128u)
      v = in[(((size_t)n * 3 + ck) * 128 + gy) * 128 + gx];
    smem[ck][yy][xx] = v;
  }
  __syncthreads();
#pragma unroll
  for (int g = 0; g < 16; ++g) acc[g] = b[g0 + g];
#pragma unroll
  for (int ck = 0; ck < 3; ++ck) {
    const float* wrow = wt + (size_t)(ck * 9) * 64 + g0;
#pragma unroll
    for (int dy = 0; dy < 3; ++dy) {
#pragma unroll
      for (int dx = 0; dx < 3; ++dx) {
        float xv = smem[ck][py + dy][px + dx];
        const float* wp = wrow + (dy * 3 + dx) * 64;
#pragma unroll
        for (int g = 0; g < 16; ++g) acc[g] = fmaf(xv, wp[g], acc[g]);
      }
    }
  }
}

__global__ __launch_bounds__(256) void conv1_stats(const float* __restrict__ in,
                                                   const float* __restrict__ wt,
                                                   const float* __restrict__ b,
                                                   double* __restrict__ pS,
                                                   double* __restrict__ pQ) {
  __shared__ float smem[3][18][18];
  __shared__ double ldsS[4][16], ldsQ[4][16];
  const int tX = blockIdx.x & 7, tY = blockIdx.x >> 3;
  const int g0 = blockIdx.y * 16, n = blockIdx.z;
  float acc[16];
  conv1_acc_body(in, wt, b, tX, tY, g0, n, smem, acc);
  const int lane = threadIdx.x & 63, w = threadIdx.x >> 6;
#pragma unroll
  for (int g = 0; g < 16; ++g) {
    double s = wave_reduce_d((double)acc[g]);
    double q = wave_reduce_d((double)acc[g] * (double)acc[g]);
    if (lane == 0) { ldsS[w][g] = s; ldsQ[w][g] = q; }
  }
  __syncthreads();
  const int p = n * 64 + blockIdx.x;  // P = 2048
  if (threadIdx.x < 16) {
    int g = threadIdx.x;
    pS[(size_t)(g0 + g) * 2048 + p] = ldsS[0][g] + ldsS[1][g] + ldsS[2][g] + ldsS[3][g];
  } else if (threadIdx.x < 32) {
    int g = threadIdx.x - 16;
    pQ[(size_t)(g0 + g) * 2048 + p] = ldsQ[0][g] + ldsQ[1][g] + ldsQ[2][g] + ldsQ[3][g];
  }
}

__global__ __launch_bounds__(256) void conv1_pool(const float* __restrict__ in,
                                                  const float* __restrict__ wt,
                                                  const float* __restrict__ b,
                                                  const float* __restrict__ scsh,
                                                  float* __restrict__ out) {
  __shared__ float smem[3][18][18];
  __shared__ float pool[4][16][16];
  const int tX = blockIdx.x & 7, tY = blockIdx.x >> 3;
  const int g0 = blockIdx.y * 16, n = blockIdx.z;
  float acc[16];
  conv1_acc_body(in, wt, b, tX, tY, g0, n, smem, acc);
  const int px = threadIdx.x & 15, py = threadIdx.x >> 4;
  for (int chunk = 0; chunk < 4; ++chunk) {
    __syncthreads();
#pragma unroll
    for (int gl = 0; gl < 4; ++gl) {
      int g = chunk * 4 + gl, c = g0 + g;
      pool[gl][py][px] = fmaxf(fmaf(acc[g], scsh[c], scsh[64 + c]), 0.f);
    }
    __syncthreads();
    int gl = threadIdx.x >> 6, r = threadIdx.x & 63, qy = r >> 3, qx = r & 7;
    float m = fmaxf(fmaxf(pool[gl][2 * qy][2 * qx], pool[gl][2 * qy][2 * qx + 1]),
                    fmaxf(pool[gl][2 * qy + 1][2 * qx], pool[gl][2 * qy + 1][2 * qx + 1]));
    int c = g0 + chunk * 4 + gl;
    out[(((size_t)n * 64 + c) * 64 + tY * 8 + qy) * 64 + tX * 8 + qx] = m;
  }
}

// ---------------- NCHW fp32 -> NHWC fp32 transpose (LDS-tiled) ----------------
__global__ __launch_bounds__(256) void nchw2nhwc(const float* __restrict__ in,
                                                 float* __restrict__ out, int C, int HW) {
  __shared__ float t[64][65];
  const int c0 = blockIdx.x * 64, p0 = blockIdx.y * 64, n = blockIdx.z;
  const float* src = in + (size_t)n * C * HW;
  for (int u = threadIdx.x; u < 4096; u += 256) {
    int cl = u >> 6, pl = u & 63;
    t[cl][pl] = src[(size_t)(c0 + cl) * HW + p0 + pl];
  }
  __syncthreads();
  float* dst = out + (size_t)n * HW * C;
  for (int u = threadIdx.x; u < 4096; u += 256) {
    int pl = u >> 6, cl = u & 63;
    dst[(size_t)(p0 + pl) * C + c0 + cl] = t[cl][pl];
  }
}

// ---------------- MFMA implicit-GEMM conv 3x3 (layers 2-4) ----------------
// in: NHWC fp32; weights: bf16 codes [cout][k=tap*CIN+ci]; out z: NCHW fp32 + fp64 BN partials.
// Activations split hi/lo bf16 (x = hi + lo) -> two MFMAs, near-fp32 exact.
// Block: 4 waves; wave = 32 couts (2 MFMA groups); pixel tile 16 wide x PH high.
template <int CIN, int H, int PH>
__global__ __launch_bounds__(256) void conv_mfma(const float* __restrict__ inNHWC,
                                                 const unsigned short* __restrict__ wT,
                                                 float* __restrict__ z, int COUT,
                                                 double* __restrict__ pS,
                                                 double* __restrict__ pQ, int P) {
  constexpr int W = H;
  constexpr int TX = W / 16;
  constexpr int K = 9 * CIN;
  constexpr int CH = CIN / 32;
  constexpr int NU = (PH + 2) * 18 * 4;  // 16B staging units per ci-chunk
  __shared__ unsigned short hiT[(PH + 2) * 18 * 32];
  __shared__ unsigned short loT[(PH + 2) * 18 * 32];

  const int bx = blockIdx.x;
  const int tX = bx % TX, tY = bx / TX;
  const int n = blockIdx.z;
  const int wave = threadIdx.x >> 6, lane = threadIdx.x & 63;
  const int l15 = lane & 15, l4 = lane >> 4;
  const int wvCout = blockIdx.y * 128 + wave * 32;
  const int x0 = tX * 16, y0 = tY * PH;

  f32x4 acc[2][PH];
#pragma unroll
  for (int g = 0; g < 2; ++g)
#pragma unroll
    for (int pt = 0; pt < PH; ++pt) acc[g][pt] = (f32x4){0.f, 0.f, 0.f, 0.f};

#pragma unroll 1
  for (int cc = 0; cc < CH; ++cc) {
    __syncthreads();
    // stage (PH+2) x 18 x 32ci tile, hi/lo bf16, zero-padded at borders
    for (int u = threadIdx.x; u < NU; u += 256) {
      int q = u & 3, rem = u >> 2;
      int xx = rem % 18, yy = rem / 18;
      int gy = y0 + yy - 1, gx = x0 + xx - 1;
      us8 hv = (us8)0, lv = (us8)0;
      if ((unsigned)gy < (unsigned)H && (unsigned)gx < (unsigned)W) {
        const float* src = inNHWC + (((size_t)(n * H + gy) * W + gx) * CIN + cc * 32 + q * 8);
        float4 a = *(const float4*)src;
        float4 c = *(const float4*)(src + 4);
        float f[8] = {a.x, a.y, a.z, a.w, c.x, c.y, c.z, c.w};
#pragma unroll
        for (int j = 0; j < 8; ++j) {
          __hip_bfloat16 h = __float2bfloat16(f[j]);
          unsigned short hu;
          __builtin_memcpy(&hu, &h, 2);
          hv[j] = hu;
          lv[j] = f2us(f[j] - __bfloat162float(h));
        }
      }
      int off = (rem << 5) + (q << 3);  // (yy*18+xx)*32 + q*8
      *(us8*)(hiT + off) = hv;
      *(us8*)(loT + off) = lv;
    }
    __syncthreads();

#pragma unroll
    for (int tap = 0; tap < 9; ++tap) {
      const int dy = tap / 3, dx = tap % 3;
      bf16x8 aF[2];
#pragma unroll
      for (int g = 0; g < 2; ++g) {
        int co = wvCout + g * 16 + l15;
        aF[g] = *(const bf16x8*)(wT + (size_t)co * K + tap * CIN + cc * 32 + l4 * 8);
      }
      const int tb = (dy * 18 + dx + l15) * 32 + l4 * 8;
#pragma unroll
      for (int pt = 0; pt < PH; ++pt) {
        int off = tb + pt * (18 * 32);
        bf16x8 bh = *(const bf16x8*)(hiT + off);
        bf16x8 bl = *(const bf16x8*)(loT + off);
        acc[0][pt] = __builtin_amdgcn_mfma_f32_16x16x32_bf16(aF[0], bh, acc[0][pt], 0, 0, 0);
        acc[1][pt] = __builtin_amdgcn_mfma_f32_16x16x32_bf16(aF[1], bh, acc[1][pt], 0, 0, 0);
        acc[0][pt] = __builtin_amdgcn_mfma_f32_16x16x32_bf16(aF[0], bl, acc[0][pt], 0, 0, 0);
        acc[1][pt] = __builtin_amdgcn_mfma_f32_16x16x32_bf16(aF[1], bl, acc[1][pt], 0, 0, 0);
      }
    }
  }

  // epilogue: z store (NCHW fp32) + fused fp64 BN partials
  const int p = n * gridDim.x + bx;
#pragma unroll
  for (int g = 0; g < 2; ++g) {
    float sv[4] = {0, 0, 0, 0}, qv[4] = {0, 0, 0, 0};
#pragma unroll
    for (int pt = 0; pt < PH; ++pt) {
      int oy = y0 + pt;
#pragma unroll
      for (int r = 0; r < 4; ++r) {
        float v = acc[g][pt][r];
        int co = wvCout + g * 16 + l4 * 4 + r;
        z[(((size_t)n * COUT + co) * H + oy) * W + x0 + l15] = v;
        sv[r] += v;
        qv[r] = fmaf(v, v, qv[r]);
      }
    }
#pragma unroll
    for (int r = 0; r < 4; ++r) {
#pragma unroll
      for (int m = 1; m < 16; m <<= 1) {
        sv[r] += __shfl_xor(sv[r], m);
        qv[r] += __shfl_xor(qv[r], m);
      }
    }
    if (l15 == 0) {
#pragma unroll
      for (int r = 0; r < 4; ++r) {
        int co = wvCout + g * 16 + l4 * 4 + r;
        pS[(size_t)co * P + p] = (double)sv[r];
        pQ[(size_t)co * P + p] = (double)qv[r];
      }
    }
  }
}

// ---------------- fused norm+relu+pool (fp32 z in, NCHW out or [k][n] out) -------------
template <bool TRANS>
__global__ __launch_bounds__(256) void bn_pool(const float* __restrict__ y,
                                               const float* __restrict__ scsh, int C, int lw,
                                               int lh, int lc, int N, float* __restrict__ out) {
  const int Wo = 1 << lw, Ho = 1 << lh;
  const int total = (N << lc) << (lw + lh);
  const int Wrow = 1 << (lw + 1);
  for (int i = blockIdx.x * 256 + threadIdx.x; i < total; i += gridDim.x * 256) {
    int wo = i & (Wo - 1);
    int ho = (i >> lw) & (Ho - 1);
    int c = (i >> (lw + lh)) & (C - 1);
    int n = i >> (lw + lh + lc);
    float sc = scsh[c], sh = scsh[C + c];
    size_t idx = (((((size_t)n * C + c) << (lh + 1)) + (ho << 1)) << (lw + 1)) + (wo << 1);
    float z00 = fmaxf(fmaf(y[idx], sc, sh), 0.f);
    float z01 = fmaxf(fmaf(y[idx + 1], sc, sh), 0.f);
    float z10 = fmaxf(fmaf(y[idx + Wrow], sc, sh), 0.f);
    float z11 = fmaxf(fmaf(y[idx + Wrow + 1], sc, sh), 0.f);
    float m = fmaxf(fmaxf(z00, z01), fmaxf(z10, z11));
    if (TRANS) {
      int k = (((c << lh) + ho) << lw) + wo;
      out[(size_t)k * 32 + n] = m;
    } else {
      out[i] = m;
    }
  }
}

// ---------------- FC layers (ternary codes, alpha in epilogue) ----------------
template <int K>
__global__ __launch_bounds__(256) void fc_kernel(const float* __restrict__ pT,
                                                 const int8_t* __restrict__ codes,
                                                 const double* __restrict__ st, double nels,
                                                 const float* __restrict__ fb, int relu,
                                                 float* __restrict__ outT,
                                                 float* __restrict__ outN, int OUT) {
  const int o = blockIdx.x;
  float acc[32];
#pragma unroll
  for (int j = 0; j < 32; ++j) acc[j] = 0.f;
  const int8_t* crow = codes + (size_t)o * K;
  for (int k = threadIdx.x; k < K; k += 256) {
    int cv = crow[k];
    if (cv != 0) {
      float c = (float)cv;
      const float4* pv = (const float4*)(pT + ((size_t)k << 5));
#pragma unroll
      for (int j = 0; j < 8; ++j) {
        float4 v = pv[j];
        acc[4 * j + 0] = fmaf(c, v.x, acc[4 * j + 0]);
        acc[4 * j + 1] = fmaf(c, v.y, acc[4 * j + 1]);
        acc[4 * j + 2] = fmaf(c, v.z, acc[4 * j + 2]);
        acc[4 * j + 3] = fmaf(c, v.w, acc[4 * j + 3]);
      }
    }
  }
#pragma unroll
  for (int j = 0; j < 32; ++j) {
#pragma unroll
    for (int off = 32; off > 0; off >>= 1) acc[j] += __shfl_down(acc[j], off);
  }
  __shared__ float red[4][32];
  int lane = threadIdx.x & 63, wv = threadIdx.x >> 6;
  if (lane == 0) {
#pragma unroll
    for (int j = 0; j < 32; ++j) red[wv][j] = acc[j];
  }
  __syncthreads();
  if (threadIdx.x < 32) {
    int n = threadIdx.x;
    float alpha = tern_alpha_d(st, nels);
    float t = (red[0][n] + red[1][n] + red[2][n] + red[3][n]) * alpha + fb[o];
    if (relu) t = fmaxf(t, 0.f);
    if (outT) outT[(size_t)o * 32 + n] = t;
    if (outN) outN[(size_t)n * OUT + o] = t;
  }
}

// ---------------- host ----------------
extern "C" void kernel_launch(void* const* d_in, const int* in_sizes, int n_in, void* d_out,
                              int out_size, void* d_ws, size_t ws_size, hipStream_t stream) {
  const float* x = (const float*)d_in[0];
  const float* w1 = (const float*)d_in[1];
  const float* b1 = (const float*)d_in[2];
  const float* g1 = (const float*)d_in[3];
  const float* be1 = (const float*)d_in[4];
  const float* w2 = (const float*)d_in[5];
  const float* g2 = (const float*)d_in[7];
  const float* be2 = (const float*)d_in[8];
  const float* w3 = (const float*)d_in[9];
  const float* g3 = (const float*)d_in[11];
  const float* be3 = (const float*)d_in[12];
  const float* w4 = (const float*)d_in[13];
  const float* g4 = (const float*)d_in[15];
  const float* be4 = (const float*)d_in[16];
  const float* fw1 = (const float*)d_in[17];
  const float* fb1 = (const float*)d_in[18];
  const float* fw2 = (const float*)d_in[19];
  const float* fb2 = (const float*)d_in[20];
  // b2..b4 cancel exactly under training-mode BN (folded analytically); b1 kept in conv1.
  (void)in_sizes; (void)n_in; (void)out_size; (void)ws_size;

  char* ws = (char*)d_ws;
  size_t off = 0;
  auto alloc = [&](size_t bytes) {
    size_t o = off;
    off += (bytes + 255) & ~(size_t)255;
    return o;
  };
  float* tw1t = (float*)(ws + alloc((size_t)1728 * 4));            // [27][64] fp32
  unsigned short* wb2 = (unsigned short*)(ws + alloc((size_t)73728 * 2));    // [128][576]
  unsigned short* wb3 = (unsigned short*)(ws + alloc((size_t)294912 * 2));   // [256][1152]
  unsigned short* wb4 = (unsigned short*)(ws + alloc((size_t)1179648 * 2));  // [512][2304]
  int8_t* c2 = (int8_t*)(ws + alloc((size_t)1024000));
  double* dst = (double*)(ws + alloc((size_t)32 * 8));             // tern stats 6x4
  float* scsh = (float*)(ws + alloc((size_t)4096 * 4));
  double* pS = (double*)(ws + alloc((size_t)131072 * 8));
  double* pQ = (double*)(ws + alloc((size_t)131072 * 8));
  float* bufY = (float*)(ws + alloc((size_t)16777216 * 4));        // 67MB: z (L2-4)
  float* bufA = (float*)(ws + alloc((size_t)8388608 * 4));         // 33.5MB: pooled NCHW
  char* nhwc_c1 = ws + alloc((size_t)33554432);                    // NHWC fp32 / later c1 codes
  float* fc1T = (float*)(ws + alloc((size_t)32768 * 4));
  float* nhwc = (float*)nhwc_c1;
  int8_t* c1 = (int8_t*)nhwc_c1;  // written AFTER conv4 (last nhwc read)
  float* p4T = bufA + 4194304;    // [32768][32]; disjoint from pool3 (2.1M floats)
  // total ~140 MB (163 MB proven mapped in R1)

  hipMemsetAsync(dst, 0, 32 * 8, stream);

  struct TT { const float* w; int n; };
  TT ts[6] = {{w1, 1728},    {w2, 73728},     {w3, 294912},
              {w4, 1179648}, {fw1, 33554432}, {fw2, 1024000}};
  for (int t = 0; t < 6; ++t) {
    int blocks = (ts[t].n + 2047) / 2048;
    if (blocks > 4096) blocks = 4096;
    tern_abs_sum<<<blocks, 256, 0, stream>>>(ts[t].w, ts[t].n, dst + t * 4);
  }
  for (int t = 0; t < 6; ++t) {
    int blocks = (ts[t].n + 2047) / 2048;
    if (blocks > 4096) blocks = 4096;
    tern_masked<<<blocks, 256, 0, stream>>>(ts[t].w, ts[t].n, dst + t * 4);
  }
  tern_write_conv<<<7, 256, 0, stream>>>(w1, dst + 0, 1728, 27, 64, tw1t);
  tern_write_convb<<<288, 256, 0, stream>>>(w2, dst + 4, 73728, 64, wb2);
  tern_write_convb<<<1152, 256, 0, stream>>>(w3, dst + 8, 294912, 128, wb3);
  tern_write_convb<<<4608, 256, 0, stream>>>(w4, dst + 12, 1179648, 256, wb4);
  tern_write_code<<<4000, 256, 0, stream>>>(fw2, dst + 20, 1024000, c2);

  float* ss1 = scsh;
  float* ss2 = scsh + 128;
  float* ss3 = scsh + 512;
  float* ss4 = scsh + 1024;

  // Layer 1 (fp32 recompute path) -> pool1 NCHW in bufA -> NHWC fp32
  conv1_stats<<<dim3(64, 4, 32), 256, 0, stream>>>(x, tw1t, b1, pS, pQ);
  bn_reduce_fin<<<64, 256, 0, stream>>>(pS, pQ, 2048, g1, be1, 524288.0, ss1, 64);
  conv1_pool<<<dim3(64, 4, 32), 256, 0, stream>>>(x, tw1t, b1, ss1, bufA);
  nchw2nhwc<<<dim3(1, 64, 32), 256, 0, stream>>>(bufA, nhwc, 64, 4096);

  // Layer 2: MFMA conv (64->128 @64x64), z->bufY + BN partials
  conv_mfma<64, 64, 8><<<dim3(32, 1, 32), 256, 0, stream>>>(nhwc, wb2, bufY, 128, pS, pQ, 1024);
  bn_fin_alpha<<<128, 256, 0, stream>>>(pS, pQ, 1024, g2, be2, 131072.0, dst + 4, 73728.0, ss2,
                                        128);
  bn_pool<false><<<16384, 256, 0, stream>>>(bufY, ss2, 128, 5, 5, 7, 32, bufA);
  nchw2nhwc<<<dim3(2, 16, 32), 256, 0, stream>>>(bufA, nhwc, 128, 1024);

  // Layer 3: MFMA conv (128->256 @32x32)
  conv_mfma<128, 32, 4><<<dim3(16, 2, 32), 256, 0, stream>>>(nhwc, wb3, bufY, 256, pS, pQ, 512);
  bn_fin_alpha<<<256, 256, 0, stream>>>(pS, pQ, 512, g3, be3, 32768.0, dst + 8, 294912.0, ss3,
                                        256);
  bn_pool<false><<<8192, 256, 0, stream>>>(bufY, ss3, 256, 4, 4, 8, 32, bufA);
  nchw2nhwc<<<dim3(4, 4, 32), 256, 0, stream>>>(bufA, nhwc, 256, 256);

  // Layer 4: MFMA conv (256->512 @16x16)
  conv_mfma<256, 16, 2><<<dim3(8, 4, 32), 256, 0, stream>>>(nhwc, wb4, bufY, 512, pS, pQ, 256);
  bn_fin_alpha<<<512, 256, 0, stream>>>(pS, pQ, 256, g4, be4, 8192.0, dst + 12, 1179648.0, ss4,
                                        512);
  bn_pool<true><<<4096, 256, 0, stream>>>(bufY, ss4, 512, 3, 3, 9, 32, p4T);

  // c1 codes written now (nhwc no longer needed; same buffer)
  tern_write_code<<<131072, 256, 0, stream>>>(fw1, dst + 16, 33554432, c1);

  fc_kernel<32768><<<1024, 256, 0, stream>>>(p4T, c1, dst + 16, 33554432.0, fb1, 1, fc1T,
                                             nullptr, 1024);
  fc_kernel<1024><<<1000, 256, 0, stream>>>(fc1T, c2, dst + 20, 1024000.0, fb2, 0, nullptr,
                                            (float*)d_out, 1000);
}

// Round 6
// 1122.971 us; speedup vs baseline: 36.3588x; 1.3306x over previous
//
#include <hip/hip_runtime.h>
#include <hip/hip_bf16.h>
#include <stdint.h>

#define DEV __device__ __forceinline__

typedef __bf16 bf16x8 __attribute__((ext_vector_type(8)));
typedef float f32x4 __attribute__((ext_vector_type(4)));
typedef unsigned short us8 __attribute__((ext_vector_type(8)));

DEV unsigned short f2us(float f) {
  __hip_bfloat16 h = __float2bfloat16(f);
  unsigned short u;
  __builtin_memcpy(&u, &h, 2);
  return u;
}

DEV double wave_reduce_d(double v) {
#pragma unroll
  for (int off = 32; off > 0; off >>= 1) v += __shfl_down(v, off);
  return v;
}

DEV double dbl_block_reduce(double v, double* lds) {
  v = wave_reduce_d(v);
  int lane = threadIdx.x & 63, w = threadIdx.x >> 6;
  if (lane == 0) lds[w] = v;
  __syncthreads();
  double r = 0.0;
  if (threadIdx.x == 0) r = lds[0] + lds[1] + lds[2] + lds[3];
  __syncthreads();
  return r;
}

// ---------------- ternarize: fp64 stats ----------------
__global__ __launch_bounds__(256) void tern_abs_sum(const float* __restrict__ w, int n,
                                                    double* __restrict__ st) {
  __shared__ double lds[4];
  double s = 0.0;
  for (int i = blockIdx.x * 256 + threadIdx.x; i < n; i += gridDim.x * 256)
    s += fabs((double)w[i]);
  s = dbl_block_reduce(s, lds);
  if (threadIdx.x == 0) atomicAdd(st, s);
}

__global__ __launch_bounds__(256) void tern_masked(const float* __restrict__ w, int n,
                                                   double* __restrict__ st) {
  __shared__ double lds[4];
  const double delta = 0.7 * st[0] / (double)n;
  double ms = 0.0, cnt = 0.0;
  for (int i = blockIdx.x * 256 + threadIdx.x; i < n; i += gridDim.x * 256) {
    double a = fabs((double)w[i]);
    if (a > delta) { ms += a; cnt += 1.0; }
  }
  ms = dbl_block_reduce(ms, lds);
  cnt = dbl_block_reduce(cnt, lds);
  if (threadIdx.x == 0) { atomicAdd(st + 1, ms); atomicAdd(st + 2, cnt); }
}

DEV float tern_alpha_d(const double* st, double n) {
  double cnt = st[2];
  return (float)(cnt > 0.0 ? st[1] / fmax(cnt, 1.0) : st[0] / n);
}
DEV double tern_alpha_dd(const double* st, double n) {
  double cnt = st[2];
  return cnt > 0.0 ? st[1] / fmax(cnt, 1.0) : st[0] / n;
}

// conv2-4 weights -> bf16 codes {-1,0,+1}, layout [cout][k=tap*CIN+ci]
__global__ __launch_bounds__(256) void tern_write_convb(const float* __restrict__ w,
                                                        const double* __restrict__ st, int total,
                                                        int CIN, unsigned short* __restrict__ out) {
  int i = blockIdx.x * 256 + threadIdx.x;
  if (i >= total) return;
  double delta = 0.7 * st[0] / (double)total;
  double v = (double)w[i];
  float code = v > delta ? 1.f : (v < -delta ? -1.f : 0.f);
  int cin9 = CIN * 9;
  int o = i / cin9, rem = i - o * cin9;
  int ci = rem / 9, tap = rem - ci * 9;
  out[(size_t)o * cin9 + tap * CIN + ci] = f2us(code);
}

// conv1 weights (cin=3) -> bf16 codes padded to 32 ci: [64][k=tap*32+ci]
__global__ __launch_bounds__(256) void tern_write_convb_pad(const float* __restrict__ w,
                                                            const double* __restrict__ st,
                                                            unsigned short* __restrict__ out) {
  int i = blockIdx.x * 256 + threadIdx.x;
  if (i >= 64 * 288) return;
  int o = i / 288, rem = i - o * 288;
  int tap = rem >> 5, ci = rem & 31;
  float code = 0.f;
  if (ci < 3) {
    double delta = 0.7 * st[0] / 1728.0;
    double v = (double)w[(o * 3 + ci) * 9 + tap];
    code = v > delta ? 1.f : (v < -delta ? -1.f : 0.f);
  }
  out[i] = f2us(code);
}

// fc weights -> int8 codes (fc2)
__global__ __launch_bounds__(256) void tern_write_code(const float* __restrict__ w,
                                                       const double* __restrict__ st, int total,
                                                       int8_t* __restrict__ out) {
  int i = blockIdx.x * 256 + threadIdx.x;
  if (i >= total) return;
  double delta = 0.7 * st[0] / (double)total;
  double v = (double)w[i];
  out[i] = (int8_t)((v > delta) ? 1 : ((v < -delta) ? -1 : 0));
}

// fc1 weights -> bf16 codes [1024][32768]
__global__ __launch_bounds__(256) void tern_write_code_b16(const float* __restrict__ w,
                                                           const double* __restrict__ st,
                                                           int total,
                                                           unsigned short* __restrict__ out) {
  int i = blockIdx.x * 256 + threadIdx.x;
  if (i >= total) return;
  double delta = 0.7 * st[0] / (double)total;
  double v = (double)w[i];
  out[i] = f2us(v > delta ? 1.f : (v < -delta ? -1.f : 0.f));
}

// ---------------- BN finalize (alpha-folded; bias cancels exactly) ----------------
// stats are of z (code-conv); y = alpha*z + b. sc_z = g*alpha/sqrt(alpha^2*vz+eps),
// sh_z = be - mz*sc_z.
__global__ __launch_bounds__(256) void bn_fin_alpha(const double* __restrict__ pS,
                                                    const double* __restrict__ pQ, int P,
                                                    const float* __restrict__ g,
                                                    const float* __restrict__ be, double M,
                                                    const double* __restrict__ st, double nels,
                                                    float* __restrict__ scsh, int C) {
  __shared__ double lds[4];
  const int c = blockIdx.x;
  double s = 0.0, q = 0.0;
  for (int p = threadIdx.x; p < P; p += 256) {
    s += pS[(size_t)c * P + p];
    q += pQ[(size_t)c * P + p];
  }
  s = dbl_block_reduce(s, lds);
  q = dbl_block_reduce(q, lds);
  if (threadIdx.x == 0) {
    double al = tern_alpha_dd(st, nels);
    double mean = s / M;
    double var = q / M - mean * mean;
    double sc = (double)g[c] * al / sqrt(al * al * var + 1e-5);
    scsh[c] = (float)sc;
    scsh[C + c] = (float)((double)be[c] - mean * sc);
  }
}

// ---------------- x NCHW(3ch) -> NHWC padded to 32ch fp32 ----------------
__global__ __launch_bounds__(256) void pad32(const float* __restrict__ x,
                                             float* __restrict__ x32) {
  int i = blockIdx.x * 256 + threadIdx.x;  // 32*16384
  int px = i & 16383, n = i >> 14;
  float v0 = x[((size_t)n * 3 + 0) * 16384 + px];
  float v1 = x[((size_t)n * 3 + 1) * 16384 + px];
  float v2 = x[((size_t)n * 3 + 2) * 16384 + px];
  float4* dst = (float4*)(x32 + (size_t)i * 32);
  dst[0] = make_float4(v0, v1, v2, 0.f);
  float4 z = make_float4(0.f, 0.f, 0.f, 0.f);
#pragma unroll
  for (int j = 1; j < 8; ++j) dst[j] = z;
}

// ---------------- NCHW fp32 -> NHWC fp32 transpose ----------------
__global__ __launch_bounds__(256) void nchw2nhwc(const float* __restrict__ in,
                                                 float* __restrict__ out, int C, int HW) {
  __shared__ float t[64][65];
  const int c0 = blockIdx.x * 64, p0 = blockIdx.y * 64, n = blockIdx.z;
  const float* src = in + (size_t)n * C * HW;
  for (int u = threadIdx.x; u < 4096; u += 256) {
    int cl = u >> 6, pl = u & 63;
    t[cl][pl] = src[(size_t)(c0 + cl) * HW + p0 + pl];
  }
  __syncthreads();
  float* dst = out + (size_t)n * HW * C;
  for (int u = threadIdx.x; u < 4096; u += 256) {
    int pl = u >> 6, cl = u & 63;
    dst[(size_t)(p0 + pl) * C + c0 + cl] = t[cl][pl];
  }
}

// ---------------- MFMA implicit-GEMM conv body (hi/lo bf16 split) ----------------
// in NHWC fp32, weights bf16 codes [cout][k=tap*CIN+ci]. Wave computes 32 couts
// (2 MFMA groups) over a 16 x PH pixel tile.
template <int CIN, int H, int PH, int NW>
DEV void conv_body(const float* __restrict__ inNHWC, const unsigned short* __restrict__ wT,
                   int wvCout, int n, int x0, int y0, unsigned short* hiT, unsigned short* loT,
                   f32x4 (&acc)[2][PH]) {
  constexpr int W = H;
  constexpr int K = 9 * CIN;
  constexpr int CH = CIN / 32;
  constexpr int NU = (PH + 2) * 18 * 4;
  const int lane = threadIdx.x & 63;
  const int l15 = lane & 15, l4 = lane >> 4;

#pragma unroll
  for (int g = 0; g < 2; ++g)
#pragma unroll
    for (int pt = 0; pt < PH; ++pt) acc[g][pt] = (f32x4){0.f, 0.f, 0.f, 0.f};

#pragma unroll 1
  for (int cc = 0; cc < CH; ++cc) {
    __syncthreads();
    for (int u = threadIdx.x; u < NU; u += NW * 64) {
      int q = u & 3, rem = u >> 2;
      int xx = rem % 18, yy = rem / 18;
      int gy = y0 + yy - 1, gx = x0 + xx - 1;
      us8 hv = (us8)0, lv = (us8)0;
      if ((unsigned)gy < (unsigned)H && (unsigned)gx < (unsigned)W) {
        const float* src = inNHWC + (((size_t)(n * H + gy) * W + gx) * CIN + cc * 32 + q * 8);
        float4 a = *(const float4*)src;
        float4 c = *(const float4*)(src + 4);
        float f[8] = {a.x, a.y, a.z, a.w, c.x, c.y, c.z, c.w};
#pragma unroll
        for (int j = 0; j < 8; ++j) {
          __hip_bfloat16 h = __float2bfloat16(f[j]);
          unsigned short hu;
          __builtin_memcpy(&hu, &h, 2);
          hv[j] = hu;
          lv[j] = f2us(f[j] - __bfloat162float(h));
        }
      }
      int off = (rem << 5) + (q << 3);
      *(us8*)(hiT + off) = hv;
      *(us8*)(loT + off) = lv;
    }
    __syncthreads();

#pragma unroll
    for (int tap = 0; tap < 9; ++tap) {
      const int dy = tap / 3, dx = tap % 3;
      bf16x8 aF[2];
#pragma unroll
      for (int g = 0; g < 2; ++g) {
        int co = wvCout + g * 16 + l15;
        aF[g] = *(const bf16x8*)(wT + (size_t)co * K + tap * CIN + cc * 32 + l4 * 8);
      }
      const int tb = (dy * 18 + dx + l15) * 32 + l4 * 8;
#pragma unroll
      for (int pt = 0; pt < PH; ++pt) {
        int off = tb + pt * (18 * 32);
        bf16x8 bh = *(const bf16x8*)(hiT + off);
        bf16x8 bl = *(const bf16x8*)(loT + off);
        acc[0][pt] = __builtin_amdgcn_mfma_f32_16x16x32_bf16(aF[0], bh, acc[0][pt], 0, 0, 0);
        acc[1][pt] = __builtin_amdgcn_mfma_f32_16x16x32_bf16(aF[1], bh, acc[1][pt], 0, 0, 0);
        acc[0][pt] = __builtin_amdgcn_mfma_f32_16x16x32_bf16(aF[0], bl, acc[0][pt], 0, 0, 0);
        acc[1][pt] = __builtin_amdgcn_mfma_f32_16x16x32_bf16(aF[1], bl, acc[1][pt], 0, 0, 0);
      }
    }
  }
}

// fused fp64 BN partial write (per wave, 16-lane reduce)
template <int PH>
DEV void bn_partials(const f32x4 (&acc)[2][PH], int wvCout, int p, int P,
                     double* __restrict__ pS, double* __restrict__ pQ) {
  const int lane = threadIdx.x & 63;
  const int l15 = lane & 15, l4 = lane >> 4;
#pragma unroll
  for (int g = 0; g < 2; ++g) {
    float sv[4] = {0, 0, 0, 0}, qv[4] = {0, 0, 0, 0};
#pragma unroll
    for (int pt = 0; pt < PH; ++pt)
#pragma unroll
      for (int r = 0; r < 4; ++r) {
        float v = acc[g][pt][r];
        sv[r] += v;
        qv[r] = fmaf(v, v, qv[r]);
      }
#pragma unroll
    for (int r = 0; r < 4; ++r)
#pragma unroll
      for (int m = 1; m < 16; m <<= 1) {
        sv[r] += __shfl_xor(sv[r], m);
        qv[r] += __shfl_xor(qv[r], m);
      }
    if (l15 == 0) {
#pragma unroll
      for (int r = 0; r < 4; ++r) {
        int co = wvCout + g * 16 + l4 * 4 + r;
        pS[(size_t)co * P + p] = (double)sv[r];
        pQ[(size_t)co * P + p] = (double)qv[r];
      }
    }
  }
}

// layers 2-4: z store (NCHW fp32) + partials
template <int CIN, int H, int PH>
__global__ __launch_bounds__(256) void conv_mfma(const float* __restrict__ inNHWC,
                                                 const unsigned short* __restrict__ wT,
                                                 float* __restrict__ z, int COUT,
                                                 double* __restrict__ pS,
                                                 double* __restrict__ pQ, int P) {
  constexpr int W = H;
  constexpr int TX = W / 16;
  __shared__ unsigned short hiT[(PH + 2) * 18 * 32];
  __shared__ unsigned short loT[(PH + 2) * 18 * 32];
  const int bx = blockIdx.x;
  const int tX = bx % TX, tY = bx / TX;
  const int n = blockIdx.z;
  const int wave = threadIdx.x >> 6, lane = threadIdx.x & 63;
  const int l15 = lane & 15, l4 = lane >> 4;
  const int wvCout = blockIdx.y * 128 + wave * 32;
  const int x0 = tX * 16, y0 = tY * PH;
  f32x4 acc[2][PH];
  conv_body<CIN, H, PH, 4>(inNHWC, wT, wvCout, n, x0, y0, hiT, loT, acc);
#pragma unroll
  for (int g = 0; g < 2; ++g)
#pragma unroll
    for (int pt = 0; pt < PH; ++pt) {
      int oy = y0 + pt;
#pragma unroll
      for (int r = 0; r < 4; ++r) {
        int co = wvCout + g * 16 + l4 * 4 + r;
        z[(((size_t)n * COUT + co) * H + oy) * W + x0 + l15] = acc[g][pt][r];
      }
    }
  bn_partials<PH>(acc, wvCout, n * gridDim.x + bx, P, pS, pQ);
}

// layer 1 pass 1: partials only (z never materialized)
__global__ __launch_bounds__(128) void conv1_mfma_stats(const float* __restrict__ inNHWC,
                                                        const unsigned short* __restrict__ wT,
                                                        double* __restrict__ pS,
                                                        double* __restrict__ pQ) {
  __shared__ unsigned short hiT[10 * 18 * 32];
  __shared__ unsigned short loT[10 * 18 * 32];
  const int bx = blockIdx.x;
  const int tX = bx & 7, tY = bx >> 3;
  const int n = blockIdx.z;
  const int wave = threadIdx.x >> 6;
  const int wvCout = wave * 32;
  f32x4 acc[2][8];
  conv_body<32, 128, 8, 2>(inNHWC, wT, wvCout, n, tX * 16, tY * 8, hiT, loT, acc);
  bn_partials<8>(acc, wvCout, n * gridDim.x + bx, 4096, pS, pQ);
}

// layer 1 pass 2: recompute, BN+relu+2x2 maxpool, write pooled NHWC directly
__global__ __launch_bounds__(128) void conv1_mfma_pool(const float* __restrict__ inNHWC,
                                                       const unsigned short* __restrict__ wT,
                                                       const float* __restrict__ scsh,
                                                       float* __restrict__ outNHWC) {
  __shared__ unsigned short hiT[10 * 18 * 32];
  __shared__ unsigned short loT[10 * 18 * 32];
  const int bx = blockIdx.x;
  const int tX = bx & 7, tY = bx >> 3;
  const int n = blockIdx.z;
  const int wave = threadIdx.x >> 6, lane = threadIdx.x & 63;
  const int l15 = lane & 15, l4 = lane >> 4;
  const int wvCout = wave * 32;
  const int x0 = tX * 16, y0 = tY * 8;
  f32x4 acc[2][8];
  conv_body<32, 128, 8, 2>(inNHWC, wT, wvCout, n, x0, y0, hiT, loT, acc);
#pragma unroll
  for (int g = 0; g < 2; ++g) {
    const int co0 = wvCout + g * 16 + l4 * 4;
#pragma unroll
    for (int pt = 0; pt < 8; pt += 2) {
      float m[4];
#pragma unroll
      for (int r = 0; r < 4; ++r) {
        float sc = scsh[co0 + r], sh = scsh[64 + co0 + r];
        float v0 = fmaxf(fmaf(acc[g][pt][r], sc, sh), 0.f);
        float v1 = fmaxf(fmaf(acc[g][pt + 1][r], sc, sh), 0.f);
        float a = fmaxf(v0, v1);
        m[r] = fmaxf(a, __shfl_xor(a, 1));
      }
      if ((l15 & 1) == 0) {
        int oy = (y0 + pt) >> 1, ox = (x0 + l15) >> 1;
        *(float4*)(outNHWC + ((((size_t)n * 64 + oy) * 64 + ox) << 6) + co0) =
            make_float4(m[0], m[1], m[2], m[3]);
      }
    }
  }
}

// ---------------- fused norm+relu+pool (fp32 z in, NCHW out) ----------------
__global__ __launch_bounds__(256) void bn_pool(const float* __restrict__ y,
                                               const float* __restrict__ scsh, int C, int lw,
                                               int lh, int lc, int N, float* __restrict__ out) {
  const int Wo = 1 << lw, Ho = 1 << lh;
  const int total = (N << lc) << (lw + lh);
  const int Wrow = 1 << (lw + 1);
  for (int i = blockIdx.x * 256 + threadIdx.x; i < total; i += gridDim.x * 256) {
    int wo = i & (Wo - 1);
    int ho = (i >> lw) & (Ho - 1);
    int c = (i >> (lw + lh)) & (C - 1);
    int n = i >> (lw + lh + lc);
    float sc = scsh[c], sh = scsh[C + c];
    size_t idx = (((((size_t)n * C + c) << (lh + 1)) + (ho << 1)) << (lw + 1)) + (wo << 1);
    float z00 = fmaxf(fmaf(y[idx], sc, sh), 0.f);
    float z01 = fmaxf(fmaf(y[idx + 1], sc, sh), 0.f);
    float z10 = fmaxf(fmaf(y[idx + Wrow], sc, sh), 0.f);
    float z11 = fmaxf(fmaf(y[idx + Wrow + 1], sc, sh), 0.f);
    out[i] = fmaxf(fmaxf(z00, z01), fmaxf(z10, z11));
  }
}

// ---------------- pooled4 fp32 -> hi/lo bf16 ----------------
__global__ __launch_bounds__(256) void hilo_split(const float* __restrict__ in,
                                                  unsigned short* __restrict__ hi,
                                                  unsigned short* __restrict__ lo, int n) {
  int i = blockIdx.x * 256 + threadIdx.x;
  if (i >= n) return;
  float f = in[i];
  __hip_bfloat16 h = __float2bfloat16(f);
  unsigned short hu;
  __builtin_memcpy(&hu, &h, 2);
  hi[i] = hu;
  lo[i] = f2us(f - __bfloat162float(h));
}

// ---------------- FC1 as MFMA GEMM: [1024 o][32768 k] x [32 n][32768 k] ----------------
// grid (8 out-blocks, 4 k-slices); wave = 32 outs; partials fp32 [s][o][n]
__global__ __launch_bounds__(256) void fc1_mfma(const unsigned short* __restrict__ wT1,
                                                const unsigned short* __restrict__ aHi,
                                                const unsigned short* __restrict__ aLo,
                                                float* __restrict__ partial) {
  const int w = threadIdx.x >> 6, lane = threadIdx.x & 63;
  const int l15 = lane & 15, l4 = lane >> 4;
  const int o0 = blockIdx.x * 128 + w * 32;
  const int s = blockIdx.y;
  const int kbase = s * 8192 + l4 * 8;
  f32x4 acc[2][2];
#pragma unroll
  for (int g = 0; g < 2; ++g)
#pragma unroll
    for (int t = 0; t < 2; ++t) acc[g][t] = (f32x4){0.f, 0.f, 0.f, 0.f};
  for (int kc = 0; kc < 8192; kc += 32) {
    bf16x8 a0 = *(const bf16x8*)(wT1 + (size_t)(o0 + l15) * 32768 + kbase + kc);
    bf16x8 a1 = *(const bf16x8*)(wT1 + (size_t)(o0 + 16 + l15) * 32768 + kbase + kc);
    bf16x8 bh0 = *(const bf16x8*)(aHi + (size_t)l15 * 32768 + kbase + kc);
    bf16x8 bl0 = *(const bf16x8*)(aLo + (size_t)l15 * 32768 + kbase + kc);
    bf16x8 bh1 = *(const bf16x8*)(aHi + (size_t)(16 + l15) * 32768 + kbase + kc);
    bf16x8 bl1 = *(const bf16x8*)(aLo + (size_t)(16 + l15) * 32768 + kbase + kc);
    acc[0][0] = __builtin_amdgcn_mfma_f32_16x16x32_bf16(a0, bh0, acc[0][0], 0, 0, 0);
    acc[0][0] = __builtin_amdgcn_mfma_f32_16x16x32_bf16(a0, bl0, acc[0][0], 0, 0, 0);
    acc[1][0] = __builtin_amdgcn_mfma_f32_16x16x32_bf16(a1, bh0, acc[1][0], 0, 0, 0);
    acc[1][0] = __builtin_amdgcn_mfma_f32_16x16x32_bf16(a1, bl0, acc[1][0], 0, 0, 0);
    acc[0][1] = __builtin_amdgcn_mfma_f32_16x16x32_bf16(a0, bh1, acc[0][1], 0, 0, 0);
    acc[0][1] = __builtin_amdgcn_mfma_f32_16x16x32_bf16(a0, bl1, acc[0][1], 0, 0, 0);
    acc[1][1] = __builtin_amdgcn_mfma_f32_16x16x32_bf16(a1, bh1, acc[1][1], 0, 0, 0);
    acc[1][1] = __builtin_amdgcn_mfma_f32_16x16x32_bf16(a1, bl1, acc[1][1], 0, 0, 0);
  }
#pragma unroll
  for (int g = 0; g < 2; ++g)
#pragma unroll
    for (int t = 0; t < 2; ++t)
#pragma unroll
      for (int r = 0; r < 4; ++r) {
        int o = o0 + g * 16 + l4 * 4 + r;
        int n = t * 16 + l15;
        partial[((size_t)s * 1024 + o) * 32 + n] = acc[g][t][r];
      }
}

__global__ __launch_bounds__(256) void fc1_fin(const float* __restrict__ partial,
                                               const double* __restrict__ st,
                                               const float* __restrict__ fb,
                                               float* __restrict__ fc1T) {
  int i = blockIdx.x * 256 + threadIdx.x;  // 32768
  int o = i >> 5;
  float s = partial[i] + partial[32768 + i] + partial[65536 + i] + partial[98304 + i];
  float alpha = tern_alpha_d(st, 33554432.0);
  fc1T[i] = fmaxf(fmaf(s, alpha, fb[o]), 0.f);
}

// ---------------- FC2 (dumb row-parallel; tiny) ----------------
__global__ __launch_bounds__(256) void fc2_kernel(const float* __restrict__ xT,
                                                  const int8_t* __restrict__ codes,
                                                  const double* __restrict__ st,
                                                  const float* __restrict__ fb,
                                                  float* __restrict__ out) {
  const int o = blockIdx.x;
  float acc[32];
#pragma unroll
  for (int j = 0; j < 32; ++j) acc[j] = 0.f;
  const int8_t* crow = codes + (size_t)o * 1024;
  for (int k = threadIdx.x; k < 1024; k += 256) {
    int cv = crow[k];
    if (cv != 0) {
      float c = (float)cv;
      const float4* pv = (const float4*)(xT + ((size_t)k << 5));
#pragma unroll
      for (int j = 0; j < 8; ++j) {
        float4 v = pv[j];
        acc[4 * j + 0] = fmaf(c, v.x, acc[4 * j + 0]);
        acc[4 * j + 1] = fmaf(c, v.y, acc[4 * j + 1]);
        acc[4 * j + 2] = fmaf(c, v.z, acc[4 * j + 2]);
        acc[4 * j + 3] = fmaf(c, v.w, acc[4 * j + 3]);
      }
    }
  }
#pragma unroll
  for (int j = 0; j < 32; ++j) {
#pragma unroll
    for (int off = 32; off > 0; off >>= 1) acc[j] += __shfl_down(acc[j], off);
  }
  __shared__ float red[4][32];
  int lane = threadIdx.x & 63, wv = threadIdx.x >> 6;
  if (lane == 0) {
#pragma unroll
    for (int j = 0; j < 32; ++j) red[wv][j] = acc[j];
  }
  __syncthreads();
  if (threadIdx.x < 32) {
    int n = threadIdx.x;
    float alpha = tern_alpha_d(st, 1024000.0);
    out[(size_t)n * 1000 + o] = (red[0][n] + red[1][n] + red[2][n] + red[3][n]) * alpha + fb[o];
  }
}

// ---------------- host ----------------
extern "C" void kernel_launch(void* const* d_in, const int* in_sizes, int n_in, void* d_out,
                              int out_size, void* d_ws, size_t ws_size, hipStream_t stream) {
  const float* x = (const float*)d_in[0];
  const float* w1 = (const float*)d_in[1];
  const float* g1 = (const float*)d_in[3];
  const float* be1 = (const float*)d_in[4];
  const float* w2 = (const float*)d_in[5];
  const float* g2 = (const float*)d_in[7];
  const float* be2 = (const float*)d_in[8];
  const float* w3 = (const float*)d_in[9];
  const float* g3 = (const float*)d_in[11];
  const float* be3 = (const float*)d_in[12];
  const float* w4 = (const float*)d_in[13];
  const float* g4 = (const float*)d_in[15];
  const float* be4 = (const float*)d_in[16];
  const float* fw1 = (const float*)d_in[17];
  const float* fb1 = (const float*)d_in[18];
  const float* fw2 = (const float*)d_in[19];
  const float* fb2 = (const float*)d_in[20];
  // b1..b4 cancel exactly under training-mode BN (alpha-folded finalize).
  (void)in_sizes; (void)n_in; (void)out_size; (void)ws_size;

  char* ws = (char*)d_ws;
  size_t off = 0;
  auto alloc = [&](size_t bytes) {
    size_t o = off;
    off += (bytes + 255) & ~(size_t)255;
    return o;
  };
  unsigned short* wb1 = (unsigned short*)(ws + alloc((size_t)18432 * 2));    // [64][288]
  unsigned short* wb2 = (unsigned short*)(ws + alloc((size_t)73728 * 2));    // [128][576]
  unsigned short* wb3 = (unsigned short*)(ws + alloc((size_t)294912 * 2));   // [256][1152]
  unsigned short* wb4 = (unsigned short*)(ws + alloc((size_t)1179648 * 2));  // [512][2304]
  int8_t* c2 = (int8_t*)(ws + alloc((size_t)1024000));
  double* dst = (double*)(ws + alloc((size_t)32 * 8));
  float* scsh = (float*)(ws + alloc((size_t)4096 * 4));
  double* pS = (double*)(ws + alloc((size_t)262144 * 8));  // 2MB (layer1 P=4096 x 64c)
  double* pQ = (double*)(ws + alloc((size_t)262144 * 8));
  float* bufY = (float*)(ws + alloc((size_t)16777216 * 4));  // 67MB: x32pad / z / fc1 codes
  float* bufA = (float*)(ws + alloc((size_t)8388608 * 4));   // 33.5MB: pooled NCHW+NHWC
  unsigned short* actHi = (unsigned short*)(ws + alloc((size_t)1048576 * 2));
  unsigned short* actLo = (unsigned short*)(ws + alloc((size_t)1048576 * 2));
  float* fc1part = (float*)(ws + alloc((size_t)131072 * 4));  // [4][1024][32]
  float* fc1T = (float*)(ws + alloc((size_t)32768 * 4));      // [1024][32]
  float* x32 = bufY;                          // NHWC-32 input, dead after conv1
  unsigned short* wT1 = (unsigned short*)bufY;  // fc1 bf16 codes, written after z4 consumed
  float* bufA2 = bufA + 4194304;              // second half for NHWC copies
  // total ~111 MB (163 MB proven mapped in R1)

  hipMemsetAsync(dst, 0, 32 * 8, stream);

  struct TT { const float* w; int n; };
  TT ts[6] = {{w1, 1728},    {w2, 73728},     {w3, 294912},
              {w4, 1179648}, {fw1, 33554432}, {fw2, 1024000}};
  for (int t = 0; t < 6; ++t) {
    int blocks = (ts[t].n + 2047) / 2048;
    if (blocks > 4096) blocks = 4096;
    tern_abs_sum<<<blocks, 256, 0, stream>>>(ts[t].w, ts[t].n, dst + t * 4);
  }
  for (int t = 0; t < 6; ++t) {
    int blocks = (ts[t].n + 2047) / 2048;
    if (blocks > 4096) blocks = 4096;
    tern_masked<<<blocks, 256, 0, stream>>>(ts[t].w, ts[t].n, dst + t * 4);
  }
  tern_write_convb_pad<<<72, 256, 0, stream>>>(w1, dst + 0, wb1);
  tern_write_convb<<<288, 256, 0, stream>>>(w2, dst + 4, 73728, 64, wb2);
  tern_write_convb<<<1152, 256, 0, stream>>>(w3, dst + 8, 294912, 128, wb3);
  tern_write_convb<<<4608, 256, 0, stream>>>(w4, dst + 12, 1179648, 256, wb4);
  tern_write_code<<<4000, 256, 0, stream>>>(fw2, dst + 20, 1024000, c2);

  float* ss1 = scsh;
  float* ss2 = scsh + 128;
  float* ss3 = scsh + 512;
  float* ss4 = scsh + 1024;

  // Layer 1 via MFMA, two-pass recompute; pooled1 written directly as NHWC.
  pad32<<<2048, 256, 0, stream>>>(x, x32);
  conv1_mfma_stats<<<dim3(128, 1, 32), 128, 0, stream>>>(x32, wb1, pS, pQ);
  bn_fin_alpha<<<64, 256, 0, stream>>>(pS, pQ, 4096, g1, be1, 524288.0, dst + 0, 1728.0, ss1,
                                       64);
  conv1_mfma_pool<<<dim3(128, 1, 32), 128, 0, stream>>>(x32, wb1, ss1, bufA);

  // Layer 2: 64->128 @64x64 (reads pooled1 NHWC in bufA; z -> bufY)
  conv_mfma<64, 64, 8><<<dim3(32, 1, 32), 256, 0, stream>>>(bufA, wb2, bufY, 128, pS, pQ, 1024);
  bn_fin_alpha<<<128, 256, 0, stream>>>(pS, pQ, 1024, g2, be2, 131072.0, dst + 4, 73728.0, ss2,
                                        128);
  bn_pool<<<16384, 256, 0, stream>>>(bufY, ss2, 128, 5, 5, 7, 32, bufA);
  nchw2nhwc<<<dim3(2, 16, 32), 256, 0, stream>>>(bufA, bufA2, 128, 1024);

  // Layer 3: 128->256 @32x32
  conv_mfma<128, 32, 4><<<dim3(16, 2, 32), 256, 0, stream>>>(bufA2, wb3, bufY, 256, pS, pQ, 512);
  bn_fin_alpha<<<256, 256, 0, stream>>>(pS, pQ, 512, g3, be3, 32768.0, dst + 8, 294912.0, ss3,
                                        256);
  bn_pool<<<8192, 256, 0, stream>>>(bufY, ss3, 256, 4, 4, 8, 32, bufA);
  nchw2nhwc<<<dim3(4, 4, 32), 256, 0, stream>>>(bufA, bufA2, 256, 256);

  // Layer 4: 256->512 @16x16; pooled4 NCHW flat == [32][32768]
  conv_mfma<256, 16, 2><<<dim3(8, 4, 32), 256, 0, stream>>>(bufA2, wb4, bufY, 512, pS, pQ, 256);
  bn_fin_alpha<<<512, 256, 0, stream>>>(pS, pQ, 256, g4, be4, 8192.0, dst + 12, 1179648.0, ss4,
                                        512);
  bn_pool<<<4096, 256, 0, stream>>>(bufY, ss4, 512, 3, 3, 9, 32, bufA);
  hilo_split<<<4096, 256, 0, stream>>>(bufA, actHi, actLo, 1048576);

  // fc1 bf16 codes into bufY (z4 consumed), then MFMA GEMM + finalize
  tern_write_code_b16<<<131072, 256, 0, stream>>>(fw1, dst + 16, 33554432, wT1);
  fc1_mfma<<<dim3(8, 4), 256, 0, stream>>>(wT1, actHi, actLo, fc1part);
  fc1_fin<<<128, 256, 0, stream>>>(fc1part, dst + 16, fb1, fc1T);

  fc2_kernel<<<1000, 256, 0, stream>>>(fc1T, c2, dst + 20, fb2, (float*)d_out);
}

// Round 7
// 935.429 us; speedup vs baseline: 43.6483x; 1.2005x over previous
//
#include <hip/hip_runtime.h>
#include <hip/hip_bf16.h>
#include <stdint.h>

#define DEV __device__ __forceinline__

typedef __bf16 bf16x8 __attribute__((ext_vector_type(8)));
typedef float f32x4 __attribute__((ext_vector_type(4)));
typedef unsigned short us8 __attribute__((ext_vector_type(8)));
typedef int8_t i8x8 __attribute__((ext_vector_type(8)));

DEV unsigned short f2us(float f) {
  __hip_bfloat16 h = __float2bfloat16(f);
  unsigned short u;
  __builtin_memcpy(&u, &h, 2);
  return u;
}

DEV double wave_reduce_d(double v) {
#pragma unroll
  for (int off = 32; off > 0; off >>= 1) v += __shfl_down(v, off);
  return v;
}

DEV double dbl_block_reduce(double v, double* lds) {
  v = wave_reduce_d(v);
  int lane = threadIdx.x & 63, w = threadIdx.x >> 6;
  if (lane == 0) lds[w] = v;
  __syncthreads();
  double r = 0.0;
  if (threadIdx.x == 0) r = lds[0] + lds[1] + lds[2] + lds[3];
  __syncthreads();
  return r;
}

// ---------------- ternarize: fp64 stats, multi-tensor launches ----------------
struct TDesc { const float* w; int n; };
struct TDescs { TDesc d[6]; };

// one launch, all 6 tensors: sum|w| into st[slot*4]
__global__ __launch_bounds__(256) void tern_abs_all(TDescs td, double* __restrict__ st) {
  __shared__ double lds[4];
  const int t = blockIdx.y;
  const float* w = td.d[t].w;
  const int n = td.d[t].n;
  double s = 0.0;
  for (int i = blockIdx.x * 256 + threadIdx.x; i < n; i += gridDim.x * 256)
    s += fabs((double)w[i]);
  s = dbl_block_reduce(s, lds);
  if (threadIdx.x == 0 && s != 0.0) atomicAdd(st + t * 4, s);
}

struct MDesc { const float* w; int8_t* out; int n; };
struct MDescs { MDesc d[6]; };

// one launch, all 6 tensors: masked sum + count into st[slot*4+1,2]; optional int8
// codes write (codes depend on delta only, not alpha -> fused with this pass)
__global__ __launch_bounds__(256) void tern_masked_code_all(MDescs td, double* __restrict__ st) {
  __shared__ double lds[4];
  const int t = blockIdx.y;
  const float* w = td.d[t].w;
  int8_t* out = td.d[t].out;
  const int n = td.d[t].n;
  const double delta = 0.7 * st[t * 4] / (double)n;
  double ms = 0.0, cnt = 0.0;
  for (int i = blockIdx.x * 256 + threadIdx.x; i < n; i += gridDim.x * 256) {
    double v = (double)w[i];
    double a = fabs(v);
    if (a > delta) { ms += a; cnt += 1.0; }
    if (out) out[i] = (int8_t)((v > delta) ? 1 : ((v < -delta) ? -1 : 0));
  }
  ms = dbl_block_reduce(ms, lds);
  cnt = dbl_block_reduce(cnt, lds);
  if (threadIdx.x == 0 && cnt != 0.0) {
    atomicAdd(st + t * 4 + 1, ms);
    atomicAdd(st + t * 4 + 2, cnt);
  }
}

DEV float tern_alpha_d(const double* st, double n) {
  double cnt = st[2];
  return (float)(cnt > 0.0 ? st[1] / fmax(cnt, 1.0) : st[0] / n);
}
DEV double tern_alpha_dd(const double* st, double n) {
  double cnt = st[2];
  return cnt > 0.0 ? st[1] / fmax(cnt, 1.0) : st[0] / n;
}

// conv2-4 weights -> bf16 codes {-1,0,+1}, layout [cout][k=tap*CIN+ci]
__global__ __launch_bounds__(256) void tern_write_convb(const float* __restrict__ w,
                                                        const double* __restrict__ st, int total,
                                                        int CIN, unsigned short* __restrict__ out) {
  int i = blockIdx.x * 256 + threadIdx.x;
  if (i >= total) return;
  double delta = 0.7 * st[0] / (double)total;
  double v = (double)w[i];
  float code = v > delta ? 1.f : (v < -delta ? -1.f : 0.f);
  int cin9 = CIN * 9;
  int o = i / cin9, rem = i - o * cin9;
  int ci = rem / 9, tap = rem - ci * 9;
  out[(size_t)o * cin9 + tap * CIN + ci] = f2us(code);
}

// conv1 weights (cin=3) -> bf16 codes padded to 32 ci: [64][k=tap*32+ci]
__global__ __launch_bounds__(256) void tern_write_convb_pad(const float* __restrict__ w,
                                                            const double* __restrict__ st,
                                                            unsigned short* __restrict__ out) {
  int i = blockIdx.x * 256 + threadIdx.x;
  if (i >= 64 * 288) return;
  int o = i / 288, rem = i - o * 288;
  int tap = rem >> 5, ci = rem & 31;
  float code = 0.f;
  if (ci < 3) {
    double delta = 0.7 * st[0] / 1728.0;
    double v = (double)w[(o * 3 + ci) * 9 + tap];
    code = v > delta ? 1.f : (v < -delta ? -1.f : 0.f);
  }
  out[i] = f2us(code);
}

// ---------------- BN finalize (alpha-folded; bias cancels exactly) ----------------
__global__ __launch_bounds__(256) void bn_fin_alpha(const double* __restrict__ pS,
                                                    const double* __restrict__ pQ, int P,
                                                    const float* __restrict__ g,
                                                    const float* __restrict__ be, double M,
                                                    const double* __restrict__ st, double nels,
                                                    float* __restrict__ scsh, int C) {
  __shared__ double lds[4];
  const int c = blockIdx.x;
  double s = 0.0, q = 0.0;
  for (int p = threadIdx.x; p < P; p += 256) {
    s += pS[(size_t)c * P + p];
    q += pQ[(size_t)c * P + p];
  }
  s = dbl_block_reduce(s, lds);
  q = dbl_block_reduce(q, lds);
  if (threadIdx.x == 0) {
    double al = tern_alpha_dd(st, nels);
    double mean = s / M;
    double var = q / M - mean * mean;
    double sc = (double)g[c] * al / sqrt(al * al * var + 1e-5);
    scsh[c] = (float)sc;
    scsh[C + c] = (float)((double)be[c] - mean * sc);
  }
}

// ---------------- x NCHW(3ch) -> NHWC padded to 32ch fp32 ----------------
__global__ __launch_bounds__(256) void pad32(const float* __restrict__ x,
                                             float* __restrict__ x32) {
  int i = blockIdx.x * 256 + threadIdx.x;  // 32*16384
  int px = i & 16383, n = i >> 14;
  float v0 = x[((size_t)n * 3 + 0) * 16384 + px];
  float v1 = x[((size_t)n * 3 + 1) * 16384 + px];
  float v2 = x[((size_t)n * 3 + 2) * 16384 + px];
  float4* dst = (float4*)(x32 + (size_t)i * 32);
  dst[0] = make_float4(v0, v1, v2, 0.f);
  float4 z = make_float4(0.f, 0.f, 0.f, 0.f);
#pragma unroll
  for (int j = 1; j < 8; ++j) dst[j] = z;
}

// ---------------- NCHW fp32 -> NHWC fp32 transpose ----------------
__global__ __launch_bounds__(256) void nchw2nhwc(const float* __restrict__ in,
                                                 float* __restrict__ out, int C, int HW) {
  __shared__ float t[64][65];
  const int c0 = blockIdx.x * 64, p0 = blockIdx.y * 64, n = blockIdx.z;
  const float* src = in + (size_t)n * C * HW;
  for (int u = threadIdx.x; u < 4096; u += 256) {
    int cl = u >> 6, pl = u & 63;
    t[cl][pl] = src[(size_t)(c0 + cl) * HW + p0 + pl];
  }
  __syncthreads();
  float* dst = out + (size_t)n * HW * C;
  for (int u = threadIdx.x; u < 4096; u += 256) {
    int pl = u >> 6, cl = u & 63;
    dst[(size_t)(p0 + pl) * C + c0 + cl] = t[cl][pl];
  }
}

// ---------------- MFMA implicit-GEMM conv body (hi/lo bf16 split) ----------------
template <int CIN, int H, int PH, int NW>
DEV void conv_body(const float* __restrict__ inNHWC, const unsigned short* __restrict__ wT,
                   int wvCout, int n, int x0, int y0, unsigned short* hiT, unsigned short* loT,
                   f32x4 (&acc)[2][PH]) {
  constexpr int W = H;
  constexpr int K = 9 * CIN;
  constexpr int CH = CIN / 32;
  constexpr int NU = (PH + 2) * 18 * 4;
  const int lane = threadIdx.x & 63;
  const int l15 = lane & 15, l4 = lane >> 4;

#pragma unroll
  for (int g = 0; g < 2; ++g)
#pragma unroll
    for (int pt = 0; pt < PH; ++pt) acc[g][pt] = (f32x4){0.f, 0.f, 0.f, 0.f};

#pragma unroll 1
  for (int cc = 0; cc < CH; ++cc) {
    __syncthreads();
    for (int u = threadIdx.x; u < NU; u += NW * 64) {
      int q = u & 3, rem = u >> 2;
      int xx = rem % 18, yy = rem / 18;
      int gy = y0 + yy - 1, gx = x0 + xx - 1;
      us8 hv = (us8)0, lv = (us8)0;
      if ((unsigned)gy < (unsigned)H && (unsigned)gx < (unsigned)W) {
        const float* src = inNHWC + (((size_t)(n * H + gy) * W + gx) * CIN + cc * 32 + q * 8);
        float4 a = *(const float4*)src;
        float4 c = *(const float4*)(src + 4);
        float f[8] = {a.x, a.y, a.z, a.w, c.x, c.y, c.z, c.w};
#pragma unroll
        for (int j = 0; j < 8; ++j) {
          __hip_bfloat16 h = __float2bfloat16(f[j]);
          unsigned short hu;
          __builtin_memcpy(&hu, &h, 2);
          hv[j] = hu;
          lv[j] = f2us(f[j] - __bfloat162float(h));
        }
      }
      int off = (rem << 5) + (q << 3);
      *(us8*)(hiT + off) = hv;
      *(us8*)(loT + off) = lv;
    }
    __syncthreads();

#pragma unroll
    for (int tap = 0; tap < 9; ++tap) {
      const int dy = tap / 3, dx = tap % 3;
      bf16x8 aF[2];
#pragma unroll
      for (int g = 0; g < 2; ++g) {
        int co = wvCout + g * 16 + l15;
        aF[g] = *(const bf16x8*)(wT + (size_t)co * K + tap * CIN + cc * 32 + l4 * 8);
      }
      const int tb = (dy * 18 + dx + l15) * 32 + l4 * 8;
#pragma unroll
      for (int pt = 0; pt < PH; ++pt) {
        int off = tb + pt * (18 * 32);
        bf16x8 bh = *(const bf16x8*)(hiT + off);
        bf16x8 bl = *(const bf16x8*)(loT + off);
        acc[0][pt] = __builtin_amdgcn_mfma_f32_16x16x32_bf16(aF[0], bh, acc[0][pt], 0, 0, 0);
        acc[1][pt] = __builtin_amdgcn_mfma_f32_16x16x32_bf16(aF[1], bh, acc[1][pt], 0, 0, 0);
        acc[0][pt] = __builtin_amdgcn_mfma_f32_16x16x32_bf16(aF[0], bl, acc[0][pt], 0, 0, 0);
        acc[1][pt] = __builtin_amdgcn_mfma_f32_16x16x32_bf16(aF[1], bl, acc[1][pt], 0, 0, 0);
      }
    }
  }
}

// fused fp64 BN partial write (per wave, 16-lane reduce)
template <int PH>
DEV void bn_partials(const f32x4 (&acc)[2][PH], int wvCout, int p, int P,
                     double* __restrict__ pS, double* __restrict__ pQ) {
  const int lane = threadIdx.x & 63;
  const int l15 = lane & 15, l4 = lane >> 4;
#pragma unroll
  for (int g = 0; g < 2; ++g) {
    float sv[4] = {0, 0, 0, 0}, qv[4] = {0, 0, 0, 0};
#pragma unroll
    for (int pt = 0; pt < PH; ++pt)
#pragma unroll
      for (int r = 0; r < 4; ++r) {
        float v = acc[g][pt][r];
        sv[r] += v;
        qv[r] = fmaf(v, v, qv[r]);
      }
#pragma unroll
    for (int r = 0; r < 4; ++r)
#pragma unroll
      for (int m = 1; m < 16; m <<= 1) {
        sv[r] += __shfl_xor(sv[r], m);
        qv[r] += __shfl_xor(qv[r], m);
      }
    if (l15 == 0) {
#pragma unroll
      for (int r = 0; r < 4; ++r) {
        int co = wvCout + g * 16 + l4 * 4 + r;
        pS[(size_t)co * P + p] = (double)sv[r];
        pQ[(size_t)co * P + p] = (double)qv[r];
      }
    }
  }
}

// layers 2-4: z store (NCHW fp32) + partials
template <int CIN, int H, int PH>
__global__ __launch_bounds__(256) void conv_mfma(const float* __restrict__ inNHWC,
                                                 const unsigned short* __restrict__ wT,
                                                 float* __restrict__ z, int COUT,
                                                 double* __restrict__ pS,
                                                 double* __restrict__ pQ, int P) {
  constexpr int W = H;
  constexpr int TX = W / 16;
  __shared__ unsigned short hiT[(PH + 2) * 18 * 32];
  __shared__ unsigned short loT[(PH + 2) * 18 * 32];
  const int bx = blockIdx.x;
  const int tX = bx % TX, tY = bx / TX;
  const int n = blockIdx.z;
  const int wave = threadIdx.x >> 6, lane = threadIdx.x & 63;
  const int l15 = lane & 15, l4 = lane >> 4;
  const int wvCout = blockIdx.y * 128 + wave * 32;
  const int x0 = tX * 16, y0 = tY * PH;
  f32x4 acc[2][PH];
  conv_body<CIN, H, PH, 4>(inNHWC, wT, wvCout, n, x0, y0, hiT, loT, acc);
#pragma unroll
  for (int g = 0; g < 2; ++g)
#pragma unroll
    for (int pt = 0; pt < PH; ++pt) {
      int oy = y0 + pt;
#pragma unroll
      for (int r = 0; r < 4; ++r) {
        int co = wvCout + g * 16 + l4 * 4 + r;
        z[(((size_t)n * COUT + co) * H + oy) * W + x0 + l15] = acc[g][pt][r];
      }
    }
  bn_partials<PH>(acc, wvCout, n * gridDim.x + bx, P, pS, pQ);
}

// layer 1 pass 1: partials only (z never materialized)
__global__ __launch_bounds__(128) void conv1_mfma_stats(const float* __restrict__ inNHWC,
                                                        const unsigned short* __restrict__ wT,
                                                        double* __restrict__ pS,
                                                        double* __restrict__ pQ) {
  __shared__ unsigned short hiT[10 * 18 * 32];
  __shared__ unsigned short loT[10 * 18 * 32];
  const int bx = blockIdx.x;
  const int tX = bx & 7, tY = bx >> 3;
  const int n = blockIdx.z;
  const int wave = threadIdx.x >> 6;
  const int wvCout = wave * 32;
  f32x4 acc[2][8];
  conv_body<32, 128, 8, 2>(inNHWC, wT, wvCout, n, tX * 16, tY * 8, hiT, loT, acc);
  bn_partials<8>(acc, wvCout, n * gridDim.x + bx, 4096, pS, pQ);
}

// layer 1 pass 2: recompute, BN+relu+2x2 maxpool, write pooled NHWC directly
__global__ __launch_bounds__(128) void conv1_mfma_pool(const float* __restrict__ inNHWC,
                                                       const unsigned short* __restrict__ wT,
                                                       const float* __restrict__ scsh,
                                                       float* __restrict__ outNHWC) {
  __shared__ unsigned short hiT[10 * 18 * 32];
  __shared__ unsigned short loT[10 * 18 * 32];
  const int bx = blockIdx.x;
  const int tX = bx & 7, tY = bx >> 3;
  const int n = blockIdx.z;
  const int wave = threadIdx.x >> 6, lane = threadIdx.x & 63;
  const int l15 = lane & 15, l4 = lane >> 4;
  const int wvCout = wave * 32;
  const int x0 = tX * 16, y0 = tY * 8;
  f32x4 acc[2][8];
  conv_body<32, 128, 8, 2>(inNHWC, wT, wvCout, n, x0, y0, hiT, loT, acc);
#pragma unroll
  for (int g = 0; g < 2; ++g) {
    const int co0 = wvCout + g * 16 + l4 * 4;
#pragma unroll
    for (int pt = 0; pt < 8; pt += 2) {
      float m[4];
#pragma unroll
      for (int r = 0; r < 4; ++r) {
        float sc = scsh[co0 + r], sh = scsh[64 + co0 + r];
        float v0 = fmaxf(fmaf(acc[g][pt][r], sc, sh), 0.f);
        float v1 = fmaxf(fmaf(acc[g][pt + 1][r], sc, sh), 0.f);
        float a = fmaxf(v0, v1);
        m[r] = fmaxf(a, __shfl_xor(a, 1));
      }
      if ((l15 & 1) == 0) {
        int oy = (y0 + pt) >> 1, ox = (x0 + l15) >> 1;
        *(float4*)(outNHWC + ((((size_t)n * 64 + oy) * 64 + ox) << 6) + co0) =
            make_float4(m[0], m[1], m[2], m[3]);
      }
    }
  }
}

// ---------------- fused norm+relu+pool (fp32 z in, NCHW out) ----------------
__global__ __launch_bounds__(256) void bn_pool(const float* __restrict__ y,
                                               const float* __restrict__ scsh, int C, int lw,
                                               int lh, int lc, int N, float* __restrict__ out) {
  const int Wo = 1 << lw, Ho = 1 << lh;
  const int total = (N << lc) << (lw + lh);
  const int Wrow = 1 << (lw + 1);
  for (int i = blockIdx.x * 256 + threadIdx.x; i < total; i += gridDim.x * 256) {
    int wo = i & (Wo - 1);
    int ho = (i >> lw) & (Ho - 1);
    int c = (i >> (lw + lh)) & (C - 1);
    int n = i >> (lw + lh + lc);
    float sc = scsh[c], sh = scsh[C + c];
    size_t idx = (((((size_t)n * C + c) << (lh + 1)) + (ho << 1)) << (lw + 1)) + (wo << 1);
    float z00 = fmaxf(fmaf(y[idx], sc, sh), 0.f);
    float z01 = fmaxf(fmaf(y[idx + 1], sc, sh), 0.f);
    float z10 = fmaxf(fmaf(y[idx + Wrow], sc, sh), 0.f);
    float z11 = fmaxf(fmaf(y[idx + Wrow + 1], sc, sh), 0.f);
    out[i] = fmaxf(fmaxf(z00, z01), fmaxf(z10, z11));
  }
}

// ---------------- pooled4 fp32 -> hi/lo bf16 ----------------
__global__ __launch_bounds__(256) void hilo_split(const float* __restrict__ in,
                                                  unsigned short* __restrict__ hi,
                                                  unsigned short* __restrict__ lo, int n) {
  int i = blockIdx.x * 256 + threadIdx.x;
  if (i >= n) return;
  float f = in[i];
  __hip_bfloat16 h = __float2bfloat16(f);
  unsigned short hu;
  __builtin_memcpy(&hu, &h, 2);
  hi[i] = hu;
  lo[i] = f2us(f - __bfloat162float(h));
}

// ---------------- FC1 MFMA GEMM: A = int8 codes [1024][32768] converted in-register -------
DEV bf16x8 i8_to_bf16x8(i8x8 v) {
  us8 u;
#pragma unroll
  for (int j = 0; j < 8; ++j) {
    int c = v[j];
    u[j] = (unsigned short)(c == 0 ? 0 : (c > 0 ? 0x3F80 : 0xBF80));
  }
  bf16x8 r;
  __builtin_memcpy(&r, &u, 16);
  return r;
}

// grid (8 o-blocks, 32 k-slices) = 256 blocks; wave = 32 outs; partial fp32 [s][o][n]
__global__ __launch_bounds__(256) void fc1_mfma(const int8_t* __restrict__ c1,
                                                const unsigned short* __restrict__ aHi,
                                                const unsigned short* __restrict__ aLo,
                                                float* __restrict__ partial) {
  const int w = threadIdx.x >> 6, lane = threadIdx.x & 63;
  const int l15 = lane & 15, l4 = lane >> 4;
  const int o0 = blockIdx.x * 128 + w * 32;
  const int s = blockIdx.y;
  const int kbase = s * 1024 + l4 * 8;
  f32x4 acc[2][2];
#pragma unroll
  for (int g = 0; g < 2; ++g)
#pragma unroll
    for (int t = 0; t < 2; ++t) acc[g][t] = (f32x4){0.f, 0.f, 0.f, 0.f};
#pragma unroll 2
  for (int kc = 0; kc < 1024; kc += 32) {
    bf16x8 a0 = i8_to_bf16x8(*(const i8x8*)(c1 + (size_t)(o0 + l15) * 32768 + kbase + kc));
    bf16x8 a1 = i8_to_bf16x8(*(const i8x8*)(c1 + (size_t)(o0 + 16 + l15) * 32768 + kbase + kc));
    bf16x8 bh0 = *(const bf16x8*)(aHi + (size_t)l15 * 32768 + kbase + kc);
    bf16x8 bl0 = *(const bf16x8*)(aLo + (size_t)l15 * 32768 + kbase + kc);
    bf16x8 bh1 = *(const bf16x8*)(aHi + (size_t)(16 + l15) * 32768 + kbase + kc);
    bf16x8 bl1 = *(const bf16x8*)(aLo + (size_t)(16 + l15) * 32768 + kbase + kc);
    acc[0][0] = __builtin_amdgcn_mfma_f32_16x16x32_bf16(a0, bh0, acc[0][0], 0, 0, 0);
    acc[0][0] = __builtin_amdgcn_mfma_f32_16x16x32_bf16(a0, bl0, acc[0][0], 0, 0, 0);
    acc[1][0] = __builtin_amdgcn_mfma_f32_16x16x32_bf16(a1, bh0, acc[1][0], 0, 0, 0);
    acc[1][0] = __builtin_amdgcn_mfma_f32_16x16x32_bf16(a1, bl0, acc[1][0], 0, 0, 0);
    acc[0][1] = __builtin_amdgcn_mfma_f32_16x16x32_bf16(a0, bh1, acc[0][1], 0, 0, 0);
    acc[0][1] = __builtin_amdgcn_mfma_f32_16x16x32_bf16(a0, bl1, acc[0][1], 0, 0, 0);
    acc[1][1] = __builtin_amdgcn_mfma_f32_16x16x32_bf16(a1, bh1, acc[1][1], 0, 0, 0);
    acc[1][1] = __builtin_amdgcn_mfma_f32_16x16x32_bf16(a1, bl1, acc[1][1], 0, 0, 0);
  }
#pragma unroll
  for (int g = 0; g < 2; ++g)
#pragma unroll
    for (int t = 0; t < 2; ++t)
#pragma unroll
      for (int r = 0; r < 4; ++r) {
        int o = o0 + g * 16 + l4 * 4 + r;
        int n = t * 16 + l15;
        partial[((size_t)s * 1024 + o) * 32 + n] = acc[g][t][r];
      }
}

__global__ __launch_bounds__(256) void fc1_fin(const float* __restrict__ partial,
                                               const double* __restrict__ st,
                                               const float* __restrict__ fb,
                                               float* __restrict__ fc1T) {
  int i = blockIdx.x * 256 + threadIdx.x;  // 32768
  int o = i >> 5;
  float s = 0.f;
#pragma unroll
  for (int t = 0; t < 32; ++t) s += partial[(size_t)t * 32768 + i];
  float alpha = tern_alpha_d(st, 33554432.0);
  fc1T[i] = fmaxf(fmaf(s, alpha, fb[o]), 0.f);
}

// ---------------- FC2 (row-parallel; tiny) ----------------
__global__ __launch_bounds__(256) void fc2_kernel(const float* __restrict__ xT,
                                                  const int8_t* __restrict__ codes,
                                                  const double* __restrict__ st,
                                                  const float* __restrict__ fb,
                                                  float* __restrict__ out) {
  const int o = blockIdx.x;
  float acc[32];
#pragma unroll
  for (int j = 0; j < 32; ++j) acc[j] = 0.f;
  const int8_t* crow = codes + (size_t)o * 1024;
  for (int k = threadIdx.x; k < 1024; k += 256) {
    int cv = crow[k];
    if (cv != 0) {
      float c = (float)cv;
      const float4* pv = (const float4*)(xT + ((size_t)k << 5));
#pragma unroll
      for (int j = 0; j < 8; ++j) {
        float4 v = pv[j];
        acc[4 * j + 0] = fmaf(c, v.x, acc[4 * j + 0]);
        acc[4 * j + 1] = fmaf(c, v.y, acc[4 * j + 1]);
        acc[4 * j + 2] = fmaf(c, v.z, acc[4 * j + 2]);
        acc[4 * j + 3] = fmaf(c, v.w, acc[4 * j + 3]);
      }
    }
  }
#pragma unroll
  for (int j = 0; j < 32; ++j) {
#pragma unroll
    for (int off = 32; off > 0; off >>= 1) acc[j] += __shfl_down(acc[j], off);
  }
  __shared__ float red[4][32];
  int lane = threadIdx.x & 63, wv = threadIdx.x >> 6;
  if (lane == 0) {
#pragma unroll
    for (int j = 0; j < 32; ++j) red[wv][j] = acc[j];
  }
  __syncthreads();
  if (threadIdx.x < 32) {
    int n = threadIdx.x;
    float alpha = tern_alpha_d(st, 1024000.0);
    out[(size_t)n * 1000 + o] = (red[0][n] + red[1][n] + red[2][n] + red[3][n]) * alpha + fb[o];
  }
}

// ---------------- host ----------------
extern "C" void kernel_launch(void* const* d_in, const int* in_sizes, int n_in, void* d_out,
                              int out_size, void* d_ws, size_t ws_size, hipStream_t stream) {
  const float* x = (const float*)d_in[0];
  const float* w1 = (const float*)d_in[1];
  const float* g1 = (const float*)d_in[3];
  const float* be1 = (const float*)d_in[4];
  const float* w2 = (const float*)d_in[5];
  const float* g2 = (const float*)d_in[7];
  const float* be2 = (const float*)d_in[8];
  const float* w3 = (const float*)d_in[9];
  const float* g3 = (const float*)d_in[11];
  const float* be3 = (const float*)d_in[12];
  const float* w4 = (const float*)d_in[13];
  const float* g4 = (const float*)d_in[15];
  const float* be4 = (const float*)d_in[16];
  const float* fw1 = (const float*)d_in[17];
  const float* fb1 = (const float*)d_in[18];
  const float* fw2 = (const float*)d_in[19];
  const float* fb2 = (const float*)d_in[20];
  // b1..b4 cancel exactly under training-mode BN (alpha-folded finalize).
  (void)in_sizes; (void)n_in; (void)out_size; (void)ws_size;

  char* ws = (char*)d_ws;
  size_t off = 0;
  auto alloc = [&](size_t bytes) {
    size_t o = off;
    off += (bytes + 255) & ~(size_t)255;
    return o;
  };
  unsigned short* wb1 = (unsigned short*)(ws + alloc((size_t)18432 * 2));    // [64][288]
  unsigned short* wb2 = (unsigned short*)(ws + alloc((size_t)73728 * 2));    // [128][576]
  unsigned short* wb3 = (unsigned short*)(ws + alloc((size_t)294912 * 2));   // [256][1152]
  unsigned short* wb4 = (unsigned short*)(ws + alloc((size_t)1179648 * 2));  // [512][2304]
  int8_t* c1 = (int8_t*)(ws + alloc((size_t)33554432));  // fc1 int8 codes [1024][32768]
  int8_t* c2 = (int8_t*)(ws + alloc((size_t)1024000));
  double* dst = (double*)(ws + alloc((size_t)32 * 8));
  float* scsh = (float*)(ws + alloc((size_t)4096 * 4));
  double* pS = (double*)(ws + alloc((size_t)262144 * 8));
  double* pQ = (double*)(ws + alloc((size_t)262144 * 8));
  float* bufY = (float*)(ws + alloc((size_t)16777216 * 4));  // 67MB: x32pad / z
  float* bufA = (float*)(ws + alloc((size_t)8388608 * 4));   // 33.5MB: pooled NCHW+NHWC
  unsigned short* actHi = (unsigned short*)(ws + alloc((size_t)1048576 * 2));
  unsigned short* actLo = (unsigned short*)(ws + alloc((size_t)1048576 * 2));
  float* fc1part = (float*)(ws + alloc((size_t)1048576 * 4));  // [32][1024][32]
  float* fc1T = (float*)(ws + alloc((size_t)32768 * 4));       // [1024][32]
  float* x32 = bufY;              // NHWC-32 input, dead after conv1
  float* bufA2 = bufA + 4194304;  // second half for NHWC copies
  // total ~152 MB (163 MB proven mapped in R1)

  hipMemsetAsync(dst, 0, 32 * 8, stream);

  // ternarize stats: one abs launch + one fused masked+code launch for all 6 tensors
  TDescs ta;
  ta.d[0] = {w1, 1728};
  ta.d[1] = {w2, 73728};
  ta.d[2] = {w3, 294912};
  ta.d[3] = {w4, 1179648};
  ta.d[4] = {fw1, 33554432};
  ta.d[5] = {fw2, 1024000};
  tern_abs_all<<<dim3(2048, 6), 256, 0, stream>>>(ta, dst);
  MDescs tm;
  tm.d[0] = {w1, nullptr, 1728};
  tm.d[1] = {w2, nullptr, 73728};
  tm.d[2] = {w3, nullptr, 294912};
  tm.d[3] = {w4, nullptr, 1179648};
  tm.d[4] = {fw1, c1, 33554432};
  tm.d[5] = {fw2, c2, 1024000};
  tern_masked_code_all<<<dim3(2048, 6), 256, 0, stream>>>(tm, dst);
  tern_write_convb_pad<<<72, 256, 0, stream>>>(w1, dst + 0, wb1);
  tern_write_convb<<<288, 256, 0, stream>>>(w2, dst + 4, 73728, 64, wb2);
  tern_write_convb<<<1152, 256, 0, stream>>>(w3, dst + 8, 294912, 128, wb3);
  tern_write_convb<<<4608, 256, 0, stream>>>(w4, dst + 12, 1179648, 256, wb4);

  float* ss1 = scsh;
  float* ss2 = scsh + 128;
  float* ss3 = scsh + 512;
  float* ss4 = scsh + 1024;

  // Layer 1 via MFMA, two-pass recompute; pooled1 written directly as NHWC.
  pad32<<<2048, 256, 0, stream>>>(x, x32);
  conv1_mfma_stats<<<dim3(128, 1, 32), 128, 0, stream>>>(x32, wb1, pS, pQ);
  bn_fin_alpha<<<64, 256, 0, stream>>>(pS, pQ, 4096, g1, be1, 524288.0, dst + 0, 1728.0, ss1,
                                       64);
  conv1_mfma_pool<<<dim3(128, 1, 32), 128, 0, stream>>>(x32, wb1, ss1, bufA);

  // Layer 2: 64->128 @64x64 (reads pooled1 NHWC in bufA; z -> bufY)
  conv_mfma<64, 64, 8><<<dim3(32, 1, 32), 256, 0, stream>>>(bufA, wb2, bufY, 128, pS, pQ, 1024);
  bn_fin_alpha<<<128, 256, 0, stream>>>(pS, pQ, 1024, g2, be2, 131072.0, dst + 4, 73728.0, ss2,
                                        128);
  bn_pool<<<16384, 256, 0, stream>>>(bufY, ss2, 128, 5, 5, 7, 32, bufA);
  nchw2nhwc<<<dim3(2, 16, 32), 256, 0, stream>>>(bufA, bufA2, 128, 1024);

  // Layer 3: 128->256 @32x32
  conv_mfma<128, 32, 4><<<dim3(16, 2, 32), 256, 0, stream>>>(bufA2, wb3, bufY, 256, pS, pQ, 512);
  bn_fin_alpha<<<256, 256, 0, stream>>>(pS, pQ, 512, g3, be3, 32768.0, dst + 8, 294912.0, ss3,
                                        256);
  bn_pool<<<8192, 256, 0, stream>>>(bufY, ss3, 256, 4, 4, 8, 32, bufA);
  nchw2nhwc<<<dim3(4, 4, 32), 256, 0, stream>>>(bufA, bufA2, 256, 256);

  // Layer 4: 256->512 @16x16; pooled4 NCHW flat == [32][32768]
  conv_mfma<256, 16, 2><<<dim3(8, 4, 32), 256, 0, stream>>>(bufA2, wb4, bufY, 512, pS, pQ, 256);
  bn_fin_alpha<<<512, 256, 0, stream>>>(pS, pQ, 256, g4, be4, 8192.0, dst + 12, 1179648.0, ss4,
                                        512);
  bn_pool<<<4096, 256, 0, stream>>>(bufY, ss4, 512, 3, 3, 9, 32, bufA);
  hilo_split<<<4096, 256, 0, stream>>>(bufA, actHi, actLo, 1048576);

  // FC1 (int8 codes -> in-register bf16), 256 blocks; then finalize + FC2
  fc1_mfma<<<dim3(8, 32), 256, 0, stream>>>(c1, actHi, actLo, fc1part);
  fc1_fin<<<128, 256, 0, stream>>>(fc1part, dst + 16, fb1, fc1T);
  fc2_kernel<<<1000, 256, 0, stream>>>(fc1T, c2, dst + 20, fb2, (float*)d_out);
}

// Round 8
// 840.918 us; speedup vs baseline: 48.5540x; 1.1124x over previous
//
#include <hip/hip_runtime.h>
#include <hip/hip_bf16.h>
#include <stdint.h>

#define DEV __device__ __forceinline__

typedef __bf16 bf16x8 __attribute__((ext_vector_type(8)));
typedef float f32x4 __attribute__((ext_vector_type(4)));
typedef unsigned short us8 __attribute__((ext_vector_type(8)));
typedef int8_t i8x8 __attribute__((ext_vector_type(8)));

DEV unsigned short f2us(float f) {
  __hip_bfloat16 h = __float2bfloat16(f);
  unsigned short u;
  __builtin_memcpy(&u, &h, 2);
  return u;
}

DEV double wave_reduce_d(double v) {
#pragma unroll
  for (int off = 32; off > 0; off >>= 1) v += __shfl_down(v, off);
  return v;
}

DEV double dbl_block_reduce(double v, double* lds) {
  v = wave_reduce_d(v);
  int lane = threadIdx.x & 63, w = threadIdx.x >> 6;
  if (lane == 0) lds[w] = v;
  __syncthreads();
  double r = 0.0;
  if (threadIdx.x == 0) r = lds[0] + lds[1] + lds[2] + lds[3];
  __syncthreads();
  return r;
}

// ---------------- ternarize: fp64 stats, float4-vectorized sweeps ----------------
struct TDesc { const float* w; int n; };
struct TDescs { TDesc d[6]; };

// one launch, all 6 tensors: sum|w| into st[slot*4]. float4 loads for MLP.
__global__ __launch_bounds__(256) void tern_abs_all(TDescs td, double* __restrict__ st) {
  __shared__ double lds[4];
  const int t = blockIdx.y;
  const float4* w4 = (const float4*)td.d[t].w;
  const int n4 = td.d[t].n >> 2;
  double s = 0.0;
  for (int i = blockIdx.x * 256 + threadIdx.x; i < n4; i += gridDim.x * 256) {
    float4 v = w4[i];
    s += fabs((double)v.x) + fabs((double)v.y) + fabs((double)v.z) + fabs((double)v.w);
  }
  s = dbl_block_reduce(s, lds);
  if (threadIdx.x == 0 && s != 0.0) atomicAdd(st + t * 4, s);
}

struct MDesc { const float* w; int8_t* out; int n; };
struct MDescs { MDesc d[6]; };

// one launch, all 6 tensors: masked sum + count into st[slot*4+1,2]; optional int8
// codes (char4-packed) — codes depend on delta only, so fused with this pass.
__global__ __launch_bounds__(256) void tern_masked_code_all(MDescs td, double* __restrict__ st) {
  __shared__ double lds[4];
  const int t = blockIdx.y;
  const float4* w4 = (const float4*)td.d[t].w;
  int8_t* out = td.d[t].out;
  const int n4 = td.d[t].n >> 2;
  const double delta = 0.7 * st[t * 4] / (double)td.d[t].n;
  double ms = 0.0, cnt = 0.0;
  for (int i = blockIdx.x * 256 + threadIdx.x; i < n4; i += gridDim.x * 256) {
    float4 v = w4[i];
    double e[4] = {(double)v.x, (double)v.y, (double)v.z, (double)v.w};
    char pk[4];
#pragma unroll
    for (int j = 0; j < 4; ++j) {
      double a = fabs(e[j]);
      if (a > delta) { ms += a; cnt += 1.0; }
      pk[j] = (char)((e[j] > delta) ? 1 : ((e[j] < -delta) ? -1 : 0));
    }
    if (out) {
      int w32;
      __builtin_memcpy(&w32, pk, 4);
      *(int*)(out + ((size_t)i << 2)) = w32;
    }
  }
  ms = dbl_block_reduce(ms, lds);
  cnt = dbl_block_reduce(cnt, lds);
  if (threadIdx.x == 0 && cnt != 0.0) {
    atomicAdd(st + t * 4 + 1, ms);
    atomicAdd(st + t * 4 + 2, cnt);
  }
}

DEV float tern_alpha_d(const double* st, double n) {
  double cnt = st[2];
  return (float)(cnt > 0.0 ? st[1] / fmax(cnt, 1.0) : st[0] / n);
}
DEV double tern_alpha_dd(const double* st, double n) {
  double cnt = st[2];
  return cnt > 0.0 ? st[1] / fmax(cnt, 1.0) : st[0] / n;
}

// conv2-4 weights -> bf16 codes {-1,0,+1}, layout [cout][k=tap*CIN+ci]
__global__ __launch_bounds__(256) void tern_write_convb(const float* __restrict__ w,
                                                        const double* __restrict__ st, int total,
                                                        int CIN, unsigned short* __restrict__ out) {
  int i = blockIdx.x * 256 + threadIdx.x;
  if (i >= total) return;
  double delta = 0.7 * st[0] / (double)total;
  double v = (double)w[i];
  float code = v > delta ? 1.f : (v < -delta ? -1.f : 0.f);
  int cin9 = CIN * 9;
  int o = i / cin9, rem = i - o * cin9;
  int ci = rem / 9, tap = rem - ci * 9;
  out[(size_t)o * cin9 + tap * CIN + ci] = f2us(code);
}

// conv1 weights (cin=3) -> bf16 codes padded to 32 ci: [64][k=tap*32+ci]
__global__ __launch_bounds__(256) void tern_write_convb_pad(const float* __restrict__ w,
                                                            const double* __restrict__ st,
                                                            unsigned short* __restrict__ out) {
  int i = blockIdx.x * 256 + threadIdx.x;
  if (i >= 64 * 288) return;
  int o = i / 288, rem = i - o * 288;
  int tap = rem >> 5, ci = rem & 31;
  float code = 0.f;
  if (ci < 3) {
    double delta = 0.7 * st[0] / 1728.0;
    double v = (double)w[(o * 3 + ci) * 9 + tap];
    code = v > delta ? 1.f : (v < -delta ? -1.f : 0.f);
  }
  out[i] = f2us(code);
}

// ---------------- BN finalize (alpha-folded; bias cancels exactly) ----------------
__global__ __launch_bounds__(256) void bn_fin_alpha(const double* __restrict__ pS,
                                                    const double* __restrict__ pQ, int P,
                                                    const float* __restrict__ g,
                                                    const float* __restrict__ be, double M,
                                                    const double* __restrict__ st, double nels,
                                                    float* __restrict__ scsh, int C) {
  __shared__ double lds[4];
  const int c = blockIdx.x;
  double s = 0.0, q = 0.0;
  for (int p = threadIdx.x; p < P; p += 256) {
    s += pS[(size_t)c * P + p];
    q += pQ[(size_t)c * P + p];
  }
  s = dbl_block_reduce(s, lds);
  q = dbl_block_reduce(q, lds);
  if (threadIdx.x == 0) {
    double al = tern_alpha_dd(st, nels);
    double mean = s / M;
    double var = q / M - mean * mean;
    double sc = (double)g[c] * al / sqrt(al * al * var + 1e-5);
    scsh[c] = (float)sc;
    scsh[C + c] = (float)((double)be[c] - mean * sc);
  }
}

// ---------------- x NCHW(3ch) -> NHWC padded to 32ch fp32 ----------------
__global__ __launch_bounds__(256) void pad32(const float* __restrict__ x,
                                             float* __restrict__ x32) {
  int i = blockIdx.x * 256 + threadIdx.x;  // 32*16384
  int px = i & 16383, n = i >> 14;
  float v0 = x[((size_t)n * 3 + 0) * 16384 + px];
  float v1 = x[((size_t)n * 3 + 1) * 16384 + px];
  float v2 = x[((size_t)n * 3 + 2) * 16384 + px];
  float4* dst = (float4*)(x32 + (size_t)i * 32);
  dst[0] = make_float4(v0, v1, v2, 0.f);
  float4 z = make_float4(0.f, 0.f, 0.f, 0.f);
#pragma unroll
  for (int j = 1; j < 8; ++j) dst[j] = z;
}

// ---------------- NCHW fp32 -> NHWC fp32 transpose ----------------
__global__ __launch_bounds__(256) void nchw2nhwc(const float* __restrict__ in,
                                                 float* __restrict__ out, int C, int HW) {
  __shared__ float t[64][65];
  const int c0 = blockIdx.x * 64, p0 = blockIdx.y * 64, n = blockIdx.z;
  const float* src = in + (size_t)n * C * HW;
  for (int u = threadIdx.x; u < 4096; u += 256) {
    int cl = u >> 6, pl = u & 63;
    t[cl][pl] = src[(size_t)(c0 + cl) * HW + p0 + pl];
  }
  __syncthreads();
  float* dst = out + (size_t)n * HW * C;
  for (int u = threadIdx.x; u < 4096; u += 256) {
    int pl = u >> 6, cl = u & 63;
    dst[(size_t)(p0 + pl) * C + c0 + cl] = t[cl][pl];
  }
}

// ---------------- MFMA implicit-GEMM conv body (hi/lo bf16 split) ----------------
template <int CIN, int H, int PH, int NW>
DEV void conv_body(const float* __restrict__ inNHWC, const unsigned short* __restrict__ wT,
                   int wvCout, int n, int x0, int y0, unsigned short* hiT, unsigned short* loT,
                   f32x4 (&acc)[2][PH]) {
  constexpr int W = H;
  constexpr int K = 9 * CIN;
  constexpr int CH = CIN / 32;
  constexpr int NU = (PH + 2) * 18 * 4;
  const int lane = threadIdx.x & 63;
  const int l15 = lane & 15, l4 = lane >> 4;

#pragma unroll
  for (int g = 0; g < 2; ++g)
#pragma unroll
    for (int pt = 0; pt < PH; ++pt) acc[g][pt] = (f32x4){0.f, 0.f, 0.f, 0.f};

#pragma unroll 1
  for (int cc = 0; cc < CH; ++cc) {
    __syncthreads();
    for (int u = threadIdx.x; u < NU; u += NW * 64) {
      int q = u & 3, rem = u >> 2;
      int xx = rem % 18, yy = rem / 18;
      int gy = y0 + yy - 1, gx = x0 + xx - 1;
      us8 hv = (us8)0, lv = (us8)0;
      if ((unsigned)gy < (unsigned)H && (unsigned)gx < (unsigned)W) {
        const float* src = inNHWC + (((size_t)(n * H + gy) * W + gx) * CIN + cc * 32 + q * 8);
        float4 a = *(const float4*)src;
        float4 c = *(const float4*)(src + 4);
        float f[8] = {a.x, a.y, a.z, a.w, c.x, c.y, c.z, c.w};
#pragma unroll
        for (int j = 0; j < 8; ++j) {
          __hip_bfloat16 h = __float2bfloat16(f[j]);
          unsigned short hu;
          __builtin_memcpy(&hu, &h, 2);
          hv[j] = hu;
          lv[j] = f2us(f[j] - __bfloat162float(h));
        }
      }
      int off = (rem << 5) + (q << 3);
      *(us8*)(hiT + off) = hv;
      *(us8*)(loT + off) = lv;
    }
    __syncthreads();

#pragma unroll
    for (int tap = 0; tap < 9; ++tap) {
      const int dy = tap / 3, dx = tap % 3;
      bf16x8 aF[2];
#pragma unroll
      for (int g = 0; g < 2; ++g) {
        int co = wvCout + g * 16 + l15;
        aF[g] = *(const bf16x8*)(wT + (size_t)co * K + tap * CIN + cc * 32 + l4 * 8);
      }
      const int tb = (dy * 18 + dx + l15) * 32 + l4 * 8;
#pragma unroll
      for (int pt = 0; pt < PH; ++pt) {
        int off = tb + pt * (18 * 32);
        bf16x8 bh = *(const bf16x8*)(hiT + off);
        bf16x8 bl = *(const bf16x8*)(loT + off);
        acc[0][pt] = __builtin_amdgcn_mfma_f32_16x16x32_bf16(aF[0], bh, acc[0][pt], 0, 0, 0);
        acc[1][pt] = __builtin_amdgcn_mfma_f32_16x16x32_bf16(aF[1], bh, acc[1][pt], 0, 0, 0);
        acc[0][pt] = __builtin_amdgcn_mfma_f32_16x16x32_bf16(aF[0], bl, acc[0][pt], 0, 0, 0);
        acc[1][pt] = __builtin_amdgcn_mfma_f32_16x16x32_bf16(aF[1], bl, acc[1][pt], 0, 0, 0);
      }
    }
  }
}

// fused fp64 BN partial write (per wave, 16-lane reduce)
template <int PH>
DEV void bn_partials(const f32x4 (&acc)[2][PH], int wvCout, int p, int P,
                     double* __restrict__ pS, double* __restrict__ pQ) {
  const int lane = threadIdx.x & 63;
  const int l15 = lane & 15, l4 = lane >> 4;
#pragma unroll
  for (int g = 0; g < 2; ++g) {
    float sv[4] = {0, 0, 0, 0}, qv[4] = {0, 0, 0, 0};
#pragma unroll
    for (int pt = 0; pt < PH; ++pt)
#pragma unroll
      for (int r = 0; r < 4; ++r) {
        float v = acc[g][pt][r];
        sv[r] += v;
        qv[r] = fmaf(v, v, qv[r]);
      }
#pragma unroll
    for (int r = 0; r < 4; ++r)
#pragma unroll
      for (int m = 1; m < 16; m <<= 1) {
        sv[r] += __shfl_xor(sv[r], m);
        qv[r] += __shfl_xor(qv[r], m);
      }
    if (l15 == 0) {
#pragma unroll
      for (int r = 0; r < 4; ++r) {
        int co = wvCout + g * 16 + l4 * 4 + r;
        pS[(size_t)co * P + p] = (double)sv[r];
        pQ[(size_t)co * P + p] = (double)qv[r];
      }
    }
  }
}

// layers 2-4: z store (NCHW fp32) + partials
template <int CIN, int H, int PH>
__global__ __launch_bounds__(256) void conv_mfma(const float* __restrict__ inNHWC,
                                                 const unsigned short* __restrict__ wT,
                                                 float* __restrict__ z, int COUT,
                                                 double* __restrict__ pS,
                                                 double* __restrict__ pQ, int P) {
  constexpr int W = H;
  constexpr int TX = W / 16;
  __shared__ unsigned short hiT[(PH + 2) * 18 * 32];
  __shared__ unsigned short loT[(PH + 2) * 18 * 32];
  const int bx = blockIdx.x;
  const int tX = bx % TX, tY = bx / TX;
  const int n = blockIdx.z;
  const int wave = threadIdx.x >> 6, lane = threadIdx.x & 63;
  const int l15 = lane & 15, l4 = lane >> 4;
  const int wvCout = blockIdx.y * 128 + wave * 32;
  const int x0 = tX * 16, y0 = tY * PH;
  f32x4 acc[2][PH];
  conv_body<CIN, H, PH, 4>(inNHWC, wT, wvCout, n, x0, y0, hiT, loT, acc);
#pragma unroll
  for (int g = 0; g < 2; ++g)
#pragma unroll
    for (int pt = 0; pt < PH; ++pt) {
      int oy = y0 + pt;
#pragma unroll
      for (int r = 0; r < 4; ++r) {
        int co = wvCout + g * 16 + l4 * 4 + r;
        z[(((size_t)n * COUT + co) * H + oy) * W + x0 + l15] = acc[g][pt][r];
      }
    }
  bn_partials<PH>(acc, wvCout, n * gridDim.x + bx, P, pS, pQ);
}

// layer 1 pass 1: partials only (z never materialized)
__global__ __launch_bounds__(128) void conv1_mfma_stats(const float* __restrict__ inNHWC,
                                                        const unsigned short* __restrict__ wT,
                                                        double* __restrict__ pS,
                                                        double* __restrict__ pQ) {
  __shared__ unsigned short hiT[10 * 18 * 32];
  __shared__ unsigned short loT[10 * 18 * 32];
  const int bx = blockIdx.x;
  const int tX = bx & 7, tY = bx >> 3;
  const int n = blockIdx.z;
  const int wave = threadIdx.x >> 6;
  const int wvCout = wave * 32;
  f32x4 acc[2][8];
  conv_body<32, 128, 8, 2>(inNHWC, wT, wvCout, n, tX * 16, tY * 8, hiT, loT, acc);
  bn_partials<8>(acc, wvCout, n * gridDim.x + bx, 4096, pS, pQ);
}

// layer 1 pass 2: recompute, BN+relu+2x2 maxpool, write pooled NHWC directly
__global__ __launch_bounds__(128) void conv1_mfma_pool(const float* __restrict__ inNHWC,
                                                       const unsigned short* __restrict__ wT,
                                                       const float* __restrict__ scsh,
                                                       float* __restrict__ outNHWC) {
  __shared__ unsigned short hiT[10 * 18 * 32];
  __shared__ unsigned short loT[10 * 18 * 32];
  const int bx = blockIdx.x;
  const int tX = bx & 7, tY = bx >> 3;
  const int n = blockIdx.z;
  const int wave = threadIdx.x >> 6, lane = threadIdx.x & 63;
  const int l15 = lane & 15, l4 = lane >> 4;
  const int wvCout = wave * 32;
  const int x0 = tX * 16, y0 = tY * 8;
  f32x4 acc[2][8];
  conv_body<32, 128, 8, 2>(inNHWC, wT, wvCout, n, x0, y0, hiT, loT, acc);
#pragma unroll
  for (int g = 0; g < 2; ++g) {
    const int co0 = wvCout + g * 16 + l4 * 4;
#pragma unroll
    for (int pt = 0; pt < 8; pt += 2) {
      float m[4];
#pragma unroll
      for (int r = 0; r < 4; ++r) {
        float sc = scsh[co0 + r], sh = scsh[64 + co0 + r];
        float v0 = fmaxf(fmaf(acc[g][pt][r], sc, sh), 0.f);
        float v1 = fmaxf(fmaf(acc[g][pt + 1][r], sc, sh), 0.f);
        float a = fmaxf(v0, v1);
        m[r] = fmaxf(a, __shfl_xor(a, 1));
      }
      if ((l15 & 1) == 0) {
        int oy = (y0 + pt) >> 1, ox = (x0 + l15) >> 1;
        *(float4*)(outNHWC + ((((size_t)n * 64 + oy) * 64 + ox) << 6) + co0) =
            make_float4(m[0], m[1], m[2], m[3]);
      }
    }
  }
}

// ---------------- fused norm+relu+pool (fp32 z in, NCHW out) ----------------
__global__ __launch_bounds__(256) void bn_pool(const float* __restrict__ y,
                                               const float* __restrict__ scsh, int C, int lw,
                                               int lh, int lc, int N, float* __restrict__ out) {
  const int Wo = 1 << lw, Ho = 1 << lh;
  const int total = (N << lc) << (lw + lh);
  const int Wrow = 1 << (lw + 1);
  for (int i = blockIdx.x * 256 + threadIdx.x; i < total; i += gridDim.x * 256) {
    int wo = i & (Wo - 1);
    int ho = (i >> lw) & (Ho - 1);
    int c = (i >> (lw + lh)) & (C - 1);
    int n = i >> (lw + lh + lc);
    float sc = scsh[c], sh = scsh[C + c];
    size_t idx = (((((size_t)n * C + c) << (lh + 1)) + (ho << 1)) << (lw + 1)) + (wo << 1);
    float z00 = fmaxf(fmaf(y[idx], sc, sh), 0.f);
    float z01 = fmaxf(fmaf(y[idx + 1], sc, sh), 0.f);
    float z10 = fmaxf(fmaf(y[idx + Wrow], sc, sh), 0.f);
    float z11 = fmaxf(fmaf(y[idx + Wrow + 1], sc, sh), 0.f);
    out[i] = fmaxf(fmaxf(z00, z01), fmaxf(z10, z11));
  }
}

// ---------------- pooled4 fp32 -> hi/lo bf16 ----------------
__global__ __launch_bounds__(256) void hilo_split(const float* __restrict__ in,
                                                  unsigned short* __restrict__ hi,
                                                  unsigned short* __restrict__ lo, int n) {
  int i = blockIdx.x * 256 + threadIdx.x;
  if (i >= n) return;
  float f = in[i];
  __hip_bfloat16 h = __float2bfloat16(f);
  unsigned short hu;
  __builtin_memcpy(&hu, &h, 2);
  hi[i] = hu;
  lo[i] = f2us(f - __bfloat162float(h));
}

// ---------------- FC1 MFMA GEMM: A = int8 codes converted in-register ----------------
DEV bf16x8 i8_to_bf16x8(i8x8 v) {
  us8 u;
#pragma unroll
  for (int j = 0; j < 8; ++j) {
    int c = v[j];
    u[j] = (unsigned short)(c == 0 ? 0 : (c > 0 ? 0x3F80 : 0xBF80));
  }
  bf16x8 r;
  __builtin_memcpy(&r, &u, 16);
  return r;
}

// grid (8 o-blocks, 32 k-slices) = 256 blocks; wave = 32 outs; partial fp32 [s][o][n]
__global__ __launch_bounds__(256) void fc1_mfma(const int8_t* __restrict__ c1,
                                                const unsigned short* __restrict__ aHi,
                                                const unsigned short* __restrict__ aLo,
                                                float* __restrict__ partial) {
  const int w = threadIdx.x >> 6, lane = threadIdx.x & 63;
  const int l15 = lane & 15, l4 = lane >> 4;
  const int o0 = blockIdx.x * 128 + w * 32;
  const int s = blockIdx.y;
  const int kbase = s * 1024 + l4 * 8;
  f32x4 acc[2][2];
#pragma unroll
  for (int g = 0; g < 2; ++g)
#pragma unroll
    for (int t = 0; t < 2; ++t) acc[g][t] = (f32x4){0.f, 0.f, 0.f, 0.f};
#pragma unroll 2
  for (int kc = 0; kc < 1024; kc += 32) {
    bf16x8 a0 = i8_to_bf16x8(*(const i8x8*)(c1 + (size_t)(o0 + l15) * 32768 + kbase + kc));
    bf16x8 a1 = i8_to_bf16x8(*(const i8x8*)(c1 + (size_t)(o0 + 16 + l15) * 32768 + kbase + kc));
    bf16x8 bh0 = *(const bf16x8*)(aHi + (size_t)l15 * 32768 + kbase + kc);
    bf16x8 bl0 = *(const bf16x8*)(aLo + (size_t)l15 * 32768 + kbase + kc);
    bf16x8 bh1 = *(const bf16x8*)(aHi + (size_t)(16 + l15) * 32768 + kbase + kc);
    bf16x8 bl1 = *(const bf16x8*)(aLo + (size_t)(16 + l15) * 32768 + kbase + kc);
    acc[0][0] = __builtin_amdgcn_mfma_f32_16x16x32_bf16(a0, bh0, acc[0][0], 0, 0, 0);
    acc[0][0] = __builtin_amdgcn_mfma_f32_16x16x32_bf16(a0, bl0, acc[0][0], 0, 0, 0);
    acc[1][0] = __builtin_amdgcn_mfma_f32_16x16x32_bf16(a1, bh0, acc[1][0], 0, 0, 0);
    acc[1][0] = __builtin_amdgcn_mfma_f32_16x16x32_bf16(a1, bl0, acc[1][0], 0, 0, 0);
    acc[0][1] = __builtin_amdgcn_mfma_f32_16x16x32_bf16(a0, bh1, acc[0][1], 0, 0, 0);
    acc[0][1] = __builtin_amdgcn_mfma_f32_16x16x32_bf16(a0, bl1, acc[0][1], 0, 0, 0);
    acc[1][1] = __builtin_amdgcn_mfma_f32_16x16x32_bf16(a1, bh1, acc[1][1], 0, 0, 0);
    acc[1][1] = __builtin_amdgcn_mfma_f32_16x16x32_bf16(a1, bl1, acc[1][1], 0, 0, 0);
  }
#pragma unroll
  for (int g = 0; g < 2; ++g)
#pragma unroll
    for (int t = 0; t < 2; ++t)
#pragma unroll
      for (int r = 0; r < 4; ++r) {
        int o = o0 + g * 16 + l4 * 4 + r;
        int n = t * 16 + l15;
        partial[((size_t)s * 1024 + o) * 32 + n] = acc[g][t][r];
      }
}

__global__ __launch_bounds__(256) void fc1_fin(const float* __restrict__ partial,
                                               const double* __restrict__ st,
                                               const float* __restrict__ fb,
                                               float* __restrict__ fc1T) {
  int i = blockIdx.x * 256 + threadIdx.x;  // 32768
  int o = i >> 5;
  float s = 0.f;
#pragma unroll
  for (int t = 0; t < 32; ++t) s += partial[(size_t)t * 32768 + i];
  float alpha = tern_alpha_d(st, 33554432.0);
  fc1T[i] = fmaxf(fmaf(s, alpha, fb[o]), 0.f);
}

// ---------------- FC2 (row-parallel; tiny) ----------------
__global__ __launch_bounds__(256) void fc2_kernel(const float* __restrict__ xT,
                                                  const int8_t* __restrict__ codes,
                                                  const double* __restrict__ st,
                                                  const float* __restrict__ fb,
                                                  float* __restrict__ out) {
  const int o = blockIdx.x;
  float acc[32];
#pragma unroll
  for (int j = 0; j < 32; ++j) acc[j] = 0.f;
  const int8_t* crow = codes + (size_t)o * 1024;
  for (int k = threadIdx.x; k < 1024; k += 256) {
    int cv = crow[k];
    if (cv != 0) {
      float c = (float)cv;
      const float4* pv = (const float4*)(xT + ((size_t)k << 5));
#pragma unroll
      for (int j = 0; j < 8; ++j) {
        float4 v = pv[j];
        acc[4 * j + 0] = fmaf(c, v.x, acc[4 * j + 0]);
        acc[4 * j + 1] = fmaf(c, v.y, acc[4 * j + 1]);
        acc[4 * j + 2] = fmaf(c, v.z, acc[4 * j + 2]);
        acc[4 * j + 3] = fmaf(c, v.w, acc[4 * j + 3]);
      }
    }
  }
#pragma unroll
  for (int j = 0; j < 32; ++j) {
#pragma unroll
    for (int off = 32; off > 0; off >>= 1) acc[j] += __shfl_down(acc[j], off);
  }
  __shared__ float red[4][32];
  int lane = threadIdx.x & 63, wv = threadIdx.x >> 6;
  if (lane == 0) {
#pragma unroll
    for (int j = 0; j < 32; ++j) red[wv][j] = acc[j];
  }
  __syncthreads();
  if (threadIdx.x < 32) {
    int n = threadIdx.x;
    float alpha = tern_alpha_d(st, 1024000.0);
    out[(size_t)n * 1000 + o] = (red[0][n] + red[1][n] + red[2][n] + red[3][n]) * alpha + fb[o];
  }
}

// ---------------- host ----------------
extern "C" void kernel_launch(void* const* d_in, const int* in_sizes, int n_in, void* d_out,
                              int out_size, void* d_ws, size_t ws_size, hipStream_t stream) {
  const float* x = (const float*)d_in[0];
  const float* w1 = (const float*)d_in[1];
  const float* g1 = (const float*)d_in[3];
  const float* be1 = (const float*)d_in[4];
  const float* w2 = (const float*)d_in[5];
  const float* g2 = (const float*)d_in[7];
  const float* be2 = (const float*)d_in[8];
  const float* w3 = (const float*)d_in[9];
  const float* g3 = (const float*)d_in[11];
  const float* be3 = (const float*)d_in[12];
  const float* w4 = (const float*)d_in[13];
  const float* g4 = (const float*)d_in[15];
  const float* be4 = (const float*)d_in[16];
  const float* fw1 = (const float*)d_in[17];
  const float* fb1 = (const float*)d_in[18];
  const float* fw2 = (const float*)d_in[19];
  const float* fb2 = (const float*)d_in[20];
  // b1..b4 cancel exactly under training-mode BN (alpha-folded finalize).
  (void)in_sizes; (void)n_in; (void)out_size; (void)ws_size;

  char* ws = (char*)d_ws;
  size_t off = 0;
  auto alloc = [&](size_t bytes) {
    size_t o = off;
    off += (bytes + 255) & ~(size_t)255;
    return o;
  };
  unsigned short* wb1 = (unsigned short*)(ws + alloc((size_t)18432 * 2));    // [64][288]
  unsigned short* wb2 = (unsigned short*)(ws + alloc((size_t)73728 * 2));    // [128][576]
  unsigned short* wb3 = (unsigned short*)(ws + alloc((size_t)294912 * 2));   // [256][1152]
  unsigned short* wb4 = (unsigned short*)(ws + alloc((size_t)1179648 * 2));  // [512][2304]
  int8_t* c1 = (int8_t*)(ws + alloc((size_t)33554432));  // fc1 int8 codes [1024][32768]
  int8_t* c2 = (int8_t*)(ws + alloc((size_t)1024000));
  double* dst = (double*)(ws + alloc((size_t)32 * 8));
  float* scsh = (float*)(ws + alloc((size_t)4096 * 4));
  double* pS = (double*)(ws + alloc((size_t)262144 * 8));
  double* pQ = (double*)(ws + alloc((size_t)262144 * 8));
  float* bufY = (float*)(ws + alloc((size_t)16777216 * 4));  // 67MB: x32pad / z
  float* bufA = (float*)(ws + alloc((size_t)8388608 * 4));   // 33.5MB: pooled NCHW+NHWC
  unsigned short* actHi = (unsigned short*)(ws + alloc((size_t)1048576 * 2));
  unsigned short* actLo = (unsigned short*)(ws + alloc((size_t)1048576 * 2));
  float* fc1part = (float*)(ws + alloc((size_t)1048576 * 4));  // [32][1024][32]
  float* fc1T = (float*)(ws + alloc((size_t)32768 * 4));       // [1024][32]
  float* x32 = bufY;              // NHWC-32 input, dead after conv1
  float* bufA2 = bufA + 4194304;  // second half for NHWC copies
  // total ~152 MB (163 MB proven mapped in R1)

  hipMemsetAsync(dst, 0, 32 * 8, stream);

  // ternarize stats: one abs launch + one fused masked+code launch for all 6 tensors
  TDescs ta;
  ta.d[0] = {w1, 1728};
  ta.d[1] = {w2, 73728};
  ta.d[2] = {w3, 294912};
  ta.d[3] = {w4, 1179648};
  ta.d[4] = {fw1, 33554432};
  ta.d[5] = {fw2, 1024000};
  tern_abs_all<<<dim3(2048, 6), 256, 0, stream>>>(ta, dst);
  MDescs tm;
  tm.d[0] = {w1, nullptr, 1728};
  tm.d[1] = {w2, nullptr, 73728};
  tm.d[2] = {w3, nullptr, 294912};
  tm.d[3] = {w4, nullptr, 1179648};
  tm.d[4] = {fw1, c1, 33554432};
  tm.d[5] = {fw2, c2, 1024000};
  tern_masked_code_all<<<dim3(2048, 6), 256, 0, stream>>>(tm, dst);
  tern_write_convb_pad<<<72, 256, 0, stream>>>(w1, dst + 0, wb1);
  tern_write_convb<<<288, 256, 0, stream>>>(w2, dst + 4, 73728, 64, wb2);
  tern_write_convb<<<1152, 256, 0, stream>>>(w3, dst + 8, 294912, 128, wb3);
  tern_write_convb<<<4608, 256, 0, stream>>>(w4, dst + 12, 1179648, 256, wb4);

  float* ss1 = scsh;
  float* ss2 = scsh + 128;
  float* ss3 = scsh + 512;
  float* ss4 = scsh + 1024;

  // Layer 1 via MFMA, two-pass recompute; pooled1 written directly as NHWC.
  pad32<<<2048, 256, 0, stream>>>(x, x32);
  conv1_mfma_stats<<<dim3(128, 1, 32), 128, 0, stream>>>(x32, wb1, pS, pQ);
  bn_fin_alpha<<<64, 256, 0, stream>>>(pS, pQ, 4096, g1, be1, 524288.0, dst + 0, 1728.0, ss1,
                                       64);
  conv1_mfma_pool<<<dim3(128, 1, 32), 128, 0, stream>>>(x32, wb1, ss1, bufA);

  // Layer 2: 64->128 @64x64 (reads pooled1 NHWC in bufA; z -> bufY)
  conv_mfma<64, 64, 8><<<dim3(32, 1, 32), 256, 0, stream>>>(bufA, wb2, bufY, 128, pS, pQ, 1024);
  bn_fin_alpha<<<128, 256, 0, stream>>>(pS, pQ, 1024, g2, be2, 131072.0, dst + 4, 73728.0, ss2,
                                        128);
  bn_pool<<<16384, 256, 0, stream>>>(bufY, ss2, 128, 5, 5, 7, 32, bufA);
  nchw2nhwc<<<dim3(2, 16, 32), 256, 0, stream>>>(bufA, bufA2, 128, 1024);

  // Layer 3: 128->256 @32x32
  conv_mfma<128, 32, 4><<<dim3(16, 2, 32), 256, 0, stream>>>(bufA2, wb3, bufY, 256, pS, pQ, 512);
  bn_fin_alpha<<<256, 256, 0, stream>>>(pS, pQ, 512, g3, be3, 32768.0, dst + 8, 294912.0, ss3,
                                        256);
  bn_pool<<<8192, 256, 0, stream>>>(bufY, ss3, 256, 4, 4, 8, 32, bufA);
  nchw2nhwc<<<dim3(4, 4, 32), 256, 0, stream>>>(bufA, bufA2, 256, 256);

  // Layer 4: 256->512 @16x16; pooled4 NCHW flat == [32][32768]
  conv_mfma<256, 16, 2><<<dim3(8, 4, 32), 256, 0, stream>>>(bufA2, wb4, bufY, 512, pS, pQ, 256);
  bn_fin_alpha<<<512, 256, 0, stream>>>(pS, pQ, 256, g4, be4, 8192.0, dst + 12, 1179648.0, ss4,
                                        512);
  bn_pool<<<4096, 256, 0, stream>>>(bufY, ss4, 512, 3, 3, 9, 32, bufA);
  hilo_split<<<4096, 256, 0, stream>>>(bufA, actHi, actLo, 1048576);

  // FC1 (int8 codes -> in-register bf16), 256 blocks; then finalize + FC2
  fc1_mfma<<<dim3(8, 32), 256, 0, stream>>>(c1, actHi, actLo, fc1part);
  fc1_fin<<<128, 256, 0, stream>>>(fc1part, dst + 16, fb1, fc1T);
  fc2_kernel<<<1000, 256, 0, stream>>>(fc1T, c2, dst + 20, fb2, (float*)d_out);
}

// Round 9
// 790.566 us; speedup vs baseline: 51.6465x; 1.0637x over previous
//
#include <hip/hip_runtime.h>
#include <hip/hip_bf16.h>
#include <stdint.h>

#define DEV __device__ __forceinline__

typedef __bf16 bf16x8 __attribute__((ext_vector_type(8)));
typedef float f32x4 __attribute__((ext_vector_type(4)));
typedef unsigned short us8 __attribute__((ext_vector_type(8)));
typedef int8_t i8x8 __attribute__((ext_vector_type(8)));

DEV unsigned short f2us(float f) {
  __hip_bfloat16 h = __float2bfloat16(f);
  unsigned short u;
  __builtin_memcpy(&u, &h, 2);
  return u;
}

DEV double wave_reduce_d(double v) {
#pragma unroll
  for (int off = 32; off > 0; off >>= 1) v += __shfl_down(v, off);
  return v;
}

DEV double dbl_block_reduce(double v, double* lds) {
  v = wave_reduce_d(v);
  int lane = threadIdx.x & 63, w = threadIdx.x >> 6;
  if (lane == 0) lds[w] = v;
  __syncthreads();
  double r = 0.0;
  if (threadIdx.x == 0) r = lds[0] + lds[1] + lds[2] + lds[3];
  __syncthreads();
  return r;
}

// ---------------- ternarize: fp64 stats, 4x-unrolled float4 sweeps (MLP) ----------------
struct TDesc { const float* w; int n; };
struct TDescs { TDesc d[6]; };

DEV double abs4d(float4 v) {
  return fabs((double)v.x) + fabs((double)v.y) + fabs((double)v.z) + fabs((double)v.w);
}

// one launch, all 6 tensors: sum|w| into st[slot*4]. 4 independent load streams.
__global__ __launch_bounds__(256) void tern_abs_all(TDescs td, double* __restrict__ st) {
  __shared__ double lds[4];
  const int t = blockIdx.y;
  const float4* w4 = (const float4*)td.d[t].w;
  const int n4 = td.d[t].n >> 2;
  const int S = gridDim.x * 256;
  int i = blockIdx.x * 256 + threadIdx.x;
  double s0 = 0.0, s1 = 0.0, s2 = 0.0, s3 = 0.0;
  for (; i + 3 * S < n4; i += 4 * S) {
    float4 v0 = w4[i];
    float4 v1 = w4[i + S];
    float4 v2 = w4[i + 2 * S];
    float4 v3 = w4[i + 3 * S];
    s0 += abs4d(v0);
    s1 += abs4d(v1);
    s2 += abs4d(v2);
    s3 += abs4d(v3);
  }
  for (; i < n4; i += S) s0 += abs4d(w4[i]);
  double s = (s0 + s1) + (s2 + s3);
  s = dbl_block_reduce(s, lds);
  if (threadIdx.x == 0 && s != 0.0) atomicAdd(st + t * 4, s);
}

struct MDesc { const float* w; int8_t* out; int n; };
struct MDescs { MDesc d[6]; };

DEV int proc4(float4 v, double delta, double& ms, double& cnt) {
  float e[4] = {v.x, v.y, v.z, v.w};
  char pk[4];
#pragma unroll
  for (int j = 0; j < 4; ++j) {
    double d = (double)e[j];
    double a = fabs(d);
    if (a > delta) { ms += a; cnt += 1.0; }
    pk[j] = (char)((d > delta) ? 1 : ((d < -delta) ? -1 : 0));
  }
  int w32;
  __builtin_memcpy(&w32, pk, 4);
  return w32;
}

// one launch, all 6 tensors: masked sum + count into st[slot*4+1,2]; optional int8
// codes (4B-packed). Codes depend on delta only -> fused with this pass.
__global__ __launch_bounds__(256) void tern_masked_code_all(MDescs td, double* __restrict__ st) {
  __shared__ double lds[4];
  const int t = blockIdx.y;
  const float4* w4 = (const float4*)td.d[t].w;
  int8_t* out = td.d[t].out;
  const int n4 = td.d[t].n >> 2;
  const double delta = 0.7 * st[t * 4] / (double)td.d[t].n;
  const int S = gridDim.x * 256;
  int i = blockIdx.x * 256 + threadIdx.x;
  double m0 = 0.0, m1 = 0.0, m2 = 0.0, m3 = 0.0;
  double c0 = 0.0, c1x = 0.0, c2x = 0.0, c3 = 0.0;
  for (; i + 3 * S < n4; i += 4 * S) {
    float4 v0 = w4[i];
    float4 v1 = w4[i + S];
    float4 v2 = w4[i + 2 * S];
    float4 v3 = w4[i + 3 * S];
    int p0 = proc4(v0, delta, m0, c0);
    int p1 = proc4(v1, delta, m1, c1x);
    int p2 = proc4(v2, delta, m2, c2x);
    int p3 = proc4(v3, delta, m3, c3);
    if (out) {
      *(int*)(out + ((size_t)i << 2)) = p0;
      *(int*)(out + ((size_t)(i + S) << 2)) = p1;
      *(int*)(out + ((size_t)(i + 2 * S) << 2)) = p2;
      *(int*)(out + ((size_t)(i + 3 * S) << 2)) = p3;
    }
  }
  for (; i < n4; i += S) {
    int p = proc4(w4[i], delta, m0, c0);
    if (out) *(int*)(out + ((size_t)i << 2)) = p;
  }
  double ms = (m0 + m1) + (m2 + m3);
  double cnt = (c0 + c1x) + (c2x + c3);
  ms = dbl_block_reduce(ms, lds);
  cnt = dbl_block_reduce(cnt, lds);
  if (threadIdx.x == 0 && cnt != 0.0) {
    atomicAdd(st + t * 4 + 1, ms);
    atomicAdd(st + t * 4 + 2, cnt);
  }
}

DEV float tern_alpha_d(const double* st, double n) {
  double cnt = st[2];
  return (float)(cnt > 0.0 ? st[1] / fmax(cnt, 1.0) : st[0] / n);
}
DEV double tern_alpha_dd(const double* st, double n) {
  double cnt = st[2];
  return cnt > 0.0 ? st[1] / fmax(cnt, 1.0) : st[0] / n;
}

// conv2-4 weights -> bf16 codes {-1,0,+1}, layout [cout][k=tap*CIN+ci]
__global__ __launch_bounds__(256) void tern_write_convb(const float* __restrict__ w,
                                                        const double* __restrict__ st, int total,
                                                        int CIN, unsigned short* __restrict__ out) {
  int i = blockIdx.x * 256 + threadIdx.x;
  if (i >= total) return;
  double delta = 0.7 * st[0] / (double)total;
  double v = (double)w[i];
  float code = v > delta ? 1.f : (v < -delta ? -1.f : 0.f);
  int cin9 = CIN * 9;
  int o = i / cin9, rem = i - o * cin9;
  int ci = rem / 9, tap = rem - ci * 9;
  out[(size_t)o * cin9 + tap * CIN + ci] = f2us(code);
}

// conv1 weights (cin=3) -> bf16 codes padded to 32 ci: [64][k=tap*32+ci]
__global__ __launch_bounds__(256) void tern_write_convb_pad(const float* __restrict__ w,
                                                            const double* __restrict__ st,
                                                            unsigned short* __restrict__ out) {
  int i = blockIdx.x * 256 + threadIdx.x;
  if (i >= 64 * 288) return;
  int o = i / 288, rem = i - o * 288;
  int tap = rem >> 5, ci = rem & 31;
  float code = 0.f;
  if (ci < 3) {
    double delta = 0.7 * st[0] / 1728.0;
    double v = (double)w[(o * 3 + ci) * 9 + tap];
    code = v > delta ? 1.f : (v < -delta ? -1.f : 0.f);
  }
  out[i] = f2us(code);
}

// ---------------- BN finalize (alpha-folded; bias cancels exactly) ----------------
__global__ __launch_bounds__(256) void bn_fin_alpha(const double* __restrict__ pS,
                                                    const double* __restrict__ pQ, int P,
                                                    const float* __restrict__ g,
                                                    const float* __restrict__ be, double M,
                                                    const double* __restrict__ st, double nels,
                                                    float* __restrict__ scsh, int C) {
  __shared__ double lds[4];
  const int c = blockIdx.x;
  double s = 0.0, q = 0.0;
  for (int p = threadIdx.x; p < P; p += 256) {
    s += pS[(size_t)c * P + p];
    q += pQ[(size_t)c * P + p];
  }
  s = dbl_block_reduce(s, lds);
  q = dbl_block_reduce(q, lds);
  if (threadIdx.x == 0) {
    double al = tern_alpha_dd(st, nels);
    double mean = s / M;
    double var = q / M - mean * mean;
    double sc = (double)g[c] * al / sqrt(al * al * var + 1e-5);
    scsh[c] = (float)sc;
    scsh[C + c] = (float)((double)be[c] - mean * sc);
  }
}

// ---------------- x NCHW(3ch) -> NHWC padded to 32ch fp32 ----------------
__global__ __launch_bounds__(256) void pad32(const float* __restrict__ x,
                                             float* __restrict__ x32) {
  int i = blockIdx.x * 256 + threadIdx.x;  // 32*16384
  int px = i & 16383, n = i >> 14;
  float v0 = x[((size_t)n * 3 + 0) * 16384 + px];
  float v1 = x[((size_t)n * 3 + 1) * 16384 + px];
  float v2 = x[((size_t)n * 3 + 2) * 16384 + px];
  float4* dst = (float4*)(x32 + (size_t)i * 32);
  dst[0] = make_float4(v0, v1, v2, 0.f);
  float4 z = make_float4(0.f, 0.f, 0.f, 0.f);
#pragma unroll
  for (int j = 1; j < 8; ++j) dst[j] = z;
}

// ---------------- NCHW fp32 -> NHWC fp32 transpose ----------------
__global__ __launch_bounds__(256) void nchw2nhwc(const float* __restrict__ in,
                                                 float* __restrict__ out, int C, int HW) {
  __shared__ float t[64][65];
  const int c0 = blockIdx.x * 64, p0 = blockIdx.y * 64, n = blockIdx.z;
  const float* src = in + (size_t)n * C * HW;
  for (int u = threadIdx.x; u < 4096; u += 256) {
    int cl = u >> 6, pl = u & 63;
    t[cl][pl] = src[(size_t)(c0 + cl) * HW + p0 + pl];
  }
  __syncthreads();
  float* dst = out + (size_t)n * HW * C;
  for (int u = threadIdx.x; u < 4096; u += 256) {
    int pl = u >> 6, cl = u & 63;
    dst[(size_t)(p0 + pl) * C + c0 + cl] = t[cl][pl];
  }
}

// ---------------- MFMA implicit-GEMM conv body (hi/lo bf16 split) ----------------
template <int CIN, int H, int PH, int NW>
DEV void conv_body(const float* __restrict__ inNHWC, const unsigned short* __restrict__ wT,
                   int wvCout, int n, int x0, int y0, unsigned short* hiT, unsigned short* loT,
                   f32x4 (&acc)[2][PH]) {
  constexpr int W = H;
  constexpr int K = 9 * CIN;
  constexpr int CH = CIN / 32;
  constexpr int NU = (PH + 2) * 18 * 4;
  const int lane = threadIdx.x & 63;
  const int l15 = lane & 15, l4 = lane >> 4;

#pragma unroll
  for (int g = 0; g < 2; ++g)
#pragma unroll
    for (int pt = 0; pt < PH; ++pt) acc[g][pt] = (f32x4){0.f, 0.f, 0.f, 0.f};

#pragma unroll 1
  for (int cc = 0; cc < CH; ++cc) {
    __syncthreads();
    for (int u = threadIdx.x; u < NU; u += NW * 64) {
      int q = u & 3, rem = u >> 2;
      int xx = rem % 18, yy = rem / 18;
      int gy = y0 + yy - 1, gx = x0 + xx - 1;
      us8 hv = (us8)0, lv = (us8)0;
      if ((unsigned)gy < (unsigned)H && (unsigned)gx < (unsigned)W) {
        const float* src = inNHWC + (((size_t)(n * H + gy) * W + gx) * CIN + cc * 32 + q * 8);
        float4 a = *(const float4*)src;
        float4 c = *(const float4*)(src + 4);
        float f[8] = {a.x, a.y, a.z, a.w, c.x, c.y, c.z, c.w};
#pragma unroll
        for (int j = 0; j < 8; ++j) {
          __hip_bfloat16 h = __float2bfloat16(f[j]);
          unsigned short hu;
          __builtin_memcpy(&hu, &h, 2);
          hv[j] = hu;
          lv[j] = f2us(f[j] - __bfloat162float(h));
        }
      }
      int off = (rem << 5) + (q << 3);
      *(us8*)(hiT + off) = hv;
      *(us8*)(loT + off) = lv;
    }
    __syncthreads();

#pragma unroll
    for (int tap = 0; tap < 9; ++tap) {
      const int dy = tap / 3, dx = tap % 3;
      bf16x8 aF[2];
#pragma unroll
      for (int g = 0; g < 2; ++g) {
        int co = wvCout + g * 16 + l15;
        aF[g] = *(const bf16x8*)(wT + (size_t)co * K + tap * CIN + cc * 32 + l4 * 8);
      }
      const int tb = (dy * 18 + dx + l15) * 32 + l4 * 8;
#pragma unroll
      for (int pt = 0; pt < PH; ++pt) {
        int off = tb + pt * (18 * 32);
        bf16x8 bh = *(const bf16x8*)(hiT + off);
        bf16x8 bl = *(const bf16x8*)(loT + off);
        acc[0][pt] = __builtin_amdgcn_mfma_f32_16x16x32_bf16(aF[0], bh, acc[0][pt], 0, 0, 0);
        acc[1][pt] = __builtin_amdgcn_mfma_f32_16x16x32_bf16(aF[1], bh, acc[1][pt], 0, 0, 0);
        acc[0][pt] = __builtin_amdgcn_mfma_f32_16x16x32_bf16(aF[0], bl, acc[0][pt], 0, 0, 0);
        acc[1][pt] = __builtin_amdgcn_mfma_f32_16x16x32_bf16(aF[1], bl, acc[1][pt], 0, 0, 0);
      }
    }
  }
}

// fused fp64 BN partial write (per wave, 16-lane reduce)
template <int PH>
DEV void bn_partials(const f32x4 (&acc)[2][PH], int wvCout, int p, int P,
                     double* __restrict__ pS, double* __restrict__ pQ) {
  const int lane = threadIdx.x & 63;
  const int l15 = lane & 15, l4 = lane >> 4;
#pragma unroll
  for (int g = 0; g < 2; ++g) {
    float sv[4] = {0, 0, 0, 0}, qv[4] = {0, 0, 0, 0};
#pragma unroll
    for (int pt = 0; pt < PH; ++pt)
#pragma unroll
      for (int r = 0; r < 4; ++r) {
        float v = acc[g][pt][r];
        sv[r] += v;
        qv[r] = fmaf(v, v, qv[r]);
      }
#pragma unroll
    for (int r = 0; r < 4; ++r)
#pragma unroll
      for (int m = 1; m < 16; m <<= 1) {
        sv[r] += __shfl_xor(sv[r], m);
        qv[r] += __shfl_xor(qv[r], m);
      }
    if (l15 == 0) {
#pragma unroll
      for (int r = 0; r < 4; ++r) {
        int co = wvCout + g * 16 + l4 * 4 + r;
        pS[(size_t)co * P + p] = (double)sv[r];
        pQ[(size_t)co * P + p] = (double)qv[r];
      }
    }
  }
}

// layers 2-4: z store (NCHW fp32) + partials
template <int CIN, int H, int PH>
__global__ __launch_bounds__(256) void conv_mfma(const float* __restrict__ inNHWC,
                                                 const unsigned short* __restrict__ wT,
                                                 float* __restrict__ z, int COUT,
                                                 double* __restrict__ pS,
                                                 double* __restrict__ pQ, int P) {
  constexpr int W = H;
  constexpr int TX = W / 16;
  __shared__ unsigned short hiT[(PH + 2) * 18 * 32];
  __shared__ unsigned short loT[(PH + 2) * 18 * 32];
  const int bx = blockIdx.x;
  const int tX = bx % TX, tY = bx / TX;
  const int n = blockIdx.z;
  const int wave = threadIdx.x >> 6, lane = threadIdx.x & 63;
  const int l15 = lane & 15, l4 = lane >> 4;
  const int wvCout = blockIdx.y * 128 + wave * 32;
  const int x0 = tX * 16, y0 = tY * PH;
  f32x4 acc[2][PH];
  conv_body<CIN, H, PH, 4>(inNHWC, wT, wvCout, n, x0, y0, hiT, loT, acc);
#pragma unroll
  for (int g = 0; g < 2; ++g)
#pragma unroll
    for (int pt = 0; pt < PH; ++pt) {
      int oy = y0 + pt;
#pragma unroll
      for (int r = 0; r < 4; ++r) {
        int co = wvCout + g * 16 + l4 * 4 + r;
        z[(((size_t)n * COUT + co) * H + oy) * W + x0 + l15] = acc[g][pt][r];
      }
    }
  bn_partials<PH>(acc, wvCout, n * gridDim.x + bx, P, pS, pQ);
}

// layer 1 pass 1: partials only (z never materialized)
__global__ __launch_bounds__(128) void conv1_mfma_stats(const float* __restrict__ inNHWC,
                                                        const unsigned short* __restrict__ wT,
                                                        double* __restrict__ pS,
                                                        double* __restrict__ pQ) {
  __shared__ unsigned short hiT[10 * 18 * 32];
  __shared__ unsigned short loT[10 * 18 * 32];
  const int bx = blockIdx.x;
  const int tX = bx & 7, tY = bx >> 3;
  const int n = blockIdx.z;
  const int wave = threadIdx.x >> 6;
  const int wvCout = wave * 32;
  f32x4 acc[2][8];
  conv_body<32, 128, 8, 2>(inNHWC, wT, wvCout, n, tX * 16, tY * 8, hiT, loT, acc);
  bn_partials<8>(acc, wvCout, n * gridDim.x + bx, 4096, pS, pQ);
}

// layer 1 pass 2: recompute, BN+relu+2x2 maxpool, write pooled NHWC directly
__global__ __launch_bounds__(128) void conv1_mfma_pool(const float* __restrict__ inNHWC,
                                                       const unsigned short* __restrict__ wT,
                                                       const float* __restrict__ scsh,
                                                       float* __restrict__ outNHWC) {
  __shared__ unsigned short hiT[10 * 18 * 32];
  __shared__ unsigned short loT[10 * 18 * 32];
  const int bx = blockIdx.x;
  const int tX = bx & 7, tY = bx >> 3;
  const int n = blockIdx.z;
  const int wave = threadIdx.x >> 6, lane = threadIdx.x & 63;
  const int l15 = lane & 15, l4 = lane >> 4;
  const int wvCout = wave * 32;
  const int x0 = tX * 16, y0 = tY * 8;
  f32x4 acc[2][8];
  conv_body<32, 128, 8, 2>(inNHWC, wT, wvCout, n, x0, y0, hiT, loT, acc);
#pragma unroll
  for (int g = 0; g < 2; ++g) {
    const int co0 = wvCout + g * 16 + l4 * 4;
#pragma unroll
    for (int pt = 0; pt < 8; pt += 2) {
      float m[4];
#pragma unroll
      for (int r = 0; r < 4; ++r) {
        float sc = scsh[co0 + r], sh = scsh[64 + co0 + r];
        float v0 = fmaxf(fmaf(acc[g][pt][r], sc, sh), 0.f);
        float v1 = fmaxf(fmaf(acc[g][pt + 1][r], sc, sh), 0.f);
        float a = fmaxf(v0, v1);
        m[r] = fmaxf(a, __shfl_xor(a, 1));
      }
      if ((l15 & 1) == 0) {
        int oy = (y0 + pt) >> 1, ox = (x0 + l15) >> 1;
        *(float4*)(outNHWC + ((((size_t)n * 64 + oy) * 64 + ox) << 6) + co0) =
            make_float4(m[0], m[1], m[2], m[3]);
      }
    }
  }
}

// ---------------- fused norm+relu+pool (fp32 z in, NCHW out) ----------------
__global__ __launch_bounds__(256) void bn_pool(const float* __restrict__ y,
                                               const float* __restrict__ scsh, int C, int lw,
                                               int lh, int lc, int N, float* __restrict__ out) {
  const int Wo = 1 << lw, Ho = 1 << lh;
  const int total = (N << lc) << (lw + lh);
  const int Wrow = 1 << (lw + 1);
  for (int i = blockIdx.x * 256 + threadIdx.x; i < total; i += gridDim.x * 256) {
    int wo = i & (Wo - 1);
    int ho = (i >> lw) & (Ho - 1);
    int c = (i >> (lw + lh)) & (C - 1);
    int n = i >> (lw + lh + lc);
    float sc = scsh[c], sh = scsh[C + c];
    size_t idx = (((((size_t)n * C + c) << (lh + 1)) + (ho << 1)) << (lw + 1)) + (wo << 1);
    float z00 = fmaxf(fmaf(y[idx], sc, sh), 0.f);
    float z01 = fmaxf(fmaf(y[idx + 1], sc, sh), 0.f);
    float z10 = fmaxf(fmaf(y[idx + Wrow], sc, sh), 0.f);
    float z11 = fmaxf(fmaf(y[idx + Wrow + 1], sc, sh), 0.f);
    out[i] = fmaxf(fmaxf(z00, z01), fmaxf(z10, z11));
  }
}

// ---------------- pooled4 fp32 -> hi/lo bf16 ----------------
__global__ __launch_bounds__(256) void hilo_split(const float* __restrict__ in,
                                                  unsigned short* __restrict__ hi,
                                                  unsigned short* __restrict__ lo, int n) {
  int i = blockIdx.x * 256 + threadIdx.x;
  if (i >= n) return;
  float f = in[i];
  __hip_bfloat16 h = __float2bfloat16(f);
  unsigned short hu;
  __builtin_memcpy(&hu, &h, 2);
  hi[i] = hu;
  lo[i] = f2us(f - __bfloat162float(h));
}

// ---------------- FC1 MFMA GEMM: A = int8 codes converted in-register ----------------
DEV bf16x8 i8_to_bf16x8(i8x8 v) {
  us8 u;
#pragma unroll
  for (int j = 0; j < 8; ++j) {
    int c = v[j];
    u[j] = (unsigned short)(c == 0 ? 0 : (c > 0 ? 0x3F80 : 0xBF80));
  }
  bf16x8 r;
  __builtin_memcpy(&r, &u, 16);
  return r;
}

// grid (8 o-blocks, 32 k-slices) = 256 blocks; wave = 32 outs; partial fp32 [s][o][n]
__global__ __launch_bounds__(256) void fc1_mfma(const int8_t* __restrict__ c1,
                                                const unsigned short* __restrict__ aHi,
                                                const unsigned short* __restrict__ aLo,
                                                float* __restrict__ partial) {
  const int w = threadIdx.x >> 6, lane = threadIdx.x & 63;
  const int l15 = lane & 15, l4 = lane >> 4;
  const int o0 = blockIdx.x * 128 + w * 32;
  const int s = blockIdx.y;
  const int kbase = s * 1024 + l4 * 8;
  f32x4 acc[2][2];
#pragma unroll
  for (int g = 0; g < 2; ++g)
#pragma unroll
    for (int t = 0; t < 2; ++t) acc[g][t] = (f32x4){0.f, 0.f, 0.f, 0.f};
#pragma unroll 2
  for (int kc = 0; kc < 1024; kc += 32) {
    bf16x8 a0 = i8_to_bf16x8(*(const i8x8*)(c1 + (size_t)(o0 + l15) * 32768 + kbase + kc));
    bf16x8 a1 = i8_to_bf16x8(*(const i8x8*)(c1 + (size_t)(o0 + 16 + l15) * 32768 + kbase + kc));
    bf16x8 bh0 = *(const bf16x8*)(aHi + (size_t)l15 * 32768 + kbase + kc);
    bf16x8 bl0 = *(const bf16x8*)(aLo + (size_t)l15 * 32768 + kbase + kc);
    bf16x8 bh1 = *(const bf16x8*)(aHi + (size_t)(16 + l15) * 32768 + kbase + kc);
    bf16x8 bl1 = *(const bf16x8*)(aLo + (size_t)(16 + l15) * 32768 + kbase + kc);
    acc[0][0] = __builtin_amdgcn_mfma_f32_16x16x32_bf16(a0, bh0, acc[0][0], 0, 0, 0);
    acc[0][0] = __builtin_amdgcn_mfma_f32_16x16x32_bf16(a0, bl0, acc[0][0], 0, 0, 0);
    acc[1][0] = __builtin_amdgcn_mfma_f32_16x16x32_bf16(a1, bh0, acc[1][0], 0, 0, 0);
    acc[1][0] = __builtin_amdgcn_mfma_f32_16x16x32_bf16(a1, bl0, acc[1][0], 0, 0, 0);
    acc[0][1] = __builtin_amdgcn_mfma_f32_16x16x32_bf16(a0, bh1, acc[0][1], 0, 0, 0);
    acc[0][1] = __builtin_amdgcn_mfma_f32_16x16x32_bf16(a0, bl1, acc[0][1], 0, 0, 0);
    acc[1][1] = __builtin_amdgcn_mfma_f32_16x16x32_bf16(a1, bh1, acc[1][1], 0, 0, 0);
    acc[1][1] = __builtin_amdgcn_mfma_f32_16x16x32_bf16(a1, bl1, acc[1][1], 0, 0, 0);
  }
#pragma unroll
  for (int g = 0; g < 2; ++g)
#pragma unroll
    for (int t = 0; t < 2; ++t)
#pragma unroll
      for (int r = 0; r < 4; ++r) {
        int o = o0 + g * 16 + l4 * 4 + r;
        int n = t * 16 + l15;
        partial[((size_t)s * 1024 + o) * 32 + n] = acc[g][t][r];
      }
}

__global__ __launch_bounds__(256) void fc1_fin(const float* __restrict__ partial,
                                               const double* __restrict__ st,
                                               const float* __restrict__ fb,
                                               float* __restrict__ fc1T) {
  int i = blockIdx.x * 256 + threadIdx.x;  // 32768
  int o = i >> 5;
  float s = 0.f;
#pragma unroll
  for (int t = 0; t < 32; ++t) s += partial[(size_t)t * 32768 + i];
  float alpha = tern_alpha_d(st, 33554432.0);
  fc1T[i] = fmaxf(fmaf(s, alpha, fb[o]), 0.f);
}

// ---------------- FC2 (row-parallel; tiny) ----------------
__global__ __launch_bounds__(256) void fc2_kernel(const float* __restrict__ xT,
                                                  const int8_t* __restrict__ codes,
                                                  const double* __restrict__ st,
                                                  const float* __restrict__ fb,
                                                  float* __restrict__ out) {
  const int o = blockIdx.x;
  float acc[32];
#pragma unroll
  for (int j = 0; j < 32; ++j) acc[j] = 0.f;
  const int8_t* crow = codes + (size_t)o * 1024;
  for (int k = threadIdx.x; k < 1024; k += 256) {
    int cv = crow[k];
    if (cv != 0) {
      float c = (float)cv;
      const float4* pv = (const float4*)(xT + ((size_t)k << 5));
#pragma unroll
      for (int j = 0; j < 8; ++j) {
        float4 v = pv[j];
        acc[4 * j + 0] = fmaf(c, v.x, acc[4 * j + 0]);
        acc[4 * j + 1] = fmaf(c, v.y, acc[4 * j + 1]);
        acc[4 * j + 2] = fmaf(c, v.z, acc[4 * j + 2]);
        acc[4 * j + 3] = fmaf(c, v.w, acc[4 * j + 3]);
      }
    }
  }
#pragma unroll
  for (int j = 0; j < 32; ++j) {
#pragma unroll
    for (int off = 32; off > 0; off >>= 1) acc[j] += __shfl_down(acc[j], off);
  }
  __shared__ float red[4][32];
  int lane = threadIdx.x & 63, wv = threadIdx.x >> 6;
  if (lane == 0) {
#pragma unroll
    for (int j = 0; j < 32; ++j) red[wv][j] = acc[j];
  }
  __syncthreads();
  if (threadIdx.x < 32) {
    int n = threadIdx.x;
    float alpha = tern_alpha_d(st, 1024000.0);
    out[(size_t)n * 1000 + o] = (red[0][n] + red[1][n] + red[2][n] + red[3][n]) * alpha + fb[o];
  }
}

// ---------------- host ----------------
extern "C" void kernel_launch(void* const* d_in, const int* in_sizes, int n_in, void* d_out,
                              int out_size, void* d_ws, size_t ws_size, hipStream_t stream) {
  const float* x = (const float*)d_in[0];
  const float* w1 = (const float*)d_in[1];
  const float* g1 = (const float*)d_in[3];
  const float* be1 = (const float*)d_in[4];
  const float* w2 = (const float*)d_in[5];
  const float* g2 = (const float*)d_in[7];
  const float* be2 = (const float*)d_in[8];
  const float* w3 = (const float*)d_in[9];
  const float* g3 = (const float*)d_in[11];
  const float* be3 = (const float*)d_in[12];
  const float* w4 = (const float*)d_in[13];
  const float* g4 = (const float*)d_in[15];
  const float* be4 = (const float*)d_in[16];
  const float* fw1 = (const float*)d_in[17];
  const float* fb1 = (const float*)d_in[18];
  const float* fw2 = (const float*)d_in[19];
  const float* fb2 = (const float*)d_in[20];
  // b1..b4 cancel exactly under training-mode BN (alpha-folded finalize).
  (void)in_sizes; (void)n_in; (void)out_size; (void)ws_size;

  char* ws = (char*)d_ws;
  size_t off = 0;
  auto alloc = [&](size_t bytes) {
    size_t o = off;
    off += (bytes + 255) & ~(size_t)255;
    return o;
  };
  unsigned short* wb1 = (unsigned short*)(ws + alloc((size_t)18432 * 2));    // [64][288]
  unsigned short* wb2 = (unsigned short*)(ws + alloc((size_t)73728 * 2));    // [128][576]
  unsigned short* wb3 = (unsigned short*)(ws + alloc((size_t)294912 * 2));   // [256][1152]
  unsigned short* wb4 = (unsigned short*)(ws + alloc((size_t)1179648 * 2));  // [512][2304]
  int8_t* c1 = (int8_t*)(ws + alloc((size_t)33554432));  // fc1 int8 codes [1024][32768]
  int8_t* c2 = (int8_t*)(ws + alloc((size_t)1024000));
  double* dst = (double*)(ws + alloc((size_t)32 * 8));
  float* scsh = (float*)(ws + alloc((size_t)4096 * 4));
  double* pS = (double*)(ws + alloc((size_t)262144 * 8));
  double* pQ = (double*)(ws + alloc((size_t)262144 * 8));
  float* bufY = (float*)(ws + alloc((size_t)16777216 * 4));  // 67MB: x32pad / z
  float* bufA = (float*)(ws + alloc((size_t)8388608 * 4));   // 33.5MB: pooled NCHW+NHWC
  unsigned short* actHi = (unsigned short*)(ws + alloc((size_t)1048576 * 2));
  unsigned short* actLo = (unsigned short*)(ws + alloc((size_t)1048576 * 2));
  float* fc1part = (float*)(ws + alloc((size_t)1048576 * 4));  // [32][1024][32]
  float* fc1T = (float*)(ws + alloc((size_t)32768 * 4));       // [1024][32]
  float* x32 = bufY;              // NHWC-32 input, dead after conv1
  float* bufA2 = bufA + 4194304;  // second half for NHWC copies
  // total ~152 MB (163 MB proven mapped in R1)

  hipMemsetAsync(dst, 0, 32 * 8, stream);

  // ternarize stats: one abs launch + one fused masked+code launch for all 6 tensors
  TDescs ta;
  ta.d[0] = {w1, 1728};
  ta.d[1] = {w2, 73728};
  ta.d[2] = {w3, 294912};
  ta.d[3] = {w4, 1179648};
  ta.d[4] = {fw1, 33554432};
  ta.d[5] = {fw2, 1024000};
  tern_abs_all<<<dim3(1024, 6), 256, 0, stream>>>(ta, dst);
  MDescs tm;
  tm.d[0] = {w1, nullptr, 1728};
  tm.d[1] = {w2, nullptr, 73728};
  tm.d[2] = {w3, nullptr, 294912};
  tm.d[3] = {w4, nullptr, 1179648};
  tm.d[4] = {fw1, c1, 33554432};
  tm.d[5] = {fw2, c2, 1024000};
  tern_masked_code_all<<<dim3(1024, 6), 256, 0, stream>>>(tm, dst);
  tern_write_convb_pad<<<72, 256, 0, stream>>>(w1, dst + 0, wb1);
  tern_write_convb<<<288, 256, 0, stream>>>(w2, dst + 4, 73728, 64, wb2);
  tern_write_convb<<<1152, 256, 0, stream>>>(w3, dst + 8, 294912, 128, wb3);
  tern_write_convb<<<4608, 256, 0, stream>>>(w4, dst + 12, 1179648, 256, wb4);

  float* ss1 = scsh;
  float* ss2 = scsh + 128;
  float* ss3 = scsh + 512;
  float* ss4 = scsh + 1024;

  // Layer 1 via MFMA, two-pass recompute; pooled1 written directly as NHWC.
  pad32<<<2048, 256, 0, stream>>>(x, x32);
  conv1_mfma_stats<<<dim3(128, 1, 32), 128, 0, stream>>>(x32, wb1, pS, pQ);
  bn_fin_alpha<<<64, 256, 0, stream>>>(pS, pQ, 4096, g1, be1, 524288.0, dst + 0, 1728.0, ss1,
                                       64);
  conv1_mfma_pool<<<dim3(128, 1, 32), 128, 0, stream>>>(x32, wb1, ss1, bufA);

  // Layer 2: 64->128 @64x64 (reads pooled1 NHWC in bufA; z -> bufY)
  conv_mfma<64, 64, 8><<<dim3(32, 1, 32), 256, 0, stream>>>(bufA, wb2, bufY, 128, pS, pQ, 1024);
  bn_fin_alpha<<<128, 256, 0, stream>>>(pS, pQ, 1024, g2, be2, 131072.0, dst + 4, 73728.0, ss2,
                                        128);
  bn_pool<<<16384, 256, 0, stream>>>(bufY, ss2, 128, 5, 5, 7, 32, bufA);
  nchw2nhwc<<<dim3(2, 16, 32), 256, 0, stream>>>(bufA, bufA2, 128, 1024);

  // Layer 3: 128->256 @32x32
  conv_mfma<128, 32, 4><<<dim3(16, 2, 32), 256, 0, stream>>>(bufA2, wb3, bufY, 256, pS, pQ, 512);
  bn_fin_alpha<<<256, 256, 0, stream>>>(pS, pQ, 512, g3, be3, 32768.0, dst + 8, 294912.0, ss3,
                                        256);
  bn_pool<<<8192, 256, 0, stream>>>(bufY, ss3, 256, 4, 4, 8, 32, bufA);
  nchw2nhwc<<<dim3(4, 4, 32), 256, 0, stream>>>(bufA, bufA2, 256, 256);

  // Layer 4: 256->512 @16x16; pooled4 NCHW flat == [32][32768]
  conv_mfma<256, 16, 2><<<dim3(8, 4, 32), 256, 0, stream>>>(bufA2, wb4, bufY, 512, pS, pQ, 256);
  bn_fin_alpha<<<512, 256, 0, stream>>>(pS, pQ, 256, g4, be4, 8192.0, dst + 12, 1179648.0, ss4,
                                        512);
  bn_pool<<<4096, 256, 0, stream>>>(bufY, ss4, 512, 3, 3, 9, 32, bufA);
  hilo_split<<<4096, 256, 0, stream>>>(bufA, actHi, actLo, 1048576);

  // FC1 (int8 codes -> in-register bf16), 256 blocks; then finalize + FC2
  fc1_mfma<<<dim3(8, 32), 256, 0, stream>>>(c1, actHi, actLo, fc1part);
  fc1_fin<<<128, 256, 0, stream>>>(fc1part, dst + 16, fb1, fc1T);
  fc2_kernel<<<1000, 256, 0, stream>>>(fc1T, c2, dst + 20, fb2, (float*)d_out);
}